// Round 1
// baseline (714.448 us; speedup 1.0000x reference)
//
#include <hip/hip_runtime.h>

// ---------------------------------------------------------------------------
// Pruned multi-head attention. fp32 I/O, split-bf16 (hi+lo) MFMA compute.
// B=2, S=2048, D_MODEL=1024, H=16, d_k=64, keep=int(2048*0.9)=1843
//
// Round 9: attn_av was latency-bound at 20% occupancy (2 blocks/CU,
// MfmaUtil 10.7%, HBM 7.8%). Halved per-wave q-tile (16 rows, mt removed)
// and doubled grid.x 16->32 => 4 blocks/CU, ~40% occupancy. K/V chunk loads
// are identical across the 4 waves of a block, so the doubled read volume
// stays in L1/L2 (per-bh working set 768 KB << 4 MB L2/XCD).
// ---------------------------------------------------------------------------

typedef __attribute__((ext_vector_type(8))) short short8;   // 8 bf16 (4 VGPRs)
typedef __attribute__((ext_vector_type(4))) short short4v;
typedef __attribute__((ext_vector_type(4))) float f32x4;

#define KEEP 1843

#if __has_builtin(__builtin_amdgcn_exp2f)
  #define PEXP(x) __builtin_amdgcn_exp2f(x)
  #define QSC 0.18033688011112042f   // log2(e)/8 folded into Q projection
#else
  #define PEXP(x) __expf(x)
  #define QSC 0.125f
#endif

#define AS1(p) ((const __attribute__((address_space(1))) void*)(p))
#define AS3(p) ((__attribute__((address_space(3))) void*)(p))

static __device__ __forceinline__ float bf2f(unsigned short s) {
    union { unsigned u; float f; } v; v.u = ((unsigned)s) << 16; return v.f;
}
static __device__ __forceinline__ unsigned short f2bf(float f) {
    union { float f; unsigned u; } v; v.f = f;
    unsigned u = v.u;
    unsigned r = (u + 0x7FFFu + ((u >> 16) & 1u)) >> 16;   // RNE
    return (unsigned short)r;
}

#define MFMA(A, B, C) __builtin_amdgcn_mfma_f32_16x16x32_bf16(A, B, C, 0, 0, 0)

// fp32 array -> hi/lo bf16 arrays (x = hi + lo to ~2^-17 relative)
__global__ __launch_bounds__(256) void cvt_split(
    const float* __restrict__ in, unsigned short* __restrict__ hi,
    unsigned short* __restrict__ lo, int n4)
{
    int i = blockIdx.x * 256 + threadIdx.x;
    if (i >= n4) return;
    f32x4 x = ((const f32x4*)in)[i];
    short4v h, l;
#pragma unroll
    for (int j = 0; j < 4; j++) {
        unsigned short hv = f2bf(x[j]);
        h[j] = (short)hv;
        l[j] = (short)f2bf(x[j] - bf2f(hv));
    }
    ((short4v*)hi)[i] = h;
    ((short4v*)lo)[i] = l;
}

__global__ __launch_bounds__(256) void zero_f32(float* __restrict__ p, int n) {
    int i = blockIdx.x * 256 + threadIdx.x;
    if (i < n) p[i] = 0.f;
}

// Fused Q/K/V projections, m97-style LDS staging. 128x128 tile, BK=32.
// z=0: Q -> bf16 hi+lo head layout, scaled QSC; z=1: K likewise; z=2: V -> V^T.
__global__ __launch_bounds__(256) void gemm_qkv(
    const short* __restrict__ A0, const short* __restrict__ Al0,
    const short* __restrict__ A1, const short* __restrict__ Al1,
    const short* __restrict__ A2, const short* __restrict__ Al2,
    const short* __restrict__ W0, const short* __restrict__ Wl0,
    const short* __restrict__ W1, const short* __restrict__ Wl1,
    const short* __restrict__ W2, const short* __restrict__ Wl2,
    const float* __restrict__ b0, const float* __restrict__ b1,
    const float* __restrict__ b2,
    unsigned short* __restrict__ Qhi, unsigned short* __restrict__ Qlo,
    unsigned short* __restrict__ Khi, unsigned short* __restrict__ Klo,
    unsigned short* __restrict__ Vt)
{
    int z = blockIdx.z;
    const short *Ahg, *Alg, *Whg, *Wlg; const float* bias;
    unsigned short *oh = 0, *ol = 0; float scale; int mode;
    if (z == 0)      { Ahg=A0; Alg=Al0; Whg=W0; Wlg=Wl0; bias=b0; oh=Qhi; ol=Qlo; scale=QSC;  mode=0; }
    else if (z == 1) { Ahg=A1; Alg=Al1; Whg=W1; Wlg=Wl1; bias=b1; oh=Khi; ol=Klo; scale=1.0f; mode=0; }
    else             { Ahg=A2; Alg=Al2; Whg=W2; Wlg=Wl2; bias=b2; oh=Vt;          scale=1.0f; mode=2; }

    __shared__ __align__(16) short Ah_l[128*32];
    __shared__ __align__(16) short Al_l[128*32];
    __shared__ __align__(16) short Wh_l[128*32];
    __shared__ __align__(16) short Wl_l[128*32];

    int tid  = threadIdx.x;
    int w    = tid >> 6;
    int lane = tid & 63;
    int ln   = lane & 15;
    int quad = lane >> 4;
    int rowBase = blockIdx.y * 128;
    int colBase = blockIdx.x * 128;
    int mBase = (w & 1) * 64;        // wave's quadrant inside 128x128
    int nBase = (w >> 1) * 64;

    // staging: wave w covers rows [w*32, w*32+32); lane -> row w*32+j*16+lane/4,
    // col (lane&3)*8; LDS dest = base + lane*16B (row-major [128][32]).
    int srow = (lane >> 2);
    int scol = (lane & 3) * 8;
    const short* Ag_h = Ahg + (size_t)rowBase * 1024;
    const short* Ag_l = Alg + (size_t)rowBase * 1024;
    const short* Wg_h = Whg + (size_t)colBase * 1024;
    const short* Wg_l = Wlg + (size_t)colBase * 1024;

    f32x4 acc[4][4];
#pragma unroll
    for (int i = 0; i < 4; i++)
#pragma unroll
        for (int j = 0; j < 4; j++) acc[i][j] = (f32x4){0.f, 0.f, 0.f, 0.f};

    for (int kk = 0; kk < 1024; kk += 32) {
#pragma unroll
        for (int j = 0; j < 2; j++) {
            int r = w*32 + j*16;
            size_t go = (size_t)(r + srow) * 1024 + kk + scol;
            __builtin_amdgcn_global_load_lds(AS1(Ag_h + go), AS3(Ah_l + r*32), 16, 0, 0);
            __builtin_amdgcn_global_load_lds(AS1(Ag_l + go), AS3(Al_l + r*32), 16, 0, 0);
            __builtin_amdgcn_global_load_lds(AS1(Wg_h + go), AS3(Wh_l + r*32), 16, 0, 0);
            __builtin_amdgcn_global_load_lds(AS1(Wg_l + go), AS3(Wl_l + r*32), 16, 0, 0);
        }
        __syncthreads();

        short8 ah[4], al[4], bh[4], bl[4];
#pragma unroll
        for (int mt = 0; mt < 4; mt++) {
            int r = mBase + mt*16 + ln;
            ah[mt] = *(const short8*)(Ah_l + r*32 + quad*8);
            al[mt] = *(const short8*)(Al_l + r*32 + quad*8);
        }
#pragma unroll
        for (int nt = 0; nt < 4; nt++) {
            int c = nBase + nt*16 + ln;
            bh[nt] = *(const short8*)(Wh_l + c*32 + quad*8);
            bl[nt] = *(const short8*)(Wl_l + c*32 + quad*8);
        }
#pragma unroll
        for (int mt = 0; mt < 4; mt++)
#pragma unroll
            for (int nt = 0; nt < 4; nt++) {
                acc[mt][nt] = MFMA(ah[mt], bh[nt], acc[mt][nt]);
                acc[mt][nt] = MFMA(ah[mt], bl[nt], acc[mt][nt]);
                acc[mt][nt] = MFMA(al[mt], bh[nt], acc[mt][nt]);
            }
        __syncthreads();
    }

#pragma unroll
    for (int mt = 0; mt < 4; mt++) {
#pragma unroll
        for (int nt = 0; nt < 4; nt++) {
            int col = colBase + nBase + nt*16 + ln;
            float bv = bias[col];
#pragma unroll
            for (int i = 0; i < 4; i++) {
                int row = rowBase + mBase + mt*16 + quad*4 + i;   // D: row=quad*4+reg
                float val = (acc[mt][nt][i] + bv) * scale;
                int b_  = row >> 11, s = row & 2047;
                int h   = col >> 6,  d = col & 63;
                int bh_ = b_ * 16 + h;
                if (mode == 2) {
                    oh[((size_t)bh_ * 64 + d) * 2048 + s] = f2bf(val);
                } else {
                    size_t idx = ((size_t)bh_ * 2048 + s) * 64 + d;
                    unsigned short hv = f2bf(val);
                    oh[idx] = hv;
                    ol[idx] = f2bf(val - bf2f(hv));
                }
            }
        }
    }
}

// out = concat(bf16) @ Wo^T + bo (split Wo, fp32 out), LDS-staged.
__global__ __launch_bounds__(256) void gemm_out(
    const short* __restrict__ Ag, const short* __restrict__ Whg,
    const short* __restrict__ Wlg, const float* __restrict__ bias,
    float* __restrict__ out)
{
    __shared__ __align__(16) short A_l[128*32];
    __shared__ __align__(16) short Wh_l[128*32];
    __shared__ __align__(16) short Wl_l[128*32];

    int tid  = threadIdx.x;
    int w    = tid >> 6;
    int lane = tid & 63;
    int ln   = lane & 15;
    int quad = lane >> 4;
    int rowBase = blockIdx.y * 128;
    int colBase = blockIdx.x * 128;
    int mBase = (w & 1) * 64;
    int nBase = (w >> 1) * 64;

    int srow = (lane >> 2);
    int scol = (lane & 3) * 8;
    const short* Abase = Ag  + (size_t)rowBase * 1024;
    const short* Whb   = Whg + (size_t)colBase * 1024;
    const short* Wlb   = Wlg + (size_t)colBase * 1024;

    f32x4 acc[4][4];
#pragma unroll
    for (int i = 0; i < 4; i++)
#pragma unroll
        for (int j = 0; j < 4; j++) acc[i][j] = (f32x4){0.f, 0.f, 0.f, 0.f};

    for (int kk = 0; kk < 1024; kk += 32) {
#pragma unroll
        for (int j = 0; j < 2; j++) {
            int r = w*32 + j*16;
            size_t go = (size_t)(r + srow) * 1024 + kk + scol;
            __builtin_amdgcn_global_load_lds(AS1(Abase + go), AS3(A_l  + r*32), 16, 0, 0);
            __builtin_amdgcn_global_load_lds(AS1(Whb   + go), AS3(Wh_l + r*32), 16, 0, 0);
            __builtin_amdgcn_global_load_lds(AS1(Wlb   + go), AS3(Wl_l + r*32), 16, 0, 0);
        }
        __syncthreads();

        short8 a[4], bh[4], bl[4];
#pragma unroll
        for (int mt = 0; mt < 4; mt++)
            a[mt] = *(const short8*)(A_l + (mBase + mt*16 + ln)*32 + quad*8);
#pragma unroll
        for (int nt = 0; nt < 4; nt++) {
            int c = nBase + nt*16 + ln;
            bh[nt] = *(const short8*)(Wh_l + c*32 + quad*8);
            bl[nt] = *(const short8*)(Wl_l + c*32 + quad*8);
        }
#pragma unroll
        for (int mt = 0; mt < 4; mt++)
#pragma unroll
            for (int nt = 0; nt < 4; nt++) {
                acc[mt][nt] = MFMA(a[mt], bh[nt], acc[mt][nt]);
                acc[mt][nt] = MFMA(a[mt], bl[nt], acc[mt][nt]);
            }
        __syncthreads();
    }

#pragma unroll
    for (int mt = 0; mt < 4; mt++) {
#pragma unroll
        for (int nt = 0; nt < 4; nt++) {
            int col = colBase + nBase + nt*16 + ln;
            float bv = bias[col];
#pragma unroll
            for (int i = 0; i < 4; i++) {
                int row = rowBase + mBase + mt*16 + quad*4 + i;
                out[(size_t)row * 1024 + col] = acc[mt][nt][i] + bv;
            }
        }
    }
}

// rowsum[q] += sum over this block's k-quarter of 2^(c_qk).  Split-precision.
// Wave owns 64 q rows (4 m-tiles). grid (8 qblocks, 4 ksplit, 32 bh).
__global__ __launch_bounds__(256) void attn_rowsum(
    const short* __restrict__ Qhi, const short* __restrict__ Qlo,
    const short* __restrict__ Khi, const short* __restrict__ Klo,
    float* __restrict__ rowsum)
{
    int bh = blockIdx.z, tid = threadIdx.x;
    int w = tid >> 6, lane = tid & 63, ln = lane & 15, quad = lane >> 4;
    int qb  = blockIdx.x * 256 + w * 64;
    int kt0 = blockIdx.y * 32;            // 32 k-tiles of 16 = 512 keys
    const short* QH = Qhi + (size_t)bh * 2048 * 64;
    const short* QL = Qlo + (size_t)bh * 2048 * 64;
    const short* KH = Khi + (size_t)bh * 2048 * 64;
    const short* KL = Klo + (size_t)bh * 2048 * 64;

    short8 qh[4][2], ql[4][2];
#pragma unroll
    for (int mt = 0; mt < 4; mt++)
#pragma unroll
        for (int half = 0; half < 2; half++) {
            size_t o = (size_t)(qb + mt*16 + ln) * 64 + half*32 + quad*8;
            qh[mt][half] = *(const short8*)(QH + o);
            ql[mt][half] = *(const short8*)(QL + o);
        }

    short8 kh[2][2], kl[2][2];   // [buf][dchunk]
    auto loadK = [&](int buf, int kt) {
        size_t ko = (size_t)(kt*16 + ln) * 64 + quad*8;
        kh[buf][0] = *(const short8*)(KH + ko);
        kh[buf][1] = *(const short8*)(KH + ko + 32);
        kl[buf][0] = *(const short8*)(KL + ko);
        kl[buf][1] = *(const short8*)(KL + ko + 32);
    };

    float racc[4][4] = {};
    auto comp = [&](int buf) {
#pragma unroll
        for (int mt = 0; mt < 4; mt++) {
            f32x4 c1 = (f32x4){0.f,0.f,0.f,0.f};
            f32x4 c2 = (f32x4){0.f,0.f,0.f,0.f};
            c1 = MFMA(qh[mt][0], kh[buf][0], c1); c1 = MFMA(qh[mt][1], kh[buf][1], c1);
            c2 = MFMA(qh[mt][0], kl[buf][0], c2); c2 = MFMA(qh[mt][1], kl[buf][1], c2);
            c2 = MFMA(ql[mt][0], kh[buf][0], c2); c2 = MFMA(ql[mt][1], kh[buf][1], c2);
#pragma unroll
            for (int i = 0; i < 4; i++)
                racc[mt][i] += PEXP(c1[i] + c2[i]);
        }
    };

    loadK(0, kt0);
    for (int t = 0; t < 32; t += 2) {
        loadK(1, kt0 + t + 1);
        comp(0);
        if (t + 2 < 32) loadK(0, kt0 + t + 2);
        comp(1);
    }
#pragma unroll
    for (int mt = 0; mt < 4; mt++)
#pragma unroll
        for (int i = 0; i < 4; i++)
            for (int d = 1; d < 16; d <<= 1)
                racc[mt][i] += __shfl_xor(racc[mt][i], d, 64);
    if (ln == 0) {
#pragma unroll
        for (int mt = 0; mt < 4; mt++)
#pragma unroll
            for (int i = 0; i < 4; i++)
                atomicAdd(&rowsum[bh * 2048 + qb + mt*16 + quad*4 + i], racc[mt][i]);
    }
}

// colsum[k] += sum over this block's q-quarter of 2^(c_qk)/rowsum[q].
// Wave owns 64 keys (4 n-tiles). grid (8 kblocks, 4 qsplit, 32 bh).
__global__ __launch_bounds__(256) void attn_colsum(
    const short* __restrict__ Qhi, const short* __restrict__ Qlo,
    const short* __restrict__ Khi, const short* __restrict__ Klo,
    const float* __restrict__ rowsum, float* __restrict__ colsum)
{
    __shared__ float sli[512];
    int bh = blockIdx.z, tid = threadIdx.x;
    int q0 = blockIdx.y * 512;
    for (int j = tid; j < 512; j += 256)
        sli[j] = 1.0f / rowsum[bh * 2048 + q0 + j];
    __syncthreads();

    int w = tid >> 6, lane = tid & 63, ln = lane & 15, quad = lane >> 4;
    int kb  = blockIdx.x * 256 + w * 64;
    int qt0 = blockIdx.y * 32;            // 32 q-tiles of 16
    const short* QH = Qhi + (size_t)bh * 2048 * 64;
    const short* QL = Qlo + (size_t)bh * 2048 * 64;
    const short* KH = Khi + (size_t)bh * 2048 * 64;
    const short* KL = Klo + (size_t)bh * 2048 * 64;

    short8 kh[4][2], kl[4][2];
#pragma unroll
    for (int nt = 0; nt < 4; nt++)
#pragma unroll
        for (int half = 0; half < 2; half++) {
            size_t o = (size_t)(kb + nt*16 + ln) * 64 + half*32 + quad*8;
            kh[nt][half] = *(const short8*)(KH + o);
            kl[nt][half] = *(const short8*)(KL + o);
        }

    short8 qh[2][2], ql[2][2];   // [buf][half]
    auto loadQ = [&](int buf, int qt) {
        size_t qo = (size_t)((qt0 + qt)*16 + ln) * 64 + quad*8;
        qh[buf][0] = *(const short8*)(QH + qo);
        qh[buf][1] = *(const short8*)(QH + qo + 32);
        ql[buf][0] = *(const short8*)(QL + qo);
        ql[buf][1] = *(const short8*)(QL + qo + 32);
    };

    float cacc[4] = {0.f, 0.f, 0.f, 0.f};
    auto comp = [&](int buf, int qt) {
#pragma unroll
        for (int nt = 0; nt < 4; nt++) {
            f32x4 c1 = (f32x4){0.f,0.f,0.f,0.f};
            f32x4 c2 = (f32x4){0.f,0.f,0.f,0.f};
            c1 = MFMA(qh[buf][0], kh[nt][0], c1); c1 = MFMA(qh[buf][1], kh[nt][1], c1);
            c2 = MFMA(qh[buf][0], kl[nt][0], c2); c2 = MFMA(qh[buf][1], kl[nt][1], c2);
            c2 = MFMA(ql[buf][0], kh[nt][0], c2); c2 = MFMA(ql[buf][1], kh[nt][1], c2);
#pragma unroll
            for (int i = 0; i < 4; i++) {
                int r = qt*16 + quad*4 + i;
                cacc[nt] += PEXP(c1[i] + c2[i]) * sli[r];
            }
        }
    };

    loadQ(0, 0);
    for (int qt = 0; qt < 32; qt += 2) {
        loadQ(1, qt + 1);
        comp(0, qt);
        if (qt + 2 < 32) loadQ(0, qt + 2);
        comp(1, qt + 1);
    }
#pragma unroll
    for (int nt = 0; nt < 4; nt++) {
        cacc[nt] += __shfl_xor(cacc[nt], 16, 64);
        cacc[nt] += __shfl_xor(cacc[nt], 32, 64);
        if (lane < 16) atomicAdd(&colsum[bh * 2048 + kb + nt*16 + lane], cacc[nt]);
    }
}

// Per (b,h): threshold = KEEP-th largest col_sum; mask = col_sum >= threshold.
__global__ __launch_bounds__(256) void topk_mask(
    const float* __restrict__ colsum, float* __restrict__ maskf)
{
    __shared__ unsigned keys[2048];
    __shared__ int cnt;
    int bh = blockIdx.x, tid = threadIdx.x;
    for (int j = tid; j < 2048; j += 256) {
        unsigned u = __float_as_uint(colsum[bh * 2048 + j]);
        keys[j] = (u & 0x80000000u) ? ~u : (u | 0x80000000u);
    }
    __syncthreads();
    unsigned long long lo = 0, hi = 0x100000000ULL;
    while (hi - lo > 1) {
        unsigned long long mid = (lo + hi) >> 1;
        if (tid == 0) cnt = 0;
        __syncthreads();
        int local = 0;
        for (int j = tid; j < 2048; j += 256) local += (keys[j] >= (unsigned)mid) ? 1 : 0;
        atomicAdd(&cnt, local);
        __syncthreads();
        int c = cnt;
        __syncthreads();
        if (c >= KEEP) lo = mid; else hi = mid;
    }
    unsigned thr = (unsigned)lo;
    for (int j = tid; j < 2048; j += 256)
        maskf[bh * 2048 + j] = (keys[j] >= thr) ? 1.0f : 0.0f;
}

// Vt[(bh*64+d)*2048+k] *= mask   (0/1 -> exact zeroing)
__global__ __launch_bounds__(256) void mask_v(
    unsigned short* __restrict__ Vt, const float* __restrict__ maskf)
{
    int i = blockIdx.x * 256 + threadIdx.x;   // short8 group
    int k8  = i & 255;
    int row = i >> 8;
    int bh  = row >> 6;
    const float* m = maskf + bh * 2048 + k8 * 8;
    short8 v = ((short8*)Vt)[i];
#pragma unroll
    for (int j = 0; j < 8; j++)
        if (m[j] == 0.0f) v[j] = 0;
    ((short8*)Vt)[i] = v;
}

// Flash-style PV, no block barriers (Pl per-wave LDS; in-order DS + fences).
// P = 2^c unnormalized; 1/rowsum applied in epilogue; V pre-masked.
// R9: wave owns 16 q-rows, grid (32, 32) -> 4 blocks/CU (was 2).
__global__ __launch_bounds__(256) void attn_av(
    const short* __restrict__ Qhi, const short* __restrict__ Khi,
    const short* __restrict__ Vt, const float* __restrict__ rowsum,
    unsigned short* __restrict__ concat)
{
    __shared__ __align__(16) short Pl[4][16][40];   // [wave][row][key+pad]
    int bh = blockIdx.y, tid = threadIdx.x;
    int w = tid >> 6, lane = tid & 63, ln = lane & 15, quad = lane >> 4;
    int qb = blockIdx.x * 64 + w * 16;
    const short* Q = Qhi + (size_t)bh * 2048 * 64;
    const short* K = Khi + (size_t)bh * 2048 * 64;
    const short* V = Vt  + (size_t)bh * 64 * 2048;

    short8 qh[2];
    float lrow[4];
#pragma unroll
    for (int half = 0; half < 2; half++)
        qh[half] = *(const short8*)(Q + (size_t)(qb + ln) * 64 + half*32 + quad*8);
#pragma unroll
    for (int i = 0; i < 4; i++)
        lrow[i] = 1.0f / rowsum[bh * 2048 + qb + quad*4 + i];

    f32x4 o[4];
#pragma unroll
    for (int nt = 0; nt < 4; nt++) o[nt] = (f32x4){0.f,0.f,0.f,0.f};

    short8 kb_[2][2][2];   // [buf][half][part]
    short8 vb_[2][4];      // [buf][nt]
    auto loadKV = [&](int buf, int kc) {
#pragma unroll
        for (int half = 0; half < 2; half++) {
            size_t ko = (size_t)(kc*32 + half*16 + ln) * 64 + quad*8;
            kb_[buf][half][0] = *(const short8*)(K + ko);
            kb_[buf][half][1] = *(const short8*)(K + ko + 32);
        }
#pragma unroll
        for (int nt = 0; nt < 4; nt++)
            vb_[buf][nt] = *(const short8*)(V + (size_t)(nt*16 + ln) * 2048 + kc*32 + quad*8);
    };
    auto comp = [&](int buf) {
#pragma unroll
        for (int half = 0; half < 2; half++) {
            f32x4 c = (f32x4){0.f,0.f,0.f,0.f};
            c = MFMA(qh[0], kb_[buf][half][0], c);
            c = MFMA(qh[1], kb_[buf][half][1], c);
#pragma unroll
            for (int i = 0; i < 4; i++)
                Pl[w][quad*4 + i][half*16 + ln] = (short)f2bf(PEXP(c[i]));
        }
        asm volatile("s_waitcnt lgkmcnt(0)" ::: "memory");
        short8 aP = *(const short8*)(&Pl[w][ln][quad*8]);
#pragma unroll
        for (int nt = 0; nt < 4; nt++)
            o[nt] = MFMA(aP, vb_[buf][nt], o[nt]);
        asm volatile("" ::: "memory");
    };

    loadKV(0, 0);
    for (int kc = 0; kc < 64; kc += 2) {
        loadKV(1, kc + 1);
        comp(0);
        if (kc + 2 < 64) loadKV(0, kc + 2);
        comp(1);
    }

    int b_ = bh >> 4, h = bh & 15;
#pragma unroll
    for (int nt = 0; nt < 4; nt++)
#pragma unroll
        for (int i = 0; i < 4; i++) {
            int qrow = qb + quad*4 + i;
            int col  = h*64 + nt*16 + ln;
            concat[((size_t)(b_*2048 + qrow)) * 1024 + col] =
                f2bf(o[nt][i] * lrow[i]);
        }
}

extern "C" void kernel_launch(void* const* d_in, const int* in_sizes, int n_in,
                              void* d_out, int out_size, void* d_ws, size_t ws_size,
                              hipStream_t stream)
{
    const float* q  = (const float*)d_in[0];
    const float* k  = (const float*)d_in[1];
    const float* v  = (const float*)d_in[2];
    const float* Wq = (const float*)d_in[3];
    const float* bq = (const float*)d_in[4];
    const float* Wk = (const float*)d_in[5];
    const float* bk = (const float*)d_in[6];
    const float* Wv = (const float*)d_in[7];
    const float* bv = (const float*)d_in[8];
    const float* Wo = (const float*)d_in[9];
    const float* bo = (const float*)d_in[10];

    char* ws = (char*)d_ws;
    size_t off = 0;
    auto alloc = [&](size_t bytes) -> void* {
        void* p = ws + off;
        off += (bytes + 255) & ~(size_t)255;
        return p;
    };
    const size_t ASZ = (size_t)4096 * 1024 * 2;   // 8.4 MB bf16 activation
    const size_t WSZ = (size_t)1024 * 1024 * 2;   // 2 MB bf16 weight
    unsigned short* qh_ = (unsigned short*)alloc(ASZ);
    unsigned short* ql_ = (unsigned short*)alloc(ASZ);
    unsigned short* kh_ = (unsigned short*)alloc(ASZ);
    unsigned short* kl_ = (unsigned short*)alloc(ASZ);
    unsigned short* vh_ = (unsigned short*)alloc(ASZ);
    unsigned short* vl_ = (unsigned short*)alloc(ASZ);
    unsigned short* wqh = (unsigned short*)alloc(WSZ);
    unsigned short* wql = (unsigned short*)alloc(WSZ);
    unsigned short* wkh = (unsigned short*)alloc(WSZ);
    unsigned short* wkl = (unsigned short*)alloc(WSZ);
    unsigned short* wvh = (unsigned short*)alloc(WSZ);
    unsigned short* wvl = (unsigned short*)alloc(WSZ);
    unsigned short* woh = (unsigned short*)alloc(WSZ);
    unsigned short* wol = (unsigned short*)alloc(WSZ);
    short* Qhi = (short*)alloc(ASZ);
    short* Qlo = (short*)alloc(ASZ);
    short* Khi = (short*)alloc(ASZ);
    short* Klo = (short*)alloc(ASZ);
    short* Vt  = (short*)alloc(ASZ);
    float* rowsum = (float*)alloc((size_t)32 * 2048 * 4);
    float* colsum = (float*)alloc((size_t)32 * 2048 * 4);
    float* maskf  = (float*)alloc((size_t)32 * 2048 * 4);
    unsigned short* concat = (unsigned short*)alloc(ASZ);
    // total ~118 MB (known-safe)

    dim3 blk(256);
    const int An4 = 4096 * 1024 / 4, Wn4 = 1024 * 1024 / 4;

    cvt_split<<<An4/256, blk, 0, stream>>>(q,  qh_, ql_, An4);
    cvt_split<<<An4/256, blk, 0, stream>>>(k,  kh_, kl_, An4);
    cvt_split<<<An4/256, blk, 0, stream>>>(v,  vh_, vl_, An4);
    cvt_split<<<Wn4/256, blk, 0, stream>>>(Wq, wqh, wql, Wn4);
    cvt_split<<<Wn4/256, blk, 0, stream>>>(Wk, wkh, wkl, Wn4);
    cvt_split<<<Wn4/256, blk, 0, stream>>>(Wv, wvh, wvl, Wn4);
    cvt_split<<<Wn4/256, blk, 0, stream>>>(Wo, woh, wol, Wn4);
    zero_f32 <<<dim3(512), blk, 0, stream>>>(rowsum, 2 * 32 * 2048);  // rowsum+colsum

    gemm_qkv<<<dim3(8, 32, 3), blk, 0, stream>>>(
        (const short*)qh_, (const short*)ql_, (const short*)kh_, (const short*)kl_,
        (const short*)vh_, (const short*)vl_,
        (const short*)wqh, (const short*)wql, (const short*)wkh, (const short*)wkl,
        (const short*)wvh, (const short*)wvl,
        bq, bk, bv,
        (unsigned short*)Qhi, (unsigned short*)Qlo,
        (unsigned short*)Khi, (unsigned short*)Klo, (unsigned short*)Vt);

    attn_rowsum<<<dim3(8, 4, 32), blk, 0, stream>>>(Qhi, Qlo, Khi, Klo, rowsum);
    attn_colsum<<<dim3(8, 4, 32), blk, 0, stream>>>(Qhi, Qlo, Khi, Klo, rowsum, colsum);
    topk_mask  <<<dim3(32),   blk, 0, stream>>>(colsum, maskf);
    mask_v     <<<dim3(2048), blk, 0, stream>>>((unsigned short*)Vt, maskf);
    attn_av    <<<dim3(32, 32), blk, 0, stream>>>(Qhi, Khi, Vt, rowsum, concat);

    gemm_out<<<dim3(8, 32), blk, 0, stream>>>((const short*)concat,
        (const short*)woh, (const short*)wol, bo, (float*)d_out);
}

// Round 2
// 616.252 us; speedup vs baseline: 1.1593x; 1.1593x over previous
//
#include <hip/hip_runtime.h>

// ---------------------------------------------------------------------------
// Pruned multi-head attention. fp32 I/O, split-bf16 (hi+lo) MFMA compute.
// B=2, S=2048, D_MODEL=1024, H=16, d_k=64, keep=int(2048*0.9)=1843
//
// Round 10: R9 (thin 16-row waves) regressed 2x — per-wave K/V traffic and
// chain iterations doubled while MFMA/iter halved. Reverted to the fat
// 32-row wave tile and instead added SPLIT-K (ksplit=2): each block handles
// 1024 keys, writing fp32 partial O; waves/CU 8 -> 16 with identical
// per-wave per-iteration work and unchanged total K/V traffic. av_combine
// sums the two partials, applies 1/rowsum, converts to bf16 concat.
// Partial buffer aliases the dead qh_..kl_ staging region (33.55 MB).
// ---------------------------------------------------------------------------

typedef __attribute__((ext_vector_type(8))) short short8;   // 8 bf16 (4 VGPRs)
typedef __attribute__((ext_vector_type(4))) short short4v;
typedef __attribute__((ext_vector_type(4))) float f32x4;

#define KEEP 1843

#if __has_builtin(__builtin_amdgcn_exp2f)
  #define PEXP(x) __builtin_amdgcn_exp2f(x)
  #define QSC 0.18033688011112042f   // log2(e)/8 folded into Q projection
#else
  #define PEXP(x) __expf(x)
  #define QSC 0.125f
#endif

#define AS1(p) ((const __attribute__((address_space(1))) void*)(p))
#define AS3(p) ((__attribute__((address_space(3))) void*)(p))

static __device__ __forceinline__ float bf2f(unsigned short s) {
    union { unsigned u; float f; } v; v.u = ((unsigned)s) << 16; return v.f;
}
static __device__ __forceinline__ unsigned short f2bf(float f) {
    union { float f; unsigned u; } v; v.f = f;
    unsigned u = v.u;
    unsigned r = (u + 0x7FFFu + ((u >> 16) & 1u)) >> 16;   // RNE
    return (unsigned short)r;
}

#define MFMA(A, B, C) __builtin_amdgcn_mfma_f32_16x16x32_bf16(A, B, C, 0, 0, 0)

// fp32 array -> hi/lo bf16 arrays (x = hi + lo to ~2^-17 relative)
__global__ __launch_bounds__(256) void cvt_split(
    const float* __restrict__ in, unsigned short* __restrict__ hi,
    unsigned short* __restrict__ lo, int n4)
{
    int i = blockIdx.x * 256 + threadIdx.x;
    if (i >= n4) return;
    f32x4 x = ((const f32x4*)in)[i];
    short4v h, l;
#pragma unroll
    for (int j = 0; j < 4; j++) {
        unsigned short hv = f2bf(x[j]);
        h[j] = (short)hv;
        l[j] = (short)f2bf(x[j] - bf2f(hv));
    }
    ((short4v*)hi)[i] = h;
    ((short4v*)lo)[i] = l;
}

__global__ __launch_bounds__(256) void zero_f32(float* __restrict__ p, int n) {
    int i = blockIdx.x * 256 + threadIdx.x;
    if (i < n) p[i] = 0.f;
}

// Fused Q/K/V projections, m97-style LDS staging. 128x128 tile, BK=32.
// z=0: Q -> bf16 hi+lo head layout, scaled QSC; z=1: K likewise; z=2: V -> V^T.
__global__ __launch_bounds__(256) void gemm_qkv(
    const short* __restrict__ A0, const short* __restrict__ Al0,
    const short* __restrict__ A1, const short* __restrict__ Al1,
    const short* __restrict__ A2, const short* __restrict__ Al2,
    const short* __restrict__ W0, const short* __restrict__ Wl0,
    const short* __restrict__ W1, const short* __restrict__ Wl1,
    const short* __restrict__ W2, const short* __restrict__ Wl2,
    const float* __restrict__ b0, const float* __restrict__ b1,
    const float* __restrict__ b2,
    unsigned short* __restrict__ Qhi, unsigned short* __restrict__ Qlo,
    unsigned short* __restrict__ Khi, unsigned short* __restrict__ Klo,
    unsigned short* __restrict__ Vt)
{
    int z = blockIdx.z;
    const short *Ahg, *Alg, *Whg, *Wlg; const float* bias;
    unsigned short *oh = 0, *ol = 0; float scale; int mode;
    if (z == 0)      { Ahg=A0; Alg=Al0; Whg=W0; Wlg=Wl0; bias=b0; oh=Qhi; ol=Qlo; scale=QSC;  mode=0; }
    else if (z == 1) { Ahg=A1; Alg=Al1; Whg=W1; Wlg=Wl1; bias=b1; oh=Khi; ol=Klo; scale=1.0f; mode=0; }
    else             { Ahg=A2; Alg=Al2; Whg=W2; Wlg=Wl2; bias=b2; oh=Vt;          scale=1.0f; mode=2; }

    __shared__ __align__(16) short Ah_l[128*32];
    __shared__ __align__(16) short Al_l[128*32];
    __shared__ __align__(16) short Wh_l[128*32];
    __shared__ __align__(16) short Wl_l[128*32];

    int tid  = threadIdx.x;
    int w    = tid >> 6;
    int lane = tid & 63;
    int ln   = lane & 15;
    int quad = lane >> 4;
    int rowBase = blockIdx.y * 128;
    int colBase = blockIdx.x * 128;
    int mBase = (w & 1) * 64;        // wave's quadrant inside 128x128
    int nBase = (w >> 1) * 64;

    // staging: wave w covers rows [w*32, w*32+32); lane -> row w*32+j*16+lane/4,
    // col (lane&3)*8; LDS dest = base + lane*16B (row-major [128][32]).
    int srow = (lane >> 2);
    int scol = (lane & 3) * 8;
    const short* Ag_h = Ahg + (size_t)rowBase * 1024;
    const short* Ag_l = Alg + (size_t)rowBase * 1024;
    const short* Wg_h = Whg + (size_t)colBase * 1024;
    const short* Wg_l = Wlg + (size_t)colBase * 1024;

    f32x4 acc[4][4];
#pragma unroll
    for (int i = 0; i < 4; i++)
#pragma unroll
        for (int j = 0; j < 4; j++) acc[i][j] = (f32x4){0.f, 0.f, 0.f, 0.f};

    for (int kk = 0; kk < 1024; kk += 32) {
#pragma unroll
        for (int j = 0; j < 2; j++) {
            int r = w*32 + j*16;
            size_t go = (size_t)(r + srow) * 1024 + kk + scol;
            __builtin_amdgcn_global_load_lds(AS1(Ag_h + go), AS3(Ah_l + r*32), 16, 0, 0);
            __builtin_amdgcn_global_load_lds(AS1(Ag_l + go), AS3(Al_l + r*32), 16, 0, 0);
            __builtin_amdgcn_global_load_lds(AS1(Wg_h + go), AS3(Wh_l + r*32), 16, 0, 0);
            __builtin_amdgcn_global_load_lds(AS1(Wg_l + go), AS3(Wl_l + r*32), 16, 0, 0);
        }
        __syncthreads();

        short8 ah[4], al[4], bh[4], bl[4];
#pragma unroll
        for (int mt = 0; mt < 4; mt++) {
            int r = mBase + mt*16 + ln;
            ah[mt] = *(const short8*)(Ah_l + r*32 + quad*8);
            al[mt] = *(const short8*)(Al_l + r*32 + quad*8);
        }
#pragma unroll
        for (int nt = 0; nt < 4; nt++) {
            int c = nBase + nt*16 + ln;
            bh[nt] = *(const short8*)(Wh_l + c*32 + quad*8);
            bl[nt] = *(const short8*)(Wl_l + c*32 + quad*8);
        }
#pragma unroll
        for (int mt = 0; mt < 4; mt++)
#pragma unroll
            for (int nt = 0; nt < 4; nt++) {
                acc[mt][nt] = MFMA(ah[mt], bh[nt], acc[mt][nt]);
                acc[mt][nt] = MFMA(ah[mt], bl[nt], acc[mt][nt]);
                acc[mt][nt] = MFMA(al[mt], bh[nt], acc[mt][nt]);
            }
        __syncthreads();
    }

#pragma unroll
    for (int mt = 0; mt < 4; mt++) {
#pragma unroll
        for (int nt = 0; nt < 4; nt++) {
            int col = colBase + nBase + nt*16 + ln;
            float bv = bias[col];
#pragma unroll
            for (int i = 0; i < 4; i++) {
                int row = rowBase + mBase + mt*16 + quad*4 + i;   // D: row=quad*4+reg
                float val = (acc[mt][nt][i] + bv) * scale;
                int b_  = row >> 11, s = row & 2047;
                int h   = col >> 6,  d = col & 63;
                int bh_ = b_ * 16 + h;
                if (mode == 2) {
                    oh[((size_t)bh_ * 64 + d) * 2048 + s] = f2bf(val);
                } else {
                    size_t idx = ((size_t)bh_ * 2048 + s) * 64 + d;
                    unsigned short hv = f2bf(val);
                    oh[idx] = hv;
                    ol[idx] = f2bf(val - bf2f(hv));
                }
            }
        }
    }
}

// out = concat(bf16) @ Wo^T + bo (split Wo, fp32 out), LDS-staged.
__global__ __launch_bounds__(256) void gemm_out(
    const short* __restrict__ Ag, const short* __restrict__ Whg,
    const short* __restrict__ Wlg, const float* __restrict__ bias,
    float* __restrict__ out)
{
    __shared__ __align__(16) short A_l[128*32];
    __shared__ __align__(16) short Wh_l[128*32];
    __shared__ __align__(16) short Wl_l[128*32];

    int tid  = threadIdx.x;
    int w    = tid >> 6;
    int lane = tid & 63;
    int ln   = lane & 15;
    int quad = lane >> 4;
    int rowBase = blockIdx.y * 128;
    int colBase = blockIdx.x * 128;
    int mBase = (w & 1) * 64;
    int nBase = (w >> 1) * 64;

    int srow = (lane >> 2);
    int scol = (lane & 3) * 8;
    const short* Abase = Ag  + (size_t)rowBase * 1024;
    const short* Whb   = Whg + (size_t)colBase * 1024;
    const short* Wlb   = Wlg + (size_t)colBase * 1024;

    f32x4 acc[4][4];
#pragma unroll
    for (int i = 0; i < 4; i++)
#pragma unroll
        for (int j = 0; j < 4; j++) acc[i][j] = (f32x4){0.f, 0.f, 0.f, 0.f};

    for (int kk = 0; kk < 1024; kk += 32) {
#pragma unroll
        for (int j = 0; j < 2; j++) {
            int r = w*32 + j*16;
            size_t go = (size_t)(r + srow) * 1024 + kk + scol;
            __builtin_amdgcn_global_load_lds(AS1(Abase + go), AS3(A_l  + r*32), 16, 0, 0);
            __builtin_amdgcn_global_load_lds(AS1(Whb   + go), AS3(Wh_l + r*32), 16, 0, 0);
            __builtin_amdgcn_global_load_lds(AS1(Wlb   + go), AS3(Wl_l + r*32), 16, 0, 0);
        }
        __syncthreads();

        short8 a[4], bh[4], bl[4];
#pragma unroll
        for (int mt = 0; mt < 4; mt++)
            a[mt] = *(const short8*)(A_l + (mBase + mt*16 + ln)*32 + quad*8);
#pragma unroll
        for (int nt = 0; nt < 4; nt++) {
            int c = nBase + nt*16 + ln;
            bh[nt] = *(const short8*)(Wh_l + c*32 + quad*8);
            bl[nt] = *(const short8*)(Wl_l + c*32 + quad*8);
        }
#pragma unroll
        for (int mt = 0; mt < 4; mt++)
#pragma unroll
            for (int nt = 0; nt < 4; nt++) {
                acc[mt][nt] = MFMA(a[mt], bh[nt], acc[mt][nt]);
                acc[mt][nt] = MFMA(a[mt], bl[nt], acc[mt][nt]);
            }
        __syncthreads();
    }

#pragma unroll
    for (int mt = 0; mt < 4; mt++) {
#pragma unroll
        for (int nt = 0; nt < 4; nt++) {
            int col = colBase + nBase + nt*16 + ln;
            float bv = bias[col];
#pragma unroll
            for (int i = 0; i < 4; i++) {
                int row = rowBase + mBase + mt*16 + quad*4 + i;
                out[(size_t)row * 1024 + col] = acc[mt][nt][i] + bv;
            }
        }
    }
}

// rowsum[q] += sum over this block's k-quarter of 2^(c_qk).  Split-precision.
// Wave owns 64 q rows (4 m-tiles). grid (8 qblocks, 4 ksplit, 32 bh).
__global__ __launch_bounds__(256) void attn_rowsum(
    const short* __restrict__ Qhi, const short* __restrict__ Qlo,
    const short* __restrict__ Khi, const short* __restrict__ Klo,
    float* __restrict__ rowsum)
{
    int bh = blockIdx.z, tid = threadIdx.x;
    int w = tid >> 6, lane = tid & 63, ln = lane & 15, quad = lane >> 4;
    int qb  = blockIdx.x * 256 + w * 64;
    int kt0 = blockIdx.y * 32;            // 32 k-tiles of 16 = 512 keys
    const short* QH = Qhi + (size_t)bh * 2048 * 64;
    const short* QL = Qlo + (size_t)bh * 2048 * 64;
    const short* KH = Khi + (size_t)bh * 2048 * 64;
    const short* KL = Klo + (size_t)bh * 2048 * 64;

    short8 qh[4][2], ql[4][2];
#pragma unroll
    for (int mt = 0; mt < 4; mt++)
#pragma unroll
        for (int half = 0; half < 2; half++) {
            size_t o = (size_t)(qb + mt*16 + ln) * 64 + half*32 + quad*8;
            qh[mt][half] = *(const short8*)(QH + o);
            ql[mt][half] = *(const short8*)(QL + o);
        }

    short8 kh[2][2], kl[2][2];   // [buf][dchunk]
    auto loadK = [&](int buf, int kt) {
        size_t ko = (size_t)(kt*16 + ln) * 64 + quad*8;
        kh[buf][0] = *(const short8*)(KH + ko);
        kh[buf][1] = *(const short8*)(KH + ko + 32);
        kl[buf][0] = *(const short8*)(KL + ko);
        kl[buf][1] = *(const short8*)(KL + ko + 32);
    };

    float racc[4][4] = {};
    auto comp = [&](int buf) {
#pragma unroll
        for (int mt = 0; mt < 4; mt++) {
            f32x4 c1 = (f32x4){0.f,0.f,0.f,0.f};
            f32x4 c2 = (f32x4){0.f,0.f,0.f,0.f};
            c1 = MFMA(qh[mt][0], kh[buf][0], c1); c1 = MFMA(qh[mt][1], kh[buf][1], c1);
            c2 = MFMA(qh[mt][0], kl[buf][0], c2); c2 = MFMA(qh[mt][1], kl[buf][1], c2);
            c2 = MFMA(ql[mt][0], kh[buf][0], c2); c2 = MFMA(ql[mt][1], kh[buf][1], c2);
#pragma unroll
            for (int i = 0; i < 4; i++)
                racc[mt][i] += PEXP(c1[i] + c2[i]);
        }
    };

    loadK(0, kt0);
    for (int t = 0; t < 32; t += 2) {
        loadK(1, kt0 + t + 1);
        comp(0);
        if (t + 2 < 32) loadK(0, kt0 + t + 2);
        comp(1);
    }
#pragma unroll
    for (int mt = 0; mt < 4; mt++)
#pragma unroll
        for (int i = 0; i < 4; i++)
            for (int d = 1; d < 16; d <<= 1)
                racc[mt][i] += __shfl_xor(racc[mt][i], d, 64);
    if (ln == 0) {
#pragma unroll
        for (int mt = 0; mt < 4; mt++)
#pragma unroll
            for (int i = 0; i < 4; i++)
                atomicAdd(&rowsum[bh * 2048 + qb + mt*16 + quad*4 + i], racc[mt][i]);
    }
}

// colsum[k] += sum over this block's q-quarter of 2^(c_qk)/rowsum[q].
// Wave owns 64 keys (4 n-tiles). grid (8 kblocks, 4 qsplit, 32 bh).
__global__ __launch_bounds__(256) void attn_colsum(
    const short* __restrict__ Qhi, const short* __restrict__ Qlo,
    const short* __restrict__ Khi, const short* __restrict__ Klo,
    const float* __restrict__ rowsum, float* __restrict__ colsum)
{
    __shared__ float sli[512];
    int bh = blockIdx.z, tid = threadIdx.x;
    int q0 = blockIdx.y * 512;
    for (int j = tid; j < 512; j += 256)
        sli[j] = 1.0f / rowsum[bh * 2048 + q0 + j];
    __syncthreads();

    int w = tid >> 6, lane = tid & 63, ln = lane & 15, quad = lane >> 4;
    int kb  = blockIdx.x * 256 + w * 64;
    int qt0 = blockIdx.y * 32;            // 32 q-tiles of 16
    const short* QH = Qhi + (size_t)bh * 2048 * 64;
    const short* QL = Qlo + (size_t)bh * 2048 * 64;
    const short* KH = Khi + (size_t)bh * 2048 * 64;
    const short* KL = Klo + (size_t)bh * 2048 * 64;

    short8 kh[4][2], kl[4][2];
#pragma unroll
    for (int nt = 0; nt < 4; nt++)
#pragma unroll
        for (int half = 0; half < 2; half++) {
            size_t o = (size_t)(kb + nt*16 + ln) * 64 + half*32 + quad*8;
            kh[nt][half] = *(const short8*)(KH + o);
            kl[nt][half] = *(const short8*)(KL + o);
        }

    short8 qh[2][2], ql[2][2];   // [buf][half]
    auto loadQ = [&](int buf, int qt) {
        size_t qo = (size_t)((qt0 + qt)*16 + ln) * 64 + quad*8;
        qh[buf][0] = *(const short8*)(QH + qo);
        qh[buf][1] = *(const short8*)(QH + qo + 32);
        ql[buf][0] = *(const short8*)(QL + qo);
        ql[buf][1] = *(const short8*)(QL + qo + 32);
    };

    float cacc[4] = {0.f, 0.f, 0.f, 0.f};
    auto comp = [&](int buf, int qt) {
#pragma unroll
        for (int nt = 0; nt < 4; nt++) {
            f32x4 c1 = (f32x4){0.f,0.f,0.f,0.f};
            f32x4 c2 = (f32x4){0.f,0.f,0.f,0.f};
            c1 = MFMA(qh[buf][0], kh[nt][0], c1); c1 = MFMA(qh[buf][1], kh[nt][1], c1);
            c2 = MFMA(qh[buf][0], kl[nt][0], c2); c2 = MFMA(qh[buf][1], kl[nt][1], c2);
            c2 = MFMA(ql[buf][0], kh[nt][0], c2); c2 = MFMA(ql[buf][1], kh[nt][1], c2);
#pragma unroll
            for (int i = 0; i < 4; i++) {
                int r = qt*16 + quad*4 + i;
                cacc[nt] += PEXP(c1[i] + c2[i]) * sli[r];
            }
        }
    };

    loadQ(0, 0);
    for (int qt = 0; qt < 32; qt += 2) {
        loadQ(1, qt + 1);
        comp(0, qt);
        if (qt + 2 < 32) loadQ(0, qt + 2);
        comp(1, qt + 1);
    }
#pragma unroll
    for (int nt = 0; nt < 4; nt++) {
        cacc[nt] += __shfl_xor(cacc[nt], 16, 64);
        cacc[nt] += __shfl_xor(cacc[nt], 32, 64);
        if (lane < 16) atomicAdd(&colsum[bh * 2048 + kb + nt*16 + lane], cacc[nt]);
    }
}

// Per (b,h): threshold = KEEP-th largest col_sum; mask = col_sum >= threshold.
__global__ __launch_bounds__(256) void topk_mask(
    const float* __restrict__ colsum, float* __restrict__ maskf)
{
    __shared__ unsigned keys[2048];
    __shared__ int cnt;
    int bh = blockIdx.x, tid = threadIdx.x;
    for (int j = tid; j < 2048; j += 256) {
        unsigned u = __float_as_uint(colsum[bh * 2048 + j]);
        keys[j] = (u & 0x80000000u) ? ~u : (u | 0x80000000u);
    }
    __syncthreads();
    unsigned long long lo = 0, hi = 0x100000000ULL;
    while (hi - lo > 1) {
        unsigned long long mid = (lo + hi) >> 1;
        if (tid == 0) cnt = 0;
        __syncthreads();
        int local = 0;
        for (int j = tid; j < 2048; j += 256) local += (keys[j] >= (unsigned)mid) ? 1 : 0;
        atomicAdd(&cnt, local);
        __syncthreads();
        int c = cnt;
        __syncthreads();
        if (c >= KEEP) lo = mid; else hi = mid;
    }
    unsigned thr = (unsigned)lo;
    for (int j = tid; j < 2048; j += 256)
        maskf[bh * 2048 + j] = (keys[j] >= thr) ? 1.0f : 0.0f;
}

// Vt[(bh*64+d)*2048+k] *= mask   (0/1 -> exact zeroing)
__global__ __launch_bounds__(256) void mask_v(
    unsigned short* __restrict__ Vt, const float* __restrict__ maskf)
{
    int i = blockIdx.x * 256 + threadIdx.x;   // short8 group
    int k8  = i & 255;
    int row = i >> 8;
    int bh  = row >> 6;
    const float* m = maskf + bh * 2048 + k8 * 8;
    short8 v = ((short8*)Vt)[i];
#pragma unroll
    for (int j = 0; j < 8; j++)
        if (m[j] == 0.0f) v[j] = 0;
    ((short8*)Vt)[i] = v;
}

// Flash-style PV, no block barriers (Pl per-wave LDS; in-order DS + fences).
// P = 2^c unnormalized; V pre-masked. Split-K: blockIdx.z = half of key range.
// fp32 partial O written to workspace; av_combine applies 1/rowsum + bf16.
__global__ __launch_bounds__(256) void attn_av(
    const short* __restrict__ Qhi, const short* __restrict__ Khi,
    const short* __restrict__ Vt,
    float* __restrict__ partial)
{
    __shared__ __align__(16) short Pl[4][2][16][40];   // [wave][mt][row][key+pad]
    int bh = blockIdx.y, tid = threadIdx.x;
    int ks = blockIdx.z;
    int w = tid >> 6, lane = tid & 63, ln = lane & 15, quad = lane >> 4;
    int qb = blockIdx.x * 128 + w * 32;
    const short* Q = Qhi + (size_t)bh * 2048 * 64;
    const short* K = Khi + (size_t)bh * 2048 * 64;
    const short* V = Vt  + (size_t)bh * 64 * 2048;

    short8 qh[2][2];
#pragma unroll
    for (int mt = 0; mt < 2; mt++)
#pragma unroll
        for (int half = 0; half < 2; half++)
            qh[mt][half] = *(const short8*)(Q + (size_t)(qb + mt*16 + ln) * 64 + half*32 + quad*8);

    f32x4 o[2][4];
#pragma unroll
    for (int mt = 0; mt < 2; mt++)
#pragma unroll
        for (int nt = 0; nt < 4; nt++) o[mt][nt] = (f32x4){0.f,0.f,0.f,0.f};

    short8 kb_[2][2][2];   // [buf][half][part]
    short8 vb_[2][4];      // [buf][nt]
    auto loadKV = [&](int buf, int kc) {
#pragma unroll
        for (int half = 0; half < 2; half++) {
            size_t ko = (size_t)(kc*32 + half*16 + ln) * 64 + quad*8;
            kb_[buf][half][0] = *(const short8*)(K + ko);
            kb_[buf][half][1] = *(const short8*)(K + ko + 32);
        }
#pragma unroll
        for (int nt = 0; nt < 4; nt++)
            vb_[buf][nt] = *(const short8*)(V + (size_t)(nt*16 + ln) * 2048 + kc*32 + quad*8);
    };
    auto comp = [&](int buf) {
#pragma unroll
        for (int half = 0; half < 2; half++)
#pragma unroll
            for (int mt = 0; mt < 2; mt++) {
                f32x4 c = (f32x4){0.f,0.f,0.f,0.f};
                c = MFMA(qh[mt][0], kb_[buf][half][0], c);
                c = MFMA(qh[mt][1], kb_[buf][half][1], c);
#pragma unroll
                for (int i = 0; i < 4; i++)
                    Pl[w][mt][quad*4 + i][half*16 + ln] = (short)f2bf(PEXP(c[i]));
            }
        asm volatile("s_waitcnt lgkmcnt(0)" ::: "memory");
        short8 aP[2];
#pragma unroll
        for (int mt = 0; mt < 2; mt++)
            aP[mt] = *(const short8*)(&Pl[w][mt][ln][quad*8]);
#pragma unroll
        for (int nt = 0; nt < 4; nt++)
#pragma unroll
            for (int mt = 0; mt < 2; mt++)
                o[mt][nt] = MFMA(aP[mt], vb_[buf][nt], o[mt][nt]);
        asm volatile("" ::: "memory");
    };

    int kc0 = ks * 32;                 // this block's 32 key-chunks (1024 keys)
    loadKV(0, kc0);
    for (int kc = 0; kc < 32; kc += 2) {
        loadKV(1, kc0 + kc + 1);
        comp(0);
        if (kc + 2 < 32) loadKV(0, kc0 + kc + 2);
        comp(1);
    }

    float* P = partial + ((size_t)(ks * 32 + bh) * 2048) * 64;
#pragma unroll
    for (int mt = 0; mt < 2; mt++)
#pragma unroll
        for (int nt = 0; nt < 4; nt++)
#pragma unroll
            for (int i = 0; i < 4; i++) {
                int qrow = qb + mt*16 + quad*4 + i;
                P[(size_t)qrow * 64 + nt*16 + ln] = o[mt][nt][i];
            }
}

// concat[b,q,h*64+d] = bf16( (partial0 + partial1) * (1/rowsum) )
__global__ __launch_bounds__(256) void av_combine(
    const float* __restrict__ partial, const float* __restrict__ rowsum,
    unsigned short* __restrict__ concat)
{
    int i = blockIdx.x * 256 + threadIdx.x;   // f32x4 group; 32*2048*64/4 total
    int d4 = i & 15;                          // which 4-wide d chunk
    int q  = (i >> 4) & 2047;
    int bh = i >> 15;
    f32x4 a = ((const f32x4*)partial)[i];
    f32x4 b = ((const f32x4*)(partial + (size_t)32 * 2048 * 64))[i];
    float inv = 1.0f / rowsum[bh * 2048 + q];
    int b_ = bh >> 4, h = bh & 15;
    short4v r;
#pragma unroll
    for (int j = 0; j < 4; j++)
        r[j] = (short)f2bf((a[j] + b[j]) * inv);
    *(short4v*)(concat + ((size_t)(b_*2048 + q)) * 1024 + h*64 + d4*4) = r;
}

extern "C" void kernel_launch(void* const* d_in, const int* in_sizes, int n_in,
                              void* d_out, int out_size, void* d_ws, size_t ws_size,
                              hipStream_t stream)
{
    const float* q  = (const float*)d_in[0];
    const float* k  = (const float*)d_in[1];
    const float* v  = (const float*)d_in[2];
    const float* Wq = (const float*)d_in[3];
    const float* bq = (const float*)d_in[4];
    const float* Wk = (const float*)d_in[5];
    const float* bk = (const float*)d_in[6];
    const float* Wv = (const float*)d_in[7];
    const float* bv = (const float*)d_in[8];
    const float* Wo = (const float*)d_in[9];
    const float* bo = (const float*)d_in[10];

    char* ws = (char*)d_ws;
    size_t off = 0;
    auto alloc = [&](size_t bytes) -> void* {
        void* p = ws + off;
        off += (bytes + 255) & ~(size_t)255;
        return p;
    };
    const size_t ASZ = (size_t)4096 * 1024 * 2;   // 8.4 MB bf16 activation
    const size_t WSZ = (size_t)1024 * 1024 * 2;   // 2 MB bf16 weight
    unsigned short* qh_ = (unsigned short*)alloc(ASZ);
    unsigned short* ql_ = (unsigned short*)alloc(ASZ);
    unsigned short* kh_ = (unsigned short*)alloc(ASZ);
    unsigned short* kl_ = (unsigned short*)alloc(ASZ);
    unsigned short* vh_ = (unsigned short*)alloc(ASZ);
    unsigned short* vl_ = (unsigned short*)alloc(ASZ);
    unsigned short* wqh = (unsigned short*)alloc(WSZ);
    unsigned short* wql = (unsigned short*)alloc(WSZ);
    unsigned short* wkh = (unsigned short*)alloc(WSZ);
    unsigned short* wkl = (unsigned short*)alloc(WSZ);
    unsigned short* wvh = (unsigned short*)alloc(WSZ);
    unsigned short* wvl = (unsigned short*)alloc(WSZ);
    unsigned short* woh = (unsigned short*)alloc(WSZ);
    unsigned short* wol = (unsigned short*)alloc(WSZ);
    short* Qhi = (short*)alloc(ASZ);
    short* Qlo = (short*)alloc(ASZ);
    short* Khi = (short*)alloc(ASZ);
    short* Klo = (short*)alloc(ASZ);
    short* Vt  = (short*)alloc(ASZ);
    float* rowsum = (float*)alloc((size_t)32 * 2048 * 4);
    float* colsum = (float*)alloc((size_t)32 * 2048 * 4);
    float* maskf  = (float*)alloc((size_t)32 * 2048 * 4);
    unsigned short* concat = (unsigned short*)alloc(ASZ);
    // total ~118 MB (known-safe)

    // Split-K partial O (2 x 32 x 2048 x 64 fp32 = 33.55 MB) aliases the
    // qh_..kl_ staging region (4 x 8.39 MB contiguous), dead after gemm_qkv.
    float* partial = (float*)qh_;

    dim3 blk(256);
    const int An4 = 4096 * 1024 / 4, Wn4 = 1024 * 1024 / 4;

    cvt_split<<<An4/256, blk, 0, stream>>>(q,  qh_, ql_, An4);
    cvt_split<<<An4/256, blk, 0, stream>>>(k,  kh_, kl_, An4);
    cvt_split<<<An4/256, blk, 0, stream>>>(v,  vh_, vl_, An4);
    cvt_split<<<Wn4/256, blk, 0, stream>>>(Wq, wqh, wql, Wn4);
    cvt_split<<<Wn4/256, blk, 0, stream>>>(Wk, wkh, wkl, Wn4);
    cvt_split<<<Wn4/256, blk, 0, stream>>>(Wv, wvh, wvl, Wn4);
    cvt_split<<<Wn4/256, blk, 0, stream>>>(Wo, woh, wol, Wn4);
    zero_f32 <<<dim3(512), blk, 0, stream>>>(rowsum, 2 * 32 * 2048);  // rowsum+colsum

    gemm_qkv<<<dim3(8, 32, 3), blk, 0, stream>>>(
        (const short*)qh_, (const short*)ql_, (const short*)kh_, (const short*)kl_,
        (const short*)vh_, (const short*)vl_,
        (const short*)wqh, (const short*)wql, (const short*)wkh, (const short*)wkl,
        (const short*)wvh, (const short*)wvl,
        bq, bk, bv,
        (unsigned short*)Qhi, (unsigned short*)Qlo,
        (unsigned short*)Khi, (unsigned short*)Klo, (unsigned short*)Vt);

    attn_rowsum<<<dim3(8, 4, 32), blk, 0, stream>>>(Qhi, Qlo, Khi, Klo, rowsum);
    attn_colsum<<<dim3(8, 4, 32), blk, 0, stream>>>(Qhi, Qlo, Khi, Klo, rowsum, colsum);
    topk_mask  <<<dim3(32),   blk, 0, stream>>>(colsum, maskf);
    mask_v     <<<dim3(2048), blk, 0, stream>>>((unsigned short*)Vt, maskf);
    attn_av    <<<dim3(16, 32, 2), blk, 0, stream>>>(Qhi, Khi, Vt, partial);
    av_combine <<<dim3(4096), blk, 0, stream>>>(partial, rowsum, concat);

    gemm_out<<<dim3(8, 32), blk, 0, stream>>>((const short*)concat,
        (const short*)woh, (const short*)wol, bo, (float*)d_out);
}

// Round 3
// 610.567 us; speedup vs baseline: 1.1701x; 1.0093x over previous
//
#include <hip/hip_runtime.h>

// ---------------------------------------------------------------------------
// Pruned multi-head attention. fp32 I/O, split-bf16 (hi+lo) MFMA compute.
// B=2, S=2048, D_MODEL=1024, H=16, d_k=64, keep=int(2048*0.9)=1843
//
// Round 11: attn_av rewritten with swapped-operand QK^T (S^T = K·Q^T via
// mfma_32x32x16) so P is lane-local: exp2 -> v_cvt_pk_bf16_f32 ->
// v_permlane32_swap_b32 feeds the PV A-fragment directly. Eliminates the
// per-chunk LDS round trip (16 ds_write_b16 + lgkmcnt(0) + ds_read_b128)
// and ~80 VALU ops of hand-RNE per chunk. R9/R10 proved occupancy isn't
// the limiter (2x waves = 0 speedup); the serial chunk pipeline was.
// Split-K + av_combine reverted (perf-neutral, +8us combine cost).
// ---------------------------------------------------------------------------

typedef __attribute__((ext_vector_type(8))) short short8;   // 8 bf16 (4 VGPRs)
typedef __attribute__((ext_vector_type(4))) short short4v;
typedef __attribute__((ext_vector_type(4))) float f32x4;
typedef __attribute__((ext_vector_type(16))) float f32x16;
typedef __attribute__((ext_vector_type(4))) unsigned int u32x4;

#define KEEP 1843

#if __has_builtin(__builtin_amdgcn_exp2f)
  #define PEXP(x) __builtin_amdgcn_exp2f(x)
  #define QSC 0.18033688011112042f   // log2(e)/8 folded into Q projection
#else
  #define PEXP(x) __expf(x)
  #define QSC 0.125f
#endif

#define AS1(p) ((const __attribute__((address_space(1))) void*)(p))
#define AS3(p) ((__attribute__((address_space(3))) void*)(p))

static __device__ __forceinline__ float bf2f(unsigned short s) {
    union { unsigned u; float f; } v; v.u = ((unsigned)s) << 16; return v.f;
}
static __device__ __forceinline__ unsigned short f2bf(float f) {
    union { float f; unsigned u; } v; v.f = f;
    unsigned u = v.u;
    unsigned r = (u + 0x7FFFu + ((u >> 16) & 1u)) >> 16;   // RNE
    return (unsigned short)r;
}

#define MFMA(A, B, C)   __builtin_amdgcn_mfma_f32_16x16x32_bf16(A, B, C, 0, 0, 0)
#define MFMA32(A, B, C) __builtin_amdgcn_mfma_f32_32x32x16_bf16(A, B, C, 0, 0, 0)

// fp32 array -> hi/lo bf16 arrays (x = hi + lo to ~2^-17 relative)
__global__ __launch_bounds__(256) void cvt_split(
    const float* __restrict__ in, unsigned short* __restrict__ hi,
    unsigned short* __restrict__ lo, int n4)
{
    int i = blockIdx.x * 256 + threadIdx.x;
    if (i >= n4) return;
    f32x4 x = ((const f32x4*)in)[i];
    short4v h, l;
#pragma unroll
    for (int j = 0; j < 4; j++) {
        unsigned short hv = f2bf(x[j]);
        h[j] = (short)hv;
        l[j] = (short)f2bf(x[j] - bf2f(hv));
    }
    ((short4v*)hi)[i] = h;
    ((short4v*)lo)[i] = l;
}

__global__ __launch_bounds__(256) void zero_f32(float* __restrict__ p, int n) {
    int i = blockIdx.x * 256 + threadIdx.x;
    if (i < n) p[i] = 0.f;
}

// Fused Q/K/V projections, m97-style LDS staging. 128x128 tile, BK=32.
// z=0: Q -> bf16 hi+lo head layout, scaled QSC; z=1: K likewise; z=2: V -> V^T.
__global__ __launch_bounds__(256) void gemm_qkv(
    const short* __restrict__ A0, const short* __restrict__ Al0,
    const short* __restrict__ A1, const short* __restrict__ Al1,
    const short* __restrict__ A2, const short* __restrict__ Al2,
    const short* __restrict__ W0, const short* __restrict__ Wl0,
    const short* __restrict__ W1, const short* __restrict__ Wl1,
    const short* __restrict__ W2, const short* __restrict__ Wl2,
    const float* __restrict__ b0, const float* __restrict__ b1,
    const float* __restrict__ b2,
    unsigned short* __restrict__ Qhi, unsigned short* __restrict__ Qlo,
    unsigned short* __restrict__ Khi, unsigned short* __restrict__ Klo,
    unsigned short* __restrict__ Vt)
{
    int z = blockIdx.z;
    const short *Ahg, *Alg, *Whg, *Wlg; const float* bias;
    unsigned short *oh = 0, *ol = 0; float scale; int mode;
    if (z == 0)      { Ahg=A0; Alg=Al0; Whg=W0; Wlg=Wl0; bias=b0; oh=Qhi; ol=Qlo; scale=QSC;  mode=0; }
    else if (z == 1) { Ahg=A1; Alg=Al1; Whg=W1; Wlg=Wl1; bias=b1; oh=Khi; ol=Klo; scale=1.0f; mode=0; }
    else             { Ahg=A2; Alg=Al2; Whg=W2; Wlg=Wl2; bias=b2; oh=Vt;          scale=1.0f; mode=2; }

    __shared__ __align__(16) short Ah_l[128*32];
    __shared__ __align__(16) short Al_l[128*32];
    __shared__ __align__(16) short Wh_l[128*32];
    __shared__ __align__(16) short Wl_l[128*32];

    int tid  = threadIdx.x;
    int w    = tid >> 6;
    int lane = tid & 63;
    int ln   = lane & 15;
    int quad = lane >> 4;
    int rowBase = blockIdx.y * 128;
    int colBase = blockIdx.x * 128;
    int mBase = (w & 1) * 64;        // wave's quadrant inside 128x128
    int nBase = (w >> 1) * 64;

    // staging: wave w covers rows [w*32, w*32+32); lane -> row w*32+j*16+lane/4,
    // col (lane&3)*8; LDS dest = base + lane*16B (row-major [128][32]).
    int srow = (lane >> 2);
    int scol = (lane & 3) * 8;
    const short* Ag_h = Ahg + (size_t)rowBase * 1024;
    const short* Ag_l = Alg + (size_t)rowBase * 1024;
    const short* Wg_h = Whg + (size_t)colBase * 1024;
    const short* Wg_l = Wlg + (size_t)colBase * 1024;

    f32x4 acc[4][4];
#pragma unroll
    for (int i = 0; i < 4; i++)
#pragma unroll
        for (int j = 0; j < 4; j++) acc[i][j] = (f32x4){0.f, 0.f, 0.f, 0.f};

    for (int kk = 0; kk < 1024; kk += 32) {
#pragma unroll
        for (int j = 0; j < 2; j++) {
            int r = w*32 + j*16;
            size_t go = (size_t)(r + srow) * 1024 + kk + scol;
            __builtin_amdgcn_global_load_lds(AS1(Ag_h + go), AS3(Ah_l + r*32), 16, 0, 0);
            __builtin_amdgcn_global_load_lds(AS1(Ag_l + go), AS3(Al_l + r*32), 16, 0, 0);
            __builtin_amdgcn_global_load_lds(AS1(Wg_h + go), AS3(Wh_l + r*32), 16, 0, 0);
            __builtin_amdgcn_global_load_lds(AS1(Wg_l + go), AS3(Wl_l + r*32), 16, 0, 0);
        }
        __syncthreads();

        short8 ah[4], al[4], bh[4], bl[4];
#pragma unroll
        for (int mt = 0; mt < 4; mt++) {
            int r = mBase + mt*16 + ln;
            ah[mt] = *(const short8*)(Ah_l + r*32 + quad*8);
            al[mt] = *(const short8*)(Al_l + r*32 + quad*8);
        }
#pragma unroll
        for (int nt = 0; nt < 4; nt++) {
            int c = nBase + nt*16 + ln;
            bh[nt] = *(const short8*)(Wh_l + c*32 + quad*8);
            bl[nt] = *(const short8*)(Wl_l + c*32 + quad*8);
        }
#pragma unroll
        for (int mt = 0; mt < 4; mt++)
#pragma unroll
            for (int nt = 0; nt < 4; nt++) {
                acc[mt][nt] = MFMA(ah[mt], bh[nt], acc[mt][nt]);
                acc[mt][nt] = MFMA(ah[mt], bl[nt], acc[mt][nt]);
                acc[mt][nt] = MFMA(al[mt], bh[nt], acc[mt][nt]);
            }
        __syncthreads();
    }

#pragma unroll
    for (int mt = 0; mt < 4; mt++) {
#pragma unroll
        for (int nt = 0; nt < 4; nt++) {
            int col = colBase + nBase + nt*16 + ln;
            float bv = bias[col];
#pragma unroll
            for (int i = 0; i < 4; i++) {
                int row = rowBase + mBase + mt*16 + quad*4 + i;   // D: row=quad*4+reg
                float val = (acc[mt][nt][i] + bv) * scale;
                int b_  = row >> 11, s = row & 2047;
                int h   = col >> 6,  d = col & 63;
                int bh_ = b_ * 16 + h;
                if (mode == 2) {
                    oh[((size_t)bh_ * 64 + d) * 2048 + s] = f2bf(val);
                } else {
                    size_t idx = ((size_t)bh_ * 2048 + s) * 64 + d;
                    unsigned short hv = f2bf(val);
                    oh[idx] = hv;
                    ol[idx] = f2bf(val - bf2f(hv));
                }
            }
        }
    }
}

// out = concat(bf16) @ Wo^T + bo (split Wo, fp32 out), LDS-staged.
__global__ __launch_bounds__(256) void gemm_out(
    const short* __restrict__ Ag, const short* __restrict__ Whg,
    const short* __restrict__ Wlg, const float* __restrict__ bias,
    float* __restrict__ out)
{
    __shared__ __align__(16) short A_l[128*32];
    __shared__ __align__(16) short Wh_l[128*32];
    __shared__ __align__(16) short Wl_l[128*32];

    int tid  = threadIdx.x;
    int w    = tid >> 6;
    int lane = tid & 63;
    int ln   = lane & 15;
    int quad = lane >> 4;
    int rowBase = blockIdx.y * 128;
    int colBase = blockIdx.x * 128;
    int mBase = (w & 1) * 64;
    int nBase = (w >> 1) * 64;

    int srow = (lane >> 2);
    int scol = (lane & 3) * 8;
    const short* Abase = Ag  + (size_t)rowBase * 1024;
    const short* Whb   = Whg + (size_t)colBase * 1024;
    const short* Wlb   = Wlg + (size_t)colBase * 1024;

    f32x4 acc[4][4];
#pragma unroll
    for (int i = 0; i < 4; i++)
#pragma unroll
        for (int j = 0; j < 4; j++) acc[i][j] = (f32x4){0.f, 0.f, 0.f, 0.f};

    for (int kk = 0; kk < 1024; kk += 32) {
#pragma unroll
        for (int j = 0; j < 2; j++) {
            int r = w*32 + j*16;
            size_t go = (size_t)(r + srow) * 1024 + kk + scol;
            __builtin_amdgcn_global_load_lds(AS1(Abase + go), AS3(A_l  + r*32), 16, 0, 0);
            __builtin_amdgcn_global_load_lds(AS1(Whb   + go), AS3(Wh_l + r*32), 16, 0, 0);
            __builtin_amdgcn_global_load_lds(AS1(Wlb   + go), AS3(Wl_l + r*32), 16, 0, 0);
        }
        __syncthreads();

        short8 a[4], bh[4], bl[4];
#pragma unroll
        for (int mt = 0; mt < 4; mt++)
            a[mt] = *(const short8*)(A_l + (mBase + mt*16 + ln)*32 + quad*8);
#pragma unroll
        for (int nt = 0; nt < 4; nt++) {
            int c = nBase + nt*16 + ln;
            bh[nt] = *(const short8*)(Wh_l + c*32 + quad*8);
            bl[nt] = *(const short8*)(Wl_l + c*32 + quad*8);
        }
#pragma unroll
        for (int mt = 0; mt < 4; mt++)
#pragma unroll
            for (int nt = 0; nt < 4; nt++) {
                acc[mt][nt] = MFMA(a[mt], bh[nt], acc[mt][nt]);
                acc[mt][nt] = MFMA(a[mt], bl[nt], acc[mt][nt]);
            }
        __syncthreads();
    }

#pragma unroll
    for (int mt = 0; mt < 4; mt++) {
#pragma unroll
        for (int nt = 0; nt < 4; nt++) {
            int col = colBase + nBase + nt*16 + ln;
            float bv = bias[col];
#pragma unroll
            for (int i = 0; i < 4; i++) {
                int row = rowBase + mBase + mt*16 + quad*4 + i;
                out[(size_t)row * 1024 + col] = acc[mt][nt][i] + bv;
            }
        }
    }
}

// rowsum[q] += sum over this block's k-quarter of 2^(c_qk).  Split-precision.
// Wave owns 64 q rows (4 m-tiles). grid (8 qblocks, 4 ksplit, 32 bh).
__global__ __launch_bounds__(256) void attn_rowsum(
    const short* __restrict__ Qhi, const short* __restrict__ Qlo,
    const short* __restrict__ Khi, const short* __restrict__ Klo,
    float* __restrict__ rowsum)
{
    int bh = blockIdx.z, tid = threadIdx.x;
    int w = tid >> 6, lane = tid & 63, ln = lane & 15, quad = lane >> 4;
    int qb  = blockIdx.x * 256 + w * 64;
    int kt0 = blockIdx.y * 32;            // 32 k-tiles of 16 = 512 keys
    const short* QH = Qhi + (size_t)bh * 2048 * 64;
    const short* QL = Qlo + (size_t)bh * 2048 * 64;
    const short* KH = Khi + (size_t)bh * 2048 * 64;
    const short* KL = Klo + (size_t)bh * 2048 * 64;

    short8 qh[4][2], ql[4][2];
#pragma unroll
    for (int mt = 0; mt < 4; mt++)
#pragma unroll
        for (int half = 0; half < 2; half++) {
            size_t o = (size_t)(qb + mt*16 + ln) * 64 + half*32 + quad*8;
            qh[mt][half] = *(const short8*)(QH + o);
            ql[mt][half] = *(const short8*)(QL + o);
        }

    short8 kh[2][2], kl[2][2];   // [buf][dchunk]
    auto loadK = [&](int buf, int kt) {
        size_t ko = (size_t)(kt*16 + ln) * 64 + quad*8;
        kh[buf][0] = *(const short8*)(KH + ko);
        kh[buf][1] = *(const short8*)(KH + ko + 32);
        kl[buf][0] = *(const short8*)(KL + ko);
        kl[buf][1] = *(const short8*)(KL + ko + 32);
    };

    float racc[4][4] = {};
    auto comp = [&](int buf) {
#pragma unroll
        for (int mt = 0; mt < 4; mt++) {
            f32x4 c1 = (f32x4){0.f,0.f,0.f,0.f};
            f32x4 c2 = (f32x4){0.f,0.f,0.f,0.f};
            c1 = MFMA(qh[mt][0], kh[buf][0], c1); c1 = MFMA(qh[mt][1], kh[buf][1], c1);
            c2 = MFMA(qh[mt][0], kl[buf][0], c2); c2 = MFMA(qh[mt][1], kl[buf][1], c2);
            c2 = MFMA(ql[mt][0], kh[buf][0], c2); c2 = MFMA(ql[mt][1], kh[buf][1], c2);
#pragma unroll
            for (int i = 0; i < 4; i++)
                racc[mt][i] += PEXP(c1[i] + c2[i]);
        }
    };

    loadK(0, kt0);
    for (int t = 0; t < 32; t += 2) {
        loadK(1, kt0 + t + 1);
        comp(0);
        if (t + 2 < 32) loadK(0, kt0 + t + 2);
        comp(1);
    }
#pragma unroll
    for (int mt = 0; mt < 4; mt++)
#pragma unroll
        for (int i = 0; i < 4; i++)
            for (int d = 1; d < 16; d <<= 1)
                racc[mt][i] += __shfl_xor(racc[mt][i], d, 64);
    if (ln == 0) {
#pragma unroll
        for (int mt = 0; mt < 4; mt++)
#pragma unroll
            for (int i = 0; i < 4; i++)
                atomicAdd(&rowsum[bh * 2048 + qb + mt*16 + quad*4 + i], racc[mt][i]);
    }
}

// colsum[k] += sum over this block's q-quarter of 2^(c_qk)/rowsum[q].
// Wave owns 64 keys (4 n-tiles). grid (8 kblocks, 4 qsplit, 32 bh).
__global__ __launch_bounds__(256) void attn_colsum(
    const short* __restrict__ Qhi, const short* __restrict__ Qlo,
    const short* __restrict__ Khi, const short* __restrict__ Klo,
    const float* __restrict__ rowsum, float* __restrict__ colsum)
{
    __shared__ float sli[512];
    int bh = blockIdx.z, tid = threadIdx.x;
    int q0 = blockIdx.y * 512;
    for (int j = tid; j < 512; j += 256)
        sli[j] = 1.0f / rowsum[bh * 2048 + q0 + j];
    __syncthreads();

    int w = tid >> 6, lane = tid & 63, ln = lane & 15, quad = lane >> 4;
    int kb  = blockIdx.x * 256 + w * 64;
    int qt0 = blockIdx.y * 32;            // 32 q-tiles of 16
    const short* QH = Qhi + (size_t)bh * 2048 * 64;
    const short* QL = Qlo + (size_t)bh * 2048 * 64;
    const short* KH = Khi + (size_t)bh * 2048 * 64;
    const short* KL = Klo + (size_t)bh * 2048 * 64;

    short8 kh[4][2], kl[4][2];
#pragma unroll
    for (int nt = 0; nt < 4; nt++)
#pragma unroll
        for (int half = 0; half < 2; half++) {
            size_t o = (size_t)(kb + nt*16 + ln) * 64 + half*32 + quad*8;
            kh[nt][half] = *(const short8*)(KH + o);
            kl[nt][half] = *(const short8*)(KL + o);
        }

    short8 qh[2][2], ql[2][2];   // [buf][half]
    auto loadQ = [&](int buf, int qt) {
        size_t qo = (size_t)((qt0 + qt)*16 + ln) * 64 + quad*8;
        qh[buf][0] = *(const short8*)(QH + qo);
        qh[buf][1] = *(const short8*)(QH + qo + 32);
        ql[buf][0] = *(const short8*)(QL + qo);
        ql[buf][1] = *(const short8*)(QL + qo + 32);
    };

    float cacc[4] = {0.f, 0.f, 0.f, 0.f};
    auto comp = [&](int buf, int qt) {
#pragma unroll
        for (int nt = 0; nt < 4; nt++) {
            f32x4 c1 = (f32x4){0.f,0.f,0.f,0.f};
            f32x4 c2 = (f32x4){0.f,0.f,0.f,0.f};
            c1 = MFMA(qh[buf][0], kh[nt][0], c1); c1 = MFMA(qh[buf][1], kh[nt][1], c1);
            c2 = MFMA(qh[buf][0], kl[nt][0], c2); c2 = MFMA(qh[buf][1], kl[nt][1], c2);
            c2 = MFMA(ql[buf][0], kh[nt][0], c2); c2 = MFMA(ql[buf][1], kh[nt][1], c2);
#pragma unroll
            for (int i = 0; i < 4; i++) {
                int r = qt*16 + quad*4 + i;
                cacc[nt] += PEXP(c1[i] + c2[i]) * sli[r];
            }
        }
    };

    loadQ(0, 0);
    for (int qt = 0; qt < 32; qt += 2) {
        loadQ(1, qt + 1);
        comp(0, qt);
        if (qt + 2 < 32) loadQ(0, qt + 2);
        comp(1, qt + 1);
    }
#pragma unroll
    for (int nt = 0; nt < 4; nt++) {
        cacc[nt] += __shfl_xor(cacc[nt], 16, 64);
        cacc[nt] += __shfl_xor(cacc[nt], 32, 64);
        if (lane < 16) atomicAdd(&colsum[bh * 2048 + kb + nt*16 + lane], cacc[nt]);
    }
}

// Per (b,h): threshold = KEEP-th largest col_sum; mask = col_sum >= threshold.
__global__ __launch_bounds__(256) void topk_mask(
    const float* __restrict__ colsum, float* __restrict__ maskf)
{
    __shared__ unsigned keys[2048];
    __shared__ int cnt;
    int bh = blockIdx.x, tid = threadIdx.x;
    for (int j = tid; j < 2048; j += 256) {
        unsigned u = __float_as_uint(colsum[bh * 2048 + j]);
        keys[j] = (u & 0x80000000u) ? ~u : (u | 0x80000000u);
    }
    __syncthreads();
    unsigned long long lo = 0, hi = 0x100000000ULL;
    while (hi - lo > 1) {
        unsigned long long mid = (lo + hi) >> 1;
        if (tid == 0) cnt = 0;
        __syncthreads();
        int local = 0;
        for (int j = tid; j < 2048; j += 256) local += (keys[j] >= (unsigned)mid) ? 1 : 0;
        atomicAdd(&cnt, local);
        __syncthreads();
        int c = cnt;
        __syncthreads();
        if (c >= KEEP) lo = mid; else hi = mid;
    }
    unsigned thr = (unsigned)lo;
    for (int j = tid; j < 2048; j += 256)
        maskf[bh * 2048 + j] = (keys[j] >= thr) ? 1.0f : 0.0f;
}

// Vt[(bh*64+d)*2048+k] *= mask   (0/1 -> exact zeroing)
__global__ __launch_bounds__(256) void mask_v(
    unsigned short* __restrict__ Vt, const float* __restrict__ maskf)
{
    int i = blockIdx.x * 256 + threadIdx.x;   // short8 group
    int k8  = i & 255;
    int row = i >> 8;
    int bh  = row >> 6;
    const float* m = maskf + bh * 2048 + k8 * 8;
    short8 v = ((short8*)Vt)[i];
#pragma unroll
    for (int j = 0; j < 8; j++)
        if (m[j] == 0.0f) v[j] = 0;
    ((short8*)Vt)[i] = v;
}

// PV with swapped-operand QK^T and fully in-register P (no LDS).
// Wave owns 32 q-rows. Per 32-key chunk:
//   S^T = mfma32(A=K, B=Q^T) x4 d-steps  -> lane holds S^T[crow(r,hi)][qb+lq]
//   p = exp2(S^T)  (Q pre-scaled by log2(e)/8)
//   cvt_pk_bf16 pairs + permlane32_swap  -> PV A-frag (P[q][k] lane-local)
//   O += mfma32(A=P, B=V) x (ks=0,1)x(nt=0,1)
// crow(r,hi) = (r&3) + 8*(r>>2) + 4*hi   (HW-verified 32x32 C/D layout)
__global__ __launch_bounds__(256) void attn_av(
    const short* __restrict__ Qhi, const short* __restrict__ Khi,
    const short* __restrict__ Vt, const float* __restrict__ rowsum,
    unsigned short* __restrict__ concat)
{
    int bh = blockIdx.y, tid = threadIdx.x;
    int w = tid >> 6, lane = tid & 63;
    int lq = lane & 31, hi = lane >> 5;
    int qb = blockIdx.x * 128 + w * 32;
    const short* Q = Qhi + (size_t)bh * 2048 * 64;
    const short* K = Khi + (size_t)bh * 2048 * 64;
    const short* V = Vt  + (size_t)bh * 64 * 2048;

    // Q^T B-frags: lane holds Q[qb+lq][ds*16 + hi*8 + j]
    short8 qf[4];
#pragma unroll
    for (int d = 0; d < 4; d++)
        qf[d] = *(const short8*)(Q + (size_t)(qb + lq) * 64 + d*16 + hi*8);

    f32x16 o0, o1;
#pragma unroll
    for (int i = 0; i < 16; i++) { o0[i] = 0.f; o1[i] = 0.f; }

    short8 kf[2][4];   // [buf][dstep]   A=K frags
    short8 vf[2][4];   // [buf][ks*2+nt] B=V frags
    auto loadKV = [&](int buf, int kc) {
        const short* kp = K + (size_t)(kc*32 + lq) * 64 + hi*8;
#pragma unroll
        for (int d = 0; d < 4; d++)
            kf[buf][d] = *(const short8*)(kp + d*16);
#pragma unroll
        for (int ks = 0; ks < 2; ks++)
#pragma unroll
            for (int nt = 0; nt < 2; nt++)
                vf[buf][ks*2+nt] = *(const short8*)(
                    V + (size_t)(nt*32 + lq) * 2048 + kc*32 + ks*16 + hi*8);
    };

    auto comp = [&](int buf) {
        f32x16 s;
#pragma unroll
        for (int i = 0; i < 16; i++) s[i] = 0.f;
        s = MFMA32(kf[buf][0], qf[0], s);
        s = MFMA32(kf[buf][1], qf[1], s);
        s = MFMA32(kf[buf][2], qf[2], s);
        s = MFMA32(kf[buf][3], qf[3], s);

        float p[16];
#pragma unroll
        for (int i = 0; i < 16; i++) p[i] = PEXP(s[i]);

        // pack p -> PV A-frags: per ks-half, pair-pack then swap halves.
        // w0..w3 before swap: {(k0,k1)},{(k2,k3)},{(k8,k9)},{(k10,k11)} (hi0)
        // after swap(w0,w2),(w1,w3): w0={(0,1)|(8,9)}, w2={(4,5)|(12,13)} etc.
        short8 pa[2];
#pragma unroll
        for (int ks = 0; ks < 2; ks++) {
            unsigned w0, w1, w2, w3;
            int o8 = ks * 8;
            asm("v_cvt_pk_bf16_f32 %0, %1, %2" : "=v"(w0) : "v"(p[o8+0]), "v"(p[o8+1]));
            asm("v_cvt_pk_bf16_f32 %0, %1, %2" : "=v"(w1) : "v"(p[o8+2]), "v"(p[o8+3]));
            asm("v_cvt_pk_bf16_f32 %0, %1, %2" : "=v"(w2) : "v"(p[o8+4]), "v"(p[o8+5]));
            asm("v_cvt_pk_bf16_f32 %0, %1, %2" : "=v"(w3) : "v"(p[o8+6]), "v"(p[o8+7]));
            asm("v_permlane32_swap_b32 %0, %1" : "+v"(w0), "+v"(w2));
            asm("v_permlane32_swap_b32 %0, %1" : "+v"(w1), "+v"(w3));
            u32x4 pw = { w0, w1, w2, w3 };
            pa[ks] = __builtin_bit_cast(short8, pw);
        }

        o0 = MFMA32(pa[0], vf[buf][0], o0);
        o1 = MFMA32(pa[0], vf[buf][1], o1);
        o0 = MFMA32(pa[1], vf[buf][2], o0);
        o1 = MFMA32(pa[1], vf[buf][3], o1);
    };

    loadKV(0, 0);
    for (int kc = 0; kc < 64; kc += 2) {
        loadKV(1, kc + 1);
        comp(0);
        if (kc + 2 < 64) loadKV(0, kc + 2);
        comp(1);
    }

    int b_ = bh >> 4, h = bh & 15;
#pragma unroll
    for (int r = 0; r < 16; r++) {
        int crow = (r & 3) + 8*(r >> 2) + 4*hi;
        float inv = 1.0f / rowsum[bh * 2048 + qb + crow];
        size_t base = ((size_t)(b_*2048 + qb + crow)) * 1024 + h*64;
        concat[base + lq]      = f2bf(o0[r] * inv);
        concat[base + 32 + lq] = f2bf(o1[r] * inv);
    }
}

extern "C" void kernel_launch(void* const* d_in, const int* in_sizes, int n_in,
                              void* d_out, int out_size, void* d_ws, size_t ws_size,
                              hipStream_t stream)
{
    const float* q  = (const float*)d_in[0];
    const float* k  = (const float*)d_in[1];
    const float* v  = (const float*)d_in[2];
    const float* Wq = (const float*)d_in[3];
    const float* bq = (const float*)d_in[4];
    const float* Wk = (const float*)d_in[5];
    const float* bk = (const float*)d_in[6];
    const float* Wv = (const float*)d_in[7];
    const float* bv = (const float*)d_in[8];
    const float* Wo = (const float*)d_in[9];
    const float* bo = (const float*)d_in[10];

    char* ws = (char*)d_ws;
    size_t off = 0;
    auto alloc = [&](size_t bytes) -> void* {
        void* p = ws + off;
        off += (bytes + 255) & ~(size_t)255;
        return p;
    };
    const size_t ASZ = (size_t)4096 * 1024 * 2;   // 8.4 MB bf16 activation
    const size_t WSZ = (size_t)1024 * 1024 * 2;   // 2 MB bf16 weight
    unsigned short* qh_ = (unsigned short*)alloc(ASZ);
    unsigned short* ql_ = (unsigned short*)alloc(ASZ);
    unsigned short* kh_ = (unsigned short*)alloc(ASZ);
    unsigned short* kl_ = (unsigned short*)alloc(ASZ);
    unsigned short* vh_ = (unsigned short*)alloc(ASZ);
    unsigned short* vl_ = (unsigned short*)alloc(ASZ);
    unsigned short* wqh = (unsigned short*)alloc(WSZ);
    unsigned short* wql = (unsigned short*)alloc(WSZ);
    unsigned short* wkh = (unsigned short*)alloc(WSZ);
    unsigned short* wkl = (unsigned short*)alloc(WSZ);
    unsigned short* wvh = (unsigned short*)alloc(WSZ);
    unsigned short* wvl = (unsigned short*)alloc(WSZ);
    unsigned short* woh = (unsigned short*)alloc(WSZ);
    unsigned short* wol = (unsigned short*)alloc(WSZ);
    short* Qhi = (short*)alloc(ASZ);
    short* Qlo = (short*)alloc(ASZ);
    short* Khi = (short*)alloc(ASZ);
    short* Klo = (short*)alloc(ASZ);
    short* Vt  = (short*)alloc(ASZ);
    float* rowsum = (float*)alloc((size_t)32 * 2048 * 4);
    float* colsum = (float*)alloc((size_t)32 * 2048 * 4);
    float* maskf  = (float*)alloc((size_t)32 * 2048 * 4);
    unsigned short* concat = (unsigned short*)alloc(ASZ);
    // total ~118 MB (known-safe)

    dim3 blk(256);
    const int An4 = 4096 * 1024 / 4, Wn4 = 1024 * 1024 / 4;

    cvt_split<<<An4/256, blk, 0, stream>>>(q,  qh_, ql_, An4);
    cvt_split<<<An4/256, blk, 0, stream>>>(k,  kh_, kl_, An4);
    cvt_split<<<An4/256, blk, 0, stream>>>(v,  vh_, vl_, An4);
    cvt_split<<<Wn4/256, blk, 0, stream>>>(Wq, wqh, wql, Wn4);
    cvt_split<<<Wn4/256, blk, 0, stream>>>(Wk, wkh, wkl, Wn4);
    cvt_split<<<Wn4/256, blk, 0, stream>>>(Wv, wvh, wvl, Wn4);
    cvt_split<<<Wn4/256, blk, 0, stream>>>(Wo, woh, wol, Wn4);
    zero_f32 <<<dim3(512), blk, 0, stream>>>(rowsum, 2 * 32 * 2048);  // rowsum+colsum

    gemm_qkv<<<dim3(8, 32, 3), blk, 0, stream>>>(
        (const short*)qh_, (const short*)ql_, (const short*)kh_, (const short*)kl_,
        (const short*)vh_, (const short*)vl_,
        (const short*)wqh, (const short*)wql, (const short*)wkh, (const short*)wkl,
        (const short*)wvh, (const short*)wvl,
        bq, bk, bv,
        (unsigned short*)Qhi, (unsigned short*)Qlo,
        (unsigned short*)Khi, (unsigned short*)Klo, (unsigned short*)Vt);

    attn_rowsum<<<dim3(8, 4, 32), blk, 0, stream>>>(Qhi, Qlo, Khi, Klo, rowsum);
    attn_colsum<<<dim3(8, 4, 32), blk, 0, stream>>>(Qhi, Qlo, Khi, Klo, rowsum, colsum);
    topk_mask  <<<dim3(32),   blk, 0, stream>>>(colsum, maskf);
    mask_v     <<<dim3(2048), blk, 0, stream>>>((unsigned short*)Vt, maskf);
    attn_av    <<<dim3(16, 32), blk, 0, stream>>>(Qhi, Khi, Vt, rowsum, concat);

    gemm_out<<<dim3(8, 32), blk, 0, stream>>>((const short*)concat,
        (const short*)woh, (const short*)wol, bo, (float*)d_out);
}

// Round 4
// 509.296 us; speedup vs baseline: 1.4028x; 1.1988x over previous
//
#include <hip/hip_runtime.h>

// ---------------------------------------------------------------------------
// Pruned multi-head attention. fp32 I/O, split-bf16 (hi+lo) MFMA compute.
// B=2, S=2048, D_MODEL=1024, H=16, d_k=64, keep=int(2048*0.9)=1843
//
// Round 12: R8/R10/R11 all pinned at ~128us with MfmaUtil 10.6% regardless
// of VALU/LDS structure -> attn_av is vector-memory TRANSACTION bound
// (strided K/V fragment gathers = ~32 txns/instr, 4 waves redundantly
// loading the same lines). Fix: (a) K and V stored in FRAGMENT-MAJOR
// layout (free: gemm_qkv epilogue was already scattered stores), so a
// wave's fragment is 1KB contiguous; (b) attn_av stages each 8KB K/V
// chunk into LDS ONCE PER BLOCK via linear global_load_lds, ds_reads are
// lane-linear (conflict-free, no swizzle). P stays in-register (R11).
// rowsum/colsum re-address K in frag layout (txn-equivalent for them).
// ---------------------------------------------------------------------------

typedef __attribute__((ext_vector_type(8))) short short8;   // 8 bf16 (4 VGPRs)
typedef __attribute__((ext_vector_type(4))) short short4v;
typedef __attribute__((ext_vector_type(4))) float f32x4;
typedef __attribute__((ext_vector_type(16))) float f32x16;
typedef __attribute__((ext_vector_type(4))) unsigned int u32x4;

#define KEEP 1843

#if __has_builtin(__builtin_amdgcn_exp2f)
  #define PEXP(x) __builtin_amdgcn_exp2f(x)
  #define QSC 0.18033688011112042f   // log2(e)/8 folded into Q projection
#else
  #define PEXP(x) __expf(x)
  #define QSC 0.125f
#endif

#define AS1(p) ((const __attribute__((address_space(1))) void*)(p))
#define AS3(p) ((__attribute__((address_space(3))) void*)(p))

static __device__ __forceinline__ float bf2f(unsigned short s) {
    union { unsigned u; float f; } v; v.u = ((unsigned)s) << 16; return v.f;
}
static __device__ __forceinline__ unsigned short f2bf(float f) {
    union { float f; unsigned u; } v; v.f = f;
    unsigned u = v.u;
    unsigned r = (u + 0x7FFFu + ((u >> 16) & 1u)) >> 16;   // RNE
    return (unsigned short)r;
}

#define MFMA(A, B, C)   __builtin_amdgcn_mfma_f32_16x16x32_bf16(A, B, C, 0, 0, 0)
#define MFMA32(A, B, C) __builtin_amdgcn_mfma_f32_32x32x16_bf16(A, B, C, 0, 0, 0)

// Fragment-major K layout (per bh, 131072 shorts):
//   element (s,d) -> (s>>5)*2048 + (((d>>4)*2 + ((d>>3)&1))*32 + (s&31))*8 + (d&7)
// Fragment-major V layout (per bh):
//   element (s,d) -> (s>>5)*2048 + ((((((s>>4)&1)*2 + (d>>5))*2 + ((s>>3)&1))*32) + (d&31))*8 + (s&7)

// fp32 array -> hi/lo bf16 arrays (x = hi + lo to ~2^-17 relative)
__global__ __launch_bounds__(256) void cvt_split(
    const float* __restrict__ in, unsigned short* __restrict__ hi,
    unsigned short* __restrict__ lo, int n4)
{
    int i = blockIdx.x * 256 + threadIdx.x;
    if (i >= n4) return;
    f32x4 x = ((const f32x4*)in)[i];
    short4v h, l;
#pragma unroll
    for (int j = 0; j < 4; j++) {
        unsigned short hv = f2bf(x[j]);
        h[j] = (short)hv;
        l[j] = (short)f2bf(x[j] - bf2f(hv));
    }
    ((short4v*)hi)[i] = h;
    ((short4v*)lo)[i] = l;
}

__global__ __launch_bounds__(256) void zero_f32(float* __restrict__ p, int n) {
    int i = blockIdx.x * 256 + threadIdx.x;
    if (i < n) p[i] = 0.f;
}

// Fused Q/K/V projections, m97-style LDS staging. 128x128 tile, BK=32.
// z=0: Q -> bf16 hi+lo row layout, scaled QSC; z=1: K -> frag-major hi+lo;
// z=2: V -> frag-major hi only.
__global__ __launch_bounds__(256) void gemm_qkv(
    const short* __restrict__ A0, const short* __restrict__ Al0,
    const short* __restrict__ A1, const short* __restrict__ Al1,
    const short* __restrict__ A2, const short* __restrict__ Al2,
    const short* __restrict__ W0, const short* __restrict__ Wl0,
    const short* __restrict__ W1, const short* __restrict__ Wl1,
    const short* __restrict__ W2, const short* __restrict__ Wl2,
    const float* __restrict__ b0, const float* __restrict__ b1,
    const float* __restrict__ b2,
    unsigned short* __restrict__ Qhi, unsigned short* __restrict__ Qlo,
    unsigned short* __restrict__ Khi, unsigned short* __restrict__ Klo,
    unsigned short* __restrict__ Vt)
{
    int z = blockIdx.z;
    const short *Ahg, *Alg, *Whg, *Wlg; const float* bias;
    unsigned short *oh = 0, *ol = 0; float scale; int mode;
    if (z == 0)      { Ahg=A0; Alg=Al0; Whg=W0; Wlg=Wl0; bias=b0; oh=Qhi; ol=Qlo; scale=QSC;  mode=0; }
    else if (z == 1) { Ahg=A1; Alg=Al1; Whg=W1; Wlg=Wl1; bias=b1; oh=Khi; ol=Klo; scale=1.0f; mode=1; }
    else             { Ahg=A2; Alg=Al2; Whg=W2; Wlg=Wl2; bias=b2; oh=Vt;          scale=1.0f; mode=2; }

    __shared__ __align__(16) short Ah_l[128*32];
    __shared__ __align__(16) short Al_l[128*32];
    __shared__ __align__(16) short Wh_l[128*32];
    __shared__ __align__(16) short Wl_l[128*32];

    int tid  = threadIdx.x;
    int w    = tid >> 6;
    int lane = tid & 63;
    int ln   = lane & 15;
    int quad = lane >> 4;
    int rowBase = blockIdx.y * 128;
    int colBase = blockIdx.x * 128;
    int mBase = (w & 1) * 64;        // wave's quadrant inside 128x128
    int nBase = (w >> 1) * 64;

    int srow = (lane >> 2);
    int scol = (lane & 3) * 8;
    const short* Ag_h = Ahg + (size_t)rowBase * 1024;
    const short* Ag_l = Alg + (size_t)rowBase * 1024;
    const short* Wg_h = Whg + (size_t)colBase * 1024;
    const short* Wg_l = Wlg + (size_t)colBase * 1024;

    f32x4 acc[4][4];
#pragma unroll
    for (int i = 0; i < 4; i++)
#pragma unroll
        for (int j = 0; j < 4; j++) acc[i][j] = (f32x4){0.f, 0.f, 0.f, 0.f};

    for (int kk = 0; kk < 1024; kk += 32) {
#pragma unroll
        for (int j = 0; j < 2; j++) {
            int r = w*32 + j*16;
            size_t go = (size_t)(r + srow) * 1024 + kk + scol;
            __builtin_amdgcn_global_load_lds(AS1(Ag_h + go), AS3(Ah_l + r*32), 16, 0, 0);
            __builtin_amdgcn_global_load_lds(AS1(Ag_l + go), AS3(Al_l + r*32), 16, 0, 0);
            __builtin_amdgcn_global_load_lds(AS1(Wg_h + go), AS3(Wh_l + r*32), 16, 0, 0);
            __builtin_amdgcn_global_load_lds(AS1(Wg_l + go), AS3(Wl_l + r*32), 16, 0, 0);
        }
        __syncthreads();

        short8 ah[4], al[4], bh[4], bl[4];
#pragma unroll
        for (int mt = 0; mt < 4; mt++) {
            int r = mBase + mt*16 + ln;
            ah[mt] = *(const short8*)(Ah_l + r*32 + quad*8);
            al[mt] = *(const short8*)(Al_l + r*32 + quad*8);
        }
#pragma unroll
        for (int nt = 0; nt < 4; nt++) {
            int c = nBase + nt*16 + ln;
            bh[nt] = *(const short8*)(Wh_l + c*32 + quad*8);
            bl[nt] = *(const short8*)(Wl_l + c*32 + quad*8);
        }
#pragma unroll
        for (int mt = 0; mt < 4; mt++)
#pragma unroll
            for (int nt = 0; nt < 4; nt++) {
                acc[mt][nt] = MFMA(ah[mt], bh[nt], acc[mt][nt]);
                acc[mt][nt] = MFMA(ah[mt], bl[nt], acc[mt][nt]);
                acc[mt][nt] = MFMA(al[mt], bh[nt], acc[mt][nt]);
            }
        __syncthreads();
    }

#pragma unroll
    for (int mt = 0; mt < 4; mt++) {
#pragma unroll
        for (int nt = 0; nt < 4; nt++) {
            int col = colBase + nBase + nt*16 + ln;
            float bv = bias[col];
#pragma unroll
            for (int i = 0; i < 4; i++) {
                int row = rowBase + mBase + mt*16 + quad*4 + i;   // D: row=quad*4+reg
                float val = (acc[mt][nt][i] + bv) * scale;
                int b_  = row >> 11, s = row & 2047;
                int h   = col >> 6,  d = col & 63;
                int bh_ = b_ * 16 + h;
                if (mode == 2) {
                    size_t idx = (size_t)bh_ * 131072 + (size_t)(s >> 5) * 2048
                        + ((size_t)((((((s >> 4) & 1) * 2 + (d >> 5)) * 2 + ((s >> 3) & 1)) * 32)
                                    + (d & 31))) * 8 + (s & 7);
                    oh[idx] = f2bf(val);
                } else if (mode == 1) {
                    size_t idx = (size_t)bh_ * 131072 + (size_t)(s >> 5) * 2048
                        + ((size_t)(((d >> 4) * 2 + ((d >> 3) & 1)) * 32 + (s & 31))) * 8 + (d & 7);
                    unsigned short hv = f2bf(val);
                    oh[idx] = hv;
                    ol[idx] = f2bf(val - bf2f(hv));
                } else {
                    size_t idx = ((size_t)bh_ * 2048 + s) * 64 + d;
                    unsigned short hv = f2bf(val);
                    oh[idx] = hv;
                    ol[idx] = f2bf(val - bf2f(hv));
                }
            }
        }
    }
}

// out = concat(bf16) @ Wo^T + bo (split Wo, fp32 out), LDS-staged.
__global__ __launch_bounds__(256) void gemm_out(
    const short* __restrict__ Ag, const short* __restrict__ Whg,
    const short* __restrict__ Wlg, const float* __restrict__ bias,
    float* __restrict__ out)
{
    __shared__ __align__(16) short A_l[128*32];
    __shared__ __align__(16) short Wh_l[128*32];
    __shared__ __align__(16) short Wl_l[128*32];

    int tid  = threadIdx.x;
    int w    = tid >> 6;
    int lane = tid & 63;
    int ln   = lane & 15;
    int quad = lane >> 4;
    int rowBase = blockIdx.y * 128;
    int colBase = blockIdx.x * 128;
    int mBase = (w & 1) * 64;
    int nBase = (w >> 1) * 64;

    int srow = (lane >> 2);
    int scol = (lane & 3) * 8;
    const short* Abase = Ag  + (size_t)rowBase * 1024;
    const short* Whb   = Whg + (size_t)colBase * 1024;
    const short* Wlb   = Wlg + (size_t)colBase * 1024;

    f32x4 acc[4][4];
#pragma unroll
    for (int i = 0; i < 4; i++)
#pragma unroll
        for (int j = 0; j < 4; j++) acc[i][j] = (f32x4){0.f, 0.f, 0.f, 0.f};

    for (int kk = 0; kk < 1024; kk += 32) {
#pragma unroll
        for (int j = 0; j < 2; j++) {
            int r = w*32 + j*16;
            size_t go = (size_t)(r + srow) * 1024 + kk + scol;
            __builtin_amdgcn_global_load_lds(AS1(Abase + go), AS3(A_l  + r*32), 16, 0, 0);
            __builtin_amdgcn_global_load_lds(AS1(Whb   + go), AS3(Wh_l + r*32), 16, 0, 0);
            __builtin_amdgcn_global_load_lds(AS1(Wlb   + go), AS3(Wl_l + r*32), 16, 0, 0);
        }
        __syncthreads();

        short8 a[4], bh[4], bl[4];
#pragma unroll
        for (int mt = 0; mt < 4; mt++)
            a[mt] = *(const short8*)(A_l + (mBase + mt*16 + ln)*32 + quad*8);
#pragma unroll
        for (int nt = 0; nt < 4; nt++) {
            int c = nBase + nt*16 + ln;
            bh[nt] = *(const short8*)(Wh_l + c*32 + quad*8);
            bl[nt] = *(const short8*)(Wl_l + c*32 + quad*8);
        }
#pragma unroll
        for (int mt = 0; mt < 4; mt++)
#pragma unroll
            for (int nt = 0; nt < 4; nt++) {
                acc[mt][nt] = MFMA(a[mt], bh[nt], acc[mt][nt]);
                acc[mt][nt] = MFMA(a[mt], bl[nt], acc[mt][nt]);
            }
        __syncthreads();
    }

#pragma unroll
    for (int mt = 0; mt < 4; mt++) {
#pragma unroll
        for (int nt = 0; nt < 4; nt++) {
            int col = colBase + nBase + nt*16 + ln;
            float bv = bias[col];
#pragma unroll
            for (int i = 0; i < 4; i++) {
                int row = rowBase + mBase + mt*16 + quad*4 + i;
                out[(size_t)row * 1024 + col] = acc[mt][nt][i] + bv;
            }
        }
    }
}

// rowsum[q] += sum over this block's k-quarter of 2^(c_qk).  Split-precision.
// K read in frag-major layout (txn-equivalent coalescing).
__global__ __launch_bounds__(256) void attn_rowsum(
    const short* __restrict__ Qhi, const short* __restrict__ Qlo,
    const short* __restrict__ Khi, const short* __restrict__ Klo,
    float* __restrict__ rowsum)
{
    int bh = blockIdx.z, tid = threadIdx.x;
    int w = tid >> 6, lane = tid & 63, ln = lane & 15, quad = lane >> 4;
    int qb  = blockIdx.x * 256 + w * 64;
    int kt0 = blockIdx.y * 32;            // 32 k-tiles of 16 = 512 keys
    const short* QH = Qhi + (size_t)bh * 2048 * 64;
    const short* QL = Qlo + (size_t)bh * 2048 * 64;
    const short* KH = Khi + (size_t)bh * 131072;
    const short* KL = Klo + (size_t)bh * 131072;

    short8 qh[4][2], ql[4][2];
#pragma unroll
    for (int mt = 0; mt < 4; mt++)
#pragma unroll
        for (int half = 0; half < 2; half++) {
            size_t o = (size_t)(qb + mt*16 + ln) * 64 + half*32 + quad*8;
            qh[mt][half] = *(const short8*)(QH + o);
            ql[mt][half] = *(const short8*)(QL + o);
        }

    short8 kh[2][2], kl[2][2];   // [buf][dchunk]
    auto loadK = [&](int buf, int kt) {
        // frag layout: (kt>>1)*2048 + half*1024 + quad*256 + ((kt&1)*16+ln)*8
        size_t ko = (size_t)(kt >> 1) * 2048 + (size_t)quad * 256 + ((kt & 1) * 16 + ln) * 8;
        kh[buf][0] = *(const short8*)(KH + ko);
        kh[buf][1] = *(const short8*)(KH + ko + 1024);
        kl[buf][0] = *(const short8*)(KL + ko);
        kl[buf][1] = *(const short8*)(KL + ko + 1024);
    };

    float racc[4][4] = {};
    auto comp = [&](int buf) {
#pragma unroll
        for (int mt = 0; mt < 4; mt++) {
            f32x4 c1 = (f32x4){0.f,0.f,0.f,0.f};
            f32x4 c2 = (f32x4){0.f,0.f,0.f,0.f};
            c1 = MFMA(qh[mt][0], kh[buf][0], c1); c1 = MFMA(qh[mt][1], kh[buf][1], c1);
            c2 = MFMA(qh[mt][0], kl[buf][0], c2); c2 = MFMA(qh[mt][1], kl[buf][1], c2);
            c2 = MFMA(ql[mt][0], kh[buf][0], c2); c2 = MFMA(ql[mt][1], kh[buf][1], c2);
#pragma unroll
            for (int i = 0; i < 4; i++)
                racc[mt][i] += PEXP(c1[i] + c2[i]);
        }
    };

    loadK(0, kt0);
    for (int t = 0; t < 32; t += 2) {
        loadK(1, kt0 + t + 1);
        comp(0);
        if (t + 2 < 32) loadK(0, kt0 + t + 2);
        comp(1);
    }
#pragma unroll
    for (int mt = 0; mt < 4; mt++)
#pragma unroll
        for (int i = 0; i < 4; i++)
            for (int d = 1; d < 16; d <<= 1)
                racc[mt][i] += __shfl_xor(racc[mt][i], d, 64);
    if (ln == 0) {
#pragma unroll
        for (int mt = 0; mt < 4; mt++)
#pragma unroll
            for (int i = 0; i < 4; i++)
                atomicAdd(&rowsum[bh * 2048 + qb + mt*16 + quad*4 + i], racc[mt][i]);
    }
}

// colsum[k] += sum over this block's q-quarter of 2^(c_qk)/rowsum[q].
__global__ __launch_bounds__(256) void attn_colsum(
    const short* __restrict__ Qhi, const short* __restrict__ Qlo,
    const short* __restrict__ Khi, const short* __restrict__ Klo,
    const float* __restrict__ rowsum, float* __restrict__ colsum)
{
    __shared__ float sli[512];
    int bh = blockIdx.z, tid = threadIdx.x;
    int q0 = blockIdx.y * 512;
    for (int j = tid; j < 512; j += 256)
        sli[j] = 1.0f / rowsum[bh * 2048 + q0 + j];
    __syncthreads();

    int w = tid >> 6, lane = tid & 63, ln = lane & 15, quad = lane >> 4;
    int kb  = blockIdx.x * 256 + w * 64;
    int qt0 = blockIdx.y * 32;            // 32 q-tiles of 16
    const short* QH = Qhi + (size_t)bh * 2048 * 64;
    const short* QL = Qlo + (size_t)bh * 2048 * 64;
    const short* KH = Khi + (size_t)bh * 131072;
    const short* KL = Klo + (size_t)bh * 131072;

    short8 kh[4][2], kl[4][2];
#pragma unroll
    for (int nt = 0; nt < 4; nt++)
#pragma unroll
        for (int half = 0; half < 2; half++) {
            size_t o = (size_t)((kb >> 5) + (nt >> 1)) * 2048 + (size_t)half * 1024
                     + (size_t)quad * 256 + ((nt & 1) * 16 + ln) * 8;
            kh[nt][half] = *(const short8*)(KH + o);
            kl[nt][half] = *(const short8*)(KL + o);
        }

    short8 qh[2][2], ql[2][2];   // [buf][half]
    auto loadQ = [&](int buf, int qt) {
        size_t qo = (size_t)((qt0 + qt)*16 + ln) * 64 + quad*8;
        qh[buf][0] = *(const short8*)(QH + qo);
        qh[buf][1] = *(const short8*)(QH + qo + 32);
        ql[buf][0] = *(const short8*)(QL + qo);
        ql[buf][1] = *(const short8*)(QL + qo + 32);
    };

    float cacc[4] = {0.f, 0.f, 0.f, 0.f};
    auto comp = [&](int buf, int qt) {
#pragma unroll
        for (int nt = 0; nt < 4; nt++) {
            f32x4 c1 = (f32x4){0.f,0.f,0.f,0.f};
            f32x4 c2 = (f32x4){0.f,0.f,0.f,0.f};
            c1 = MFMA(qh[buf][0], kh[nt][0], c1); c1 = MFMA(qh[buf][1], kh[nt][1], c1);
            c2 = MFMA(qh[buf][0], kl[nt][0], c2); c2 = MFMA(qh[buf][1], kl[nt][1], c2);
            c2 = MFMA(ql[buf][0], kh[nt][0], c2); c2 = MFMA(ql[buf][1], kh[nt][1], c2);
#pragma unroll
            for (int i = 0; i < 4; i++) {
                int r = qt*16 + quad*4 + i;
                cacc[nt] += PEXP(c1[i] + c2[i]) * sli[r];
            }
        }
    };

    loadQ(0, 0);
    for (int qt = 0; qt < 32; qt += 2) {
        loadQ(1, qt + 1);
        comp(0, qt);
        if (qt + 2 < 32) loadQ(0, qt + 2);
        comp(1, qt + 1);
    }
#pragma unroll
    for (int nt = 0; nt < 4; nt++) {
        cacc[nt] += __shfl_xor(cacc[nt], 16, 64);
        cacc[nt] += __shfl_xor(cacc[nt], 32, 64);
        if (lane < 16) atomicAdd(&colsum[bh * 2048 + kb + nt*16 + lane], cacc[nt]);
    }
}

// Per (b,h): threshold = KEEP-th largest col_sum; mask = col_sum >= threshold.
__global__ __launch_bounds__(256) void topk_mask(
    const float* __restrict__ colsum, float* __restrict__ maskf)
{
    __shared__ unsigned keys[2048];
    __shared__ int cnt;
    int bh = blockIdx.x, tid = threadIdx.x;
    for (int j = tid; j < 2048; j += 256) {
        unsigned u = __float_as_uint(colsum[bh * 2048 + j]);
        keys[j] = (u & 0x80000000u) ? ~u : (u | 0x80000000u);
    }
    __syncthreads();
    unsigned long long lo = 0, hi = 0x100000000ULL;
    while (hi - lo > 1) {
        unsigned long long mid = (lo + hi) >> 1;
        if (tid == 0) cnt = 0;
        __syncthreads();
        int local = 0;
        for (int j = tid; j < 2048; j += 256) local += (keys[j] >= (unsigned)mid) ? 1 : 0;
        atomicAdd(&cnt, local);
        __syncthreads();
        int c = cnt;
        __syncthreads();
        if (c >= KEEP) lo = mid; else hi = mid;
    }
    unsigned thr = (unsigned)lo;
    for (int j = tid; j < 2048; j += 256)
        maskf[bh * 2048 + j] = (keys[j] >= thr) ? 1.0f : 0.0f;
}

// V (frag-major) *= mask. Group g of 8 shorts covers 8 consecutive k for one d:
// k0 = (g>>8)*32 + ((g>>7)&1)*16 + ((g>>5)&1)*8
__global__ __launch_bounds__(256) void mask_v(
    unsigned short* __restrict__ Vt, const float* __restrict__ maskf)
{
    int i = blockIdx.x * 256 + threadIdx.x;   // short8 group; 32 bh x 16384 groups
    int g  = i & 16383;
    int bh = i >> 14;
    int k0 = (g >> 8) * 32 + ((g >> 7) & 1) * 16 + ((g >> 5) & 1) * 8;
    const float* m = maskf + bh * 2048 + k0;
    short8 v = ((short8*)Vt)[i];
#pragma unroll
    for (int j = 0; j < 8; j++)
        if (m[j] == 0.0f) v[j] = 0;
    ((short8*)Vt)[i] = v;
}

// PV with swapped-operand QK^T, in-register P (R11), and block-level LDS
// staging of frag-major K/V chunks (one 8KB load per block per chunk via
// linear global_load_lds; ds_reads lane-linear = conflict-free).
__global__ __launch_bounds__(256) void attn_av(
    const short* __restrict__ Qhi, const short* __restrict__ Kf,
    const short* __restrict__ Vf, const float* __restrict__ rowsum,
    unsigned short* __restrict__ concat)
{
    __shared__ __align__(16) short KA[4096];   // [0,2048): K chunk, [2048,4096): V chunk
    __shared__ __align__(16) short KB[4096];
    int bh = blockIdx.y, tid = threadIdx.x;
    int w = tid >> 6, lane = tid & 63;
    int lq = lane & 31, hi = lane >> 5;
    int qb = blockIdx.x * 128 + w * 32;
    const short* Q  = Qhi + (size_t)bh * 2048 * 64;
    const short* Kg = Kf  + (size_t)bh * 131072;
    const short* Vg = Vf  + (size_t)bh * 131072;

    // Q^T B-frags: lane holds Q[qb+lq][d*16 + hi*8 + j]  (read once)
    short8 qf[4];
#pragma unroll
    for (int d = 0; d < 4; d++)
        qf[d] = *(const short8*)(Q + (size_t)(qb + lq) * 64 + d*16 + hi*8);

    f32x16 o0, o1;
#pragma unroll
    for (int i = 0; i < 16; i++) { o0[i] = 0.f; o1[i] = 0.f; }

    auto STAGE = [&](short* B, int kc) {
        // 8KB: 256 threads x 16B for K, same for V. Wave-uniform LDS base.
        __builtin_amdgcn_global_load_lds(AS1(Kg + (size_t)kc*2048 + tid*8),
                                         AS3(B + w*512), 16, 0, 0);
        __builtin_amdgcn_global_load_lds(AS1(Vg + (size_t)kc*2048 + tid*8),
                                         AS3(B + 2048 + w*512), 16, 0, 0);
    };

    auto comp = [&](const short* B) {
        short8 kf_[4], vf_[4];
#pragma unroll
        for (int d = 0; d < 4; d++)
            kf_[d] = *(const short8*)(B + (d*2 + hi)*256 + lq*8);
#pragma unroll
        for (int ks = 0; ks < 2; ks++)
#pragma unroll
            for (int nt = 0; nt < 2; nt++)
                vf_[ks*2+nt] = *(const short8*)(B + 2048 + ((ks*2+nt)*2 + hi)*256 + lq*8);

        f32x16 s;
#pragma unroll
        for (int i = 0; i < 16; i++) s[i] = 0.f;
        s = MFMA32(kf_[0], qf[0], s);
        s = MFMA32(kf_[1], qf[1], s);
        s = MFMA32(kf_[2], qf[2], s);
        s = MFMA32(kf_[3], qf[3], s);

        float p[16];
#pragma unroll
        for (int i = 0; i < 16; i++) p[i] = PEXP(s[i]);

        short8 pa[2];
#pragma unroll
        for (int ks = 0; ks < 2; ks++) {
            unsigned w0, w1, w2, w3;
            int o8 = ks * 8;
            asm("v_cvt_pk_bf16_f32 %0, %1, %2" : "=v"(w0) : "v"(p[o8+0]), "v"(p[o8+1]));
            asm("v_cvt_pk_bf16_f32 %0, %1, %2" : "=v"(w1) : "v"(p[o8+2]), "v"(p[o8+3]));
            asm("v_cvt_pk_bf16_f32 %0, %1, %2" : "=v"(w2) : "v"(p[o8+4]), "v"(p[o8+5]));
            asm("v_cvt_pk_bf16_f32 %0, %1, %2" : "=v"(w3) : "v"(p[o8+6]), "v"(p[o8+7]));
            asm("v_permlane32_swap_b32 %0, %1" : "+v"(w0), "+v"(w2));
            asm("v_permlane32_swap_b32 %0, %1" : "+v"(w1), "+v"(w3));
            u32x4 pw = { w0, w1, w2, w3 };
            pa[ks] = __builtin_bit_cast(short8, pw);
        }

        o0 = MFMA32(pa[0], vf_[0], o0);
        o1 = MFMA32(pa[0], vf_[1], o1);
        o0 = MFMA32(pa[1], vf_[2], o0);
        o1 = MFMA32(pa[1], vf_[3], o1);
    };

    STAGE(KA, 0);
    __syncthreads();
    for (int kc = 0; kc < 64; kc += 2) {
        STAGE(KB, kc + 1);          // next chunk's loads fly under compute
        comp(KA);
        __syncthreads();            // publishes KB, guards KA reuse
        if (kc + 2 < 64) STAGE(KA, kc + 2);
        comp(KB);
        __syncthreads();
    }

    int b_ = bh >> 4, h = bh & 15;
#pragma unroll
    for (int r = 0; r < 16; r++) {
        int crow = (r & 3) + 8*(r >> 2) + 4*hi;
        float inv = 1.0f / rowsum[bh * 2048 + qb + crow];
        size_t base = ((size_t)(b_*2048 + qb + crow)) * 1024 + h*64;
        concat[base + lq]      = f2bf(o0[r] * inv);
        concat[base + 32 + lq] = f2bf(o1[r] * inv);
    }
}

extern "C" void kernel_launch(void* const* d_in, const int* in_sizes, int n_in,
                              void* d_out, int out_size, void* d_ws, size_t ws_size,
                              hipStream_t stream)
{
    const float* q  = (const float*)d_in[0];
    const float* k  = (const float*)d_in[1];
    const float* v  = (const float*)d_in[2];
    const float* Wq = (const float*)d_in[3];
    const float* bq = (const float*)d_in[4];
    const float* Wk = (const float*)d_in[5];
    const float* bk = (const float*)d_in[6];
    const float* Wv = (const float*)d_in[7];
    const float* bv = (const float*)d_in[8];
    const float* Wo = (const float*)d_in[9];
    const float* bo = (const float*)d_in[10];

    char* ws = (char*)d_ws;
    size_t off = 0;
    auto alloc = [&](size_t bytes) -> void* {
        void* p = ws + off;
        off += (bytes + 255) & ~(size_t)255;
        return p;
    };
    const size_t ASZ = (size_t)4096 * 1024 * 2;   // 8.4 MB bf16 activation
    const size_t WSZ = (size_t)1024 * 1024 * 2;   // 2 MB bf16 weight
    unsigned short* qh_ = (unsigned short*)alloc(ASZ);
    unsigned short* ql_ = (unsigned short*)alloc(ASZ);
    unsigned short* kh_ = (unsigned short*)alloc(ASZ);
    unsigned short* kl_ = (unsigned short*)alloc(ASZ);
    unsigned short* vh_ = (unsigned short*)alloc(ASZ);
    unsigned short* vl_ = (unsigned short*)alloc(ASZ);
    unsigned short* wqh = (unsigned short*)alloc(WSZ);
    unsigned short* wql = (unsigned short*)alloc(WSZ);
    unsigned short* wkh = (unsigned short*)alloc(WSZ);
    unsigned short* wkl = (unsigned short*)alloc(WSZ);
    unsigned short* wvh = (unsigned short*)alloc(WSZ);
    unsigned short* wvl = (unsigned short*)alloc(WSZ);
    unsigned short* woh = (unsigned short*)alloc(WSZ);
    unsigned short* wol = (unsigned short*)alloc(WSZ);
    short* Qhi = (short*)alloc(ASZ);
    short* Qlo = (short*)alloc(ASZ);
    short* Khi = (short*)alloc(ASZ);   // frag-major
    short* Klo = (short*)alloc(ASZ);   // frag-major
    short* Vt  = (short*)alloc(ASZ);   // frag-major
    float* rowsum = (float*)alloc((size_t)32 * 2048 * 4);
    float* colsum = (float*)alloc((size_t)32 * 2048 * 4);
    float* maskf  = (float*)alloc((size_t)32 * 2048 * 4);
    unsigned short* concat = (unsigned short*)alloc(ASZ);
    // total ~118 MB (known-safe)

    dim3 blk(256);
    const int An4 = 4096 * 1024 / 4, Wn4 = 1024 * 1024 / 4;

    cvt_split<<<An4/256, blk, 0, stream>>>(q,  qh_, ql_, An4);
    cvt_split<<<An4/256, blk, 0, stream>>>(k,  kh_, kl_, An4);
    cvt_split<<<An4/256, blk, 0, stream>>>(v,  vh_, vl_, An4);
    cvt_split<<<Wn4/256, blk, 0, stream>>>(Wq, wqh, wql, Wn4);
    cvt_split<<<Wn4/256, blk, 0, stream>>>(Wk, wkh, wkl, Wn4);
    cvt_split<<<Wn4/256, blk, 0, stream>>>(Wv, wvh, wvl, Wn4);
    cvt_split<<<Wn4/256, blk, 0, stream>>>(Wo, woh, wol, Wn4);
    zero_f32 <<<dim3(512), blk, 0, stream>>>(rowsum, 2 * 32 * 2048);  // rowsum+colsum

    gemm_qkv<<<dim3(8, 32, 3), blk, 0, stream>>>(
        (const short*)qh_, (const short*)ql_, (const short*)kh_, (const short*)kl_,
        (const short*)vh_, (const short*)vl_,
        (const short*)wqh, (const short*)wql, (const short*)wkh, (const short*)wkl,
        (const short*)wvh, (const short*)wvl,
        bq, bk, bv,
        (unsigned short*)Qhi, (unsigned short*)Qlo,
        (unsigned short*)Khi, (unsigned short*)Klo, (unsigned short*)Vt);

    attn_rowsum<<<dim3(8, 4, 32), blk, 0, stream>>>(Qhi, Qlo, Khi, Klo, rowsum);
    attn_colsum<<<dim3(8, 4, 32), blk, 0, stream>>>(Qhi, Qlo, Khi, Klo, rowsum, colsum);
    topk_mask  <<<dim3(32),   blk, 0, stream>>>(colsum, maskf);
    mask_v     <<<dim3(2048), blk, 0, stream>>>((unsigned short*)Vt, maskf);
    attn_av    <<<dim3(16, 32), blk, 0, stream>>>(Qhi, Khi, Vt, rowsum, concat);

    gemm_out<<<dim3(8, 32), blk, 0, stream>>>((const short*)concat,
        (const short*)woh, (const short*)wol, bo, (float*)d_out);
}

// Round 5
// 483.305 us; speedup vs baseline: 1.4783x; 1.0538x over previous
//
#include <hip/hip_runtime.h>

// ---------------------------------------------------------------------------
// Pruned multi-head attention. fp32 I/O, split-bf16 (hi+lo) MFMA compute.
// B=2, S=2048, D_MODEL=1024, H=16, d_k=64, keep=int(2048*0.9)=1843
//
// Round 13: gemm_qkv/gemm_out LDS reads were 8-way bank-conflicted (64B row
// stride): T2 both-sides swizzle (chunk ^= (row>>1)&3; pre-swizzled global
// source + swizzled read, rule #21 involution). XCD-chunked block remap so
// the 8 blocks sharing an A-row-panel land on ONE XCD (FETCH 203MB->~80).
// attn_rowsum switched to hi-only scores (consistent with attn_av's
// numerator; 3x less MFMA). attn_av gets XCD remap too.
// ---------------------------------------------------------------------------

typedef __attribute__((ext_vector_type(8))) short short8;   // 8 bf16 (4 VGPRs)
typedef __attribute__((ext_vector_type(4))) short short4v;
typedef __attribute__((ext_vector_type(4))) float f32x4;
typedef __attribute__((ext_vector_type(16))) float f32x16;
typedef __attribute__((ext_vector_type(4))) unsigned int u32x4;

#define KEEP 1843

#if __has_builtin(__builtin_amdgcn_exp2f)
  #define PEXP(x) __builtin_amdgcn_exp2f(x)
  #define QSC 0.18033688011112042f   // log2(e)/8 folded into Q projection
#else
  #define PEXP(x) __expf(x)
  #define QSC 0.125f
#endif

#define AS1(p) ((const __attribute__((address_space(1))) void*)(p))
#define AS3(p) ((__attribute__((address_space(3))) void*)(p))

static __device__ __forceinline__ float bf2f(unsigned short s) {
    union { unsigned u; float f; } v; v.u = ((unsigned)s) << 16; return v.f;
}
static __device__ __forceinline__ unsigned short f2bf(float f) {
    union { float f; unsigned u; } v; v.f = f;
    unsigned u = v.u;
    unsigned r = (u + 0x7FFFu + ((u >> 16) & 1u)) >> 16;   // RNE
    return (unsigned short)r;
}

#define MFMA(A, B, C)   __builtin_amdgcn_mfma_f32_16x16x32_bf16(A, B, C, 0, 0, 0)
#define MFMA32(A, B, C) __builtin_amdgcn_mfma_f32_32x32x16_bf16(A, B, C, 0, 0, 0)

// fp32 array -> hi/lo bf16 arrays (x = hi + lo to ~2^-17 relative)
__global__ __launch_bounds__(256) void cvt_split(
    const float* __restrict__ in, unsigned short* __restrict__ hi,
    unsigned short* __restrict__ lo, int n4)
{
    int i = blockIdx.x * 256 + threadIdx.x;
    if (i >= n4) return;
    f32x4 x = ((const f32x4*)in)[i];
    short4v h, l;
#pragma unroll
    for (int j = 0; j < 4; j++) {
        unsigned short hv = f2bf(x[j]);
        h[j] = (short)hv;
        l[j] = (short)f2bf(x[j] - bf2f(hv));
    }
    ((short4v*)hi)[i] = h;
    ((short4v*)lo)[i] = l;
}

__global__ __launch_bounds__(256) void zero_f32(float* __restrict__ p, int n) {
    int i = blockIdx.x * 256 + threadIdx.x;
    if (i < n) p[i] = 0.f;
}

// Fused Q/K/V projections, LDS-staged, bank-conflict-swizzled. 128x128, BK=32.
// z=0: Q row layout hi+lo scaled QSC; z=1: K frag-major hi+lo; z=2: V frag-major.
__global__ __launch_bounds__(256) void gemm_qkv(
    const short* __restrict__ A0, const short* __restrict__ Al0,
    const short* __restrict__ A1, const short* __restrict__ Al1,
    const short* __restrict__ A2, const short* __restrict__ Al2,
    const short* __restrict__ W0, const short* __restrict__ Wl0,
    const short* __restrict__ W1, const short* __restrict__ Wl1,
    const short* __restrict__ W2, const short* __restrict__ Wl2,
    const float* __restrict__ b0, const float* __restrict__ b1,
    const float* __restrict__ b2,
    unsigned short* __restrict__ Qhi, unsigned short* __restrict__ Qlo,
    unsigned short* __restrict__ Khi, unsigned short* __restrict__ Klo,
    unsigned short* __restrict__ Vt)
{
    // XCD-chunked remap: consecutive hardware ids (lin%8 = XCD) own a
    // contiguous tile range; each A-row-panel (8 x-tiles) stays on one XCD.
    int lin = blockIdx.x + (blockIdx.y << 3) + (blockIdx.z << 8);   // [0,768)
    int tile = (lin & 7) * 96 + (lin >> 3);
    int bx = tile & 7, by = (tile >> 3) & 31, bz = tile >> 8;

    const short *Ahg, *Alg, *Whg, *Wlg; const float* bias;
    unsigned short *oh = 0, *ol = 0; float scale; int mode;
    if (bz == 0)      { Ahg=A0; Alg=Al0; Whg=W0; Wlg=Wl0; bias=b0; oh=Qhi; ol=Qlo; scale=QSC;  mode=0; }
    else if (bz == 1) { Ahg=A1; Alg=Al1; Whg=W1; Wlg=Wl1; bias=b1; oh=Khi; ol=Klo; scale=1.0f; mode=1; }
    else              { Ahg=A2; Alg=Al2; Whg=W2; Wlg=Wl2; bias=b2; oh=Vt;          scale=1.0f; mode=2; }

    __shared__ __align__(16) short Ah_l[128*32];
    __shared__ __align__(16) short Al_l[128*32];
    __shared__ __align__(16) short Wh_l[128*32];
    __shared__ __align__(16) short Wl_l[128*32];

    int tid  = threadIdx.x;
    int w    = tid >> 6;
    int lane = tid & 63;
    int ln   = lane & 15;
    int quad = lane >> 4;
    int rowBase = by * 128;
    int colBase = bx * 128;
    int mBase = (w & 1) * 64;        // wave's quadrant inside 128x128
    int nBase = (w >> 1) * 64;

    // staging: lane -> row r0+(lane>>2); source chunk pre-swizzled so the
    // linear LDS dest holds chunk c' = c ^ ((row>>1)&3)  (involution).
    int srow = (lane >> 2);
    int scol = (((lane & 3) ^ ((lane >> 3) & 3))) * 8;
    // read-side swizzled chunk offset (shorts): rows differ by 16 per frag,
    // so (r>>1)&3 == (ln>>1)&3 for every fragment row.
    int cs = ((quad ^ ((ln >> 1) & 3))) * 8;

    const short* Ag_h = Ahg + (size_t)rowBase * 1024;
    const short* Ag_l = Alg + (size_t)rowBase * 1024;
    const short* Wg_h = Whg + (size_t)colBase * 1024;
    const short* Wg_l = Wlg + (size_t)colBase * 1024;

    f32x4 acc[4][4];
#pragma unroll
    for (int i = 0; i < 4; i++)
#pragma unroll
        for (int j = 0; j < 4; j++) acc[i][j] = (f32x4){0.f, 0.f, 0.f, 0.f};

    for (int kk = 0; kk < 1024; kk += 32) {
#pragma unroll
        for (int j = 0; j < 2; j++) {
            int r = w*32 + j*16;
            size_t go = (size_t)(r + srow) * 1024 + kk + scol;
            __builtin_amdgcn_global_load_lds(AS1(Ag_h + go), AS3(Ah_l + r*32), 16, 0, 0);
            __builtin_amdgcn_global_load_lds(AS1(Ag_l + go), AS3(Al_l + r*32), 16, 0, 0);
            __builtin_amdgcn_global_load_lds(AS1(Wg_h + go), AS3(Wh_l + r*32), 16, 0, 0);
            __builtin_amdgcn_global_load_lds(AS1(Wg_l + go), AS3(Wl_l + r*32), 16, 0, 0);
        }
        __syncthreads();

        short8 ah[4], al[4], bh[4], bl[4];
#pragma unroll
        for (int mt = 0; mt < 4; mt++) {
            int r = mBase + mt*16 + ln;
            ah[mt] = *(const short8*)(Ah_l + r*32 + cs);
            al[mt] = *(const short8*)(Al_l + r*32 + cs);
        }
#pragma unroll
        for (int nt = 0; nt < 4; nt++) {
            int c = nBase + nt*16 + ln;
            bh[nt] = *(const short8*)(Wh_l + c*32 + cs);
            bl[nt] = *(const short8*)(Wl_l + c*32 + cs);
        }
#pragma unroll
        for (int mt = 0; mt < 4; mt++)
#pragma unroll
            for (int nt = 0; nt < 4; nt++) {
                acc[mt][nt] = MFMA(ah[mt], bh[nt], acc[mt][nt]);
                acc[mt][nt] = MFMA(ah[mt], bl[nt], acc[mt][nt]);
                acc[mt][nt] = MFMA(al[mt], bh[nt], acc[mt][nt]);
            }
        __syncthreads();
    }

#pragma unroll
    for (int mt = 0; mt < 4; mt++) {
#pragma unroll
        for (int nt = 0; nt < 4; nt++) {
            int col = colBase + nBase + nt*16 + ln;
            float bv = bias[col];
#pragma unroll
            for (int i = 0; i < 4; i++) {
                int row = rowBase + mBase + mt*16 + quad*4 + i;   // D: row=quad*4+reg
                float val = (acc[mt][nt][i] + bv) * scale;
                int b_  = row >> 11, s = row & 2047;
                int h   = col >> 6,  d = col & 63;
                int bh_ = b_ * 16 + h;
                if (mode == 2) {
                    size_t idx = (size_t)bh_ * 131072 + (size_t)(s >> 5) * 2048
                        + ((size_t)((((((s >> 4) & 1) * 2 + (d >> 5)) * 2 + ((s >> 3) & 1)) * 32)
                                    + (d & 31))) * 8 + (s & 7);
                    oh[idx] = f2bf(val);
                } else if (mode == 1) {
                    size_t idx = (size_t)bh_ * 131072 + (size_t)(s >> 5) * 2048
                        + ((size_t)(((d >> 4) * 2 + ((d >> 3) & 1)) * 32 + (s & 31))) * 8 + (d & 7);
                    unsigned short hv = f2bf(val);
                    oh[idx] = hv;
                    ol[idx] = f2bf(val - bf2f(hv));
                } else {
                    size_t idx = ((size_t)bh_ * 2048 + s) * 64 + d;
                    unsigned short hv = f2bf(val);
                    oh[idx] = hv;
                    ol[idx] = f2bf(val - bf2f(hv));
                }
            }
        }
    }
}

// out = concat(bf16) @ Wo^T + bo (split Wo, fp32 out), LDS-staged + swizzled.
__global__ __launch_bounds__(256) void gemm_out(
    const short* __restrict__ Ag, const short* __restrict__ Whg,
    const short* __restrict__ Wlg, const float* __restrict__ bias,
    float* __restrict__ out)
{
    int lin = blockIdx.x + (blockIdx.y << 3);                  // [0,256)
    int tile = (lin & 7) * 32 + (lin >> 3);
    int bx = tile & 7, by = tile >> 3;

    __shared__ __align__(16) short A_l[128*32];
    __shared__ __align__(16) short Wh_l[128*32];
    __shared__ __align__(16) short Wl_l[128*32];

    int tid  = threadIdx.x;
    int w    = tid >> 6;
    int lane = tid & 63;
    int ln   = lane & 15;
    int quad = lane >> 4;
    int rowBase = by * 128;
    int colBase = bx * 128;
    int mBase = (w & 1) * 64;
    int nBase = (w >> 1) * 64;

    int srow = (lane >> 2);
    int scol = (((lane & 3) ^ ((lane >> 3) & 3))) * 8;
    int cs = ((quad ^ ((ln >> 1) & 3))) * 8;
    const short* Abase = Ag  + (size_t)rowBase * 1024;
    const short* Whb   = Whg + (size_t)colBase * 1024;
    const short* Wlb   = Wlg + (size_t)colBase * 1024;

    f32x4 acc[4][4];
#pragma unroll
    for (int i = 0; i < 4; i++)
#pragma unroll
        for (int j = 0; j < 4; j++) acc[i][j] = (f32x4){0.f, 0.f, 0.f, 0.f};

    for (int kk = 0; kk < 1024; kk += 32) {
#pragma unroll
        for (int j = 0; j < 2; j++) {
            int r = w*32 + j*16;
            size_t go = (size_t)(r + srow) * 1024 + kk + scol;
            __builtin_amdgcn_global_load_lds(AS1(Abase + go), AS3(A_l  + r*32), 16, 0, 0);
            __builtin_amdgcn_global_load_lds(AS1(Whb   + go), AS3(Wh_l + r*32), 16, 0, 0);
            __builtin_amdgcn_global_load_lds(AS1(Wlb   + go), AS3(Wl_l + r*32), 16, 0, 0);
        }
        __syncthreads();

        short8 a[4], bh[4], bl[4];
#pragma unroll
        for (int mt = 0; mt < 4; mt++)
            a[mt] = *(const short8*)(A_l + (mBase + mt*16 + ln)*32 + cs);
#pragma unroll
        for (int nt = 0; nt < 4; nt++) {
            int c = nBase + nt*16 + ln;
            bh[nt] = *(const short8*)(Wh_l + c*32 + cs);
            bl[nt] = *(const short8*)(Wl_l + c*32 + cs);
        }
#pragma unroll
        for (int mt = 0; mt < 4; mt++)
#pragma unroll
            for (int nt = 0; nt < 4; nt++) {
                acc[mt][nt] = MFMA(a[mt], bh[nt], acc[mt][nt]);
                acc[mt][nt] = MFMA(a[mt], bl[nt], acc[mt][nt]);
            }
        __syncthreads();
    }

#pragma unroll
    for (int mt = 0; mt < 4; mt++) {
#pragma unroll
        for (int nt = 0; nt < 4; nt++) {
            int col = colBase + nBase + nt*16 + ln;
            float bv = bias[col];
#pragma unroll
            for (int i = 0; i < 4; i++) {
                int row = rowBase + mBase + mt*16 + quad*4 + i;
                out[(size_t)row * 1024 + col] = acc[mt][nt][i] + bv;
            }
        }
    }
}

// rowsum[q] += sum over this block's k-quarter of 2^(c_qk), HI-ONLY scores
// (numerically consistent with attn_av's numerator; common-mode cancels).
__global__ __launch_bounds__(256) void attn_rowsum(
    const short* __restrict__ Qhi, const short* __restrict__ Khi,
    float* __restrict__ rowsum)
{
    int bh = blockIdx.z, tid = threadIdx.x;
    int w = tid >> 6, lane = tid & 63, ln = lane & 15, quad = lane >> 4;
    int qb  = blockIdx.x * 256 + w * 64;
    int kt0 = blockIdx.y * 32;            // 32 k-tiles of 16 = 512 keys
    const short* QH = Qhi + (size_t)bh * 2048 * 64;
    const short* KH = Khi + (size_t)bh * 131072;

    short8 qh[4][2];
#pragma unroll
    for (int mt = 0; mt < 4; mt++)
#pragma unroll
        for (int half = 0; half < 2; half++) {
            size_t o = (size_t)(qb + mt*16 + ln) * 64 + half*32 + quad*8;
            qh[mt][half] = *(const short8*)(QH + o);
        }

    short8 kh[2][2];   // [buf][dchunk]
    auto loadK = [&](int buf, int kt) {
        size_t ko = (size_t)(kt >> 1) * 2048 + (size_t)quad * 256 + ((kt & 1) * 16 + ln) * 8;
        kh[buf][0] = *(const short8*)(KH + ko);
        kh[buf][1] = *(const short8*)(KH + ko + 1024);
    };

    float racc[4][4] = {};
    auto comp = [&](int buf) {
#pragma unroll
        for (int mt = 0; mt < 4; mt++) {
            f32x4 c1 = (f32x4){0.f,0.f,0.f,0.f};
            c1 = MFMA(qh[mt][0], kh[buf][0], c1);
            c1 = MFMA(qh[mt][1], kh[buf][1], c1);
#pragma unroll
            for (int i = 0; i < 4; i++)
                racc[mt][i] += PEXP(c1[i]);
        }
    };

    loadK(0, kt0);
    for (int t = 0; t < 32; t += 2) {
        loadK(1, kt0 + t + 1);
        comp(0);
        if (t + 2 < 32) loadK(0, kt0 + t + 2);
        comp(1);
    }
#pragma unroll
    for (int mt = 0; mt < 4; mt++)
#pragma unroll
        for (int i = 0; i < 4; i++)
            for (int d = 1; d < 16; d <<= 1)
                racc[mt][i] += __shfl_xor(racc[mt][i], d, 64);
    if (ln == 0) {
#pragma unroll
        for (int mt = 0; mt < 4; mt++)
#pragma unroll
            for (int i = 0; i < 4; i++)
                atomicAdd(&rowsum[bh * 2048 + qb + mt*16 + quad*4 + i], racc[mt][i]);
    }
}

// colsum[k] += sum over this block's q-quarter of 2^(c_qk)/rowsum[q].
// 3-term split kept (feeds the top-k ranking).
__global__ __launch_bounds__(256) void attn_colsum(
    const short* __restrict__ Qhi, const short* __restrict__ Qlo,
    const short* __restrict__ Khi, const short* __restrict__ Klo,
    const float* __restrict__ rowsum, float* __restrict__ colsum)
{
    __shared__ float sli[512];
    int bh = blockIdx.z, tid = threadIdx.x;
    int q0 = blockIdx.y * 512;
    for (int j = tid; j < 512; j += 256)
        sli[j] = 1.0f / rowsum[bh * 2048 + q0 + j];
    __syncthreads();

    int w = tid >> 6, lane = tid & 63, ln = lane & 15, quad = lane >> 4;
    int kb  = blockIdx.x * 256 + w * 64;
    int qt0 = blockIdx.y * 32;            // 32 q-tiles of 16
    const short* QH = Qhi + (size_t)bh * 2048 * 64;
    const short* QL = Qlo + (size_t)bh * 2048 * 64;
    const short* KH = Khi + (size_t)bh * 131072;
    const short* KL = Klo + (size_t)bh * 131072;

    short8 kh[4][2], kl[4][2];
#pragma unroll
    for (int nt = 0; nt < 4; nt++)
#pragma unroll
        for (int half = 0; half < 2; half++) {
            size_t o = (size_t)((kb >> 5) + (nt >> 1)) * 2048 + (size_t)half * 1024
                     + (size_t)quad * 256 + ((nt & 1) * 16 + ln) * 8;
            kh[nt][half] = *(const short8*)(KH + o);
            kl[nt][half] = *(const short8*)(KL + o);
        }

    short8 qh[2][2], ql[2][2];   // [buf][half]
    auto loadQ = [&](int buf, int qt) {
        size_t qo = (size_t)((qt0 + qt)*16 + ln) * 64 + quad*8;
        qh[buf][0] = *(const short8*)(QH + qo);
        qh[buf][1] = *(const short8*)(QH + qo + 32);
        ql[buf][0] = *(const short8*)(QL + qo);
        ql[buf][1] = *(const short8*)(QL + qo + 32);
    };

    float cacc[4] = {0.f, 0.f, 0.f, 0.f};
    auto comp = [&](int buf, int qt) {
#pragma unroll
        for (int nt = 0; nt < 4; nt++) {
            f32x4 c1 = (f32x4){0.f,0.f,0.f,0.f};
            f32x4 c2 = (f32x4){0.f,0.f,0.f,0.f};
            c1 = MFMA(qh[buf][0], kh[nt][0], c1); c1 = MFMA(qh[buf][1], kh[nt][1], c1);
            c2 = MFMA(qh[buf][0], kl[nt][0], c2); c2 = MFMA(qh[buf][1], kl[nt][1], c2);
            c2 = MFMA(ql[buf][0], kh[nt][0], c2); c2 = MFMA(ql[buf][1], kh[nt][1], c2);
#pragma unroll
            for (int i = 0; i < 4; i++) {
                int r = qt*16 + quad*4 + i;
                cacc[nt] += PEXP(c1[i] + c2[i]) * sli[r];
            }
        }
    };

    loadQ(0, 0);
    for (int qt = 0; qt < 32; qt += 2) {
        loadQ(1, qt + 1);
        comp(0, qt);
        if (qt + 2 < 32) loadQ(0, qt + 2);
        comp(1, qt + 1);
    }
#pragma unroll
    for (int nt = 0; nt < 4; nt++) {
        cacc[nt] += __shfl_xor(cacc[nt], 16, 64);
        cacc[nt] += __shfl_xor(cacc[nt], 32, 64);
        if (lane < 16) atomicAdd(&colsum[bh * 2048 + kb + nt*16 + lane], cacc[nt]);
    }
}

// Per (b,h): threshold = KEEP-th largest col_sum; mask = col_sum >= threshold.
__global__ __launch_bounds__(256) void topk_mask(
    const float* __restrict__ colsum, float* __restrict__ maskf)
{
    __shared__ unsigned keys[2048];
    __shared__ int cnt;
    int bh = blockIdx.x, tid = threadIdx.x;
    for (int j = tid; j < 2048; j += 256) {
        unsigned u = __float_as_uint(colsum[bh * 2048 + j]);
        keys[j] = (u & 0x80000000u) ? ~u : (u | 0x80000000u);
    }
    __syncthreads();
    unsigned long long lo = 0, hi = 0x100000000ULL;
    while (hi - lo > 1) {
        unsigned long long mid = (lo + hi) >> 1;
        if (tid == 0) cnt = 0;
        __syncthreads();
        int local = 0;
        for (int j = tid; j < 2048; j += 256) local += (keys[j] >= (unsigned)mid) ? 1 : 0;
        atomicAdd(&cnt, local);
        __syncthreads();
        int c = cnt;
        __syncthreads();
        if (c >= KEEP) lo = mid; else hi = mid;
    }
    unsigned thr = (unsigned)lo;
    for (int j = tid; j < 2048; j += 256)
        maskf[bh * 2048 + j] = (keys[j] >= thr) ? 1.0f : 0.0f;
}

// V (frag-major) *= mask. Group g of 8 shorts covers 8 consecutive k for one d:
// k0 = (g>>8)*32 + ((g>>7)&1)*16 + ((g>>5)&1)*8
__global__ __launch_bounds__(256) void mask_v(
    unsigned short* __restrict__ Vt, const float* __restrict__ maskf)
{
    int i = blockIdx.x * 256 + threadIdx.x;   // short8 group; 32 bh x 16384 groups
    int g  = i & 16383;
    int bh = i >> 14;
    int k0 = (g >> 8) * 32 + ((g >> 7) & 1) * 16 + ((g >> 5) & 1) * 8;
    const float* m = maskf + bh * 2048 + k0;
    short8 v = ((short8*)Vt)[i];
#pragma unroll
    for (int j = 0; j < 8; j++)
        if (m[j] == 0.0f) v[j] = 0;
    ((short8*)Vt)[i] = v;
}

// PV with swapped-operand QK^T, in-register P, block-level LDS staging of
// frag-major K/V chunks. XCD-chunked remap keeps a bh's blocks on one XCD.
__global__ __launch_bounds__(256) void attn_av(
    const short* __restrict__ Qhi, const short* __restrict__ Kf,
    const short* __restrict__ Vf, const float* __restrict__ rowsum,
    unsigned short* __restrict__ concat)
{
    __shared__ __align__(16) short KA[4096];   // [0,2048): K chunk, [2048,4096): V chunk
    __shared__ __align__(16) short KB[4096];
    int lin = blockIdx.x + (blockIdx.y << 4);          // [0,512)
    int tile = (lin & 7) * 64 + (lin >> 3);
    int bxx = tile & 15, bh = tile >> 4;
    int tid = threadIdx.x;
    int w = tid >> 6, lane = tid & 63;
    int lq = lane & 31, hi = lane >> 5;
    int qb = bxx * 128 + w * 32;
    const short* Q  = Qhi + (size_t)bh * 2048 * 64;
    const short* Kg = Kf  + (size_t)bh * 131072;
    const short* Vg = Vf  + (size_t)bh * 131072;

    // Q^T B-frags: lane holds Q[qb+lq][d*16 + hi*8 + j]  (read once)
    short8 qf[4];
#pragma unroll
    for (int d = 0; d < 4; d++)
        qf[d] = *(const short8*)(Q + (size_t)(qb + lq) * 64 + d*16 + hi*8);

    f32x16 o0, o1;
#pragma unroll
    for (int i = 0; i < 16; i++) { o0[i] = 0.f; o1[i] = 0.f; }

    auto STAGE = [&](short* B, int kc) {
        __builtin_amdgcn_global_load_lds(AS1(Kg + (size_t)kc*2048 + tid*8),
                                         AS3(B + w*512), 16, 0, 0);
        __builtin_amdgcn_global_load_lds(AS1(Vg + (size_t)kc*2048 + tid*8),
                                         AS3(B + 2048 + w*512), 16, 0, 0);
    };

    auto comp = [&](const short* B) {
        short8 kf_[4], vf_[4];
#pragma unroll
        for (int d = 0; d < 4; d++)
            kf_[d] = *(const short8*)(B + (d*2 + hi)*256 + lq*8);
#pragma unroll
        for (int ks = 0; ks < 2; ks++)
#pragma unroll
            for (int nt = 0; nt < 2; nt++)
                vf_[ks*2+nt] = *(const short8*)(B + 2048 + ((ks*2+nt)*2 + hi)*256 + lq*8);

        f32x16 s;
#pragma unroll
        for (int i = 0; i < 16; i++) s[i] = 0.f;
        s = MFMA32(kf_[0], qf[0], s);
        s = MFMA32(kf_[1], qf[1], s);
        s = MFMA32(kf_[2], qf[2], s);
        s = MFMA32(kf_[3], qf[3], s);

        float p[16];
#pragma unroll
        for (int i = 0; i < 16; i++) p[i] = PEXP(s[i]);

        short8 pa[2];
#pragma unroll
        for (int ks = 0; ks < 2; ks++) {
            unsigned w0, w1, w2, w3;
            int o8 = ks * 8;
            asm("v_cvt_pk_bf16_f32 %0, %1, %2" : "=v"(w0) : "v"(p[o8+0]), "v"(p[o8+1]));
            asm("v_cvt_pk_bf16_f32 %0, %1, %2" : "=v"(w1) : "v"(p[o8+2]), "v"(p[o8+3]));
            asm("v_cvt_pk_bf16_f32 %0, %1, %2" : "=v"(w2) : "v"(p[o8+4]), "v"(p[o8+5]));
            asm("v_cvt_pk_bf16_f32 %0, %1, %2" : "=v"(w3) : "v"(p[o8+6]), "v"(p[o8+7]));
            asm("v_permlane32_swap_b32 %0, %1" : "+v"(w0), "+v"(w2));
            asm("v_permlane32_swap_b32 %0, %1" : "+v"(w1), "+v"(w3));
            u32x4 pw = { w0, w1, w2, w3 };
            pa[ks] = __builtin_bit_cast(short8, pw);
        }

        o0 = MFMA32(pa[0], vf_[0], o0);
        o1 = MFMA32(pa[0], vf_[1], o1);
        o0 = MFMA32(pa[1], vf_[2], o0);
        o1 = MFMA32(pa[1], vf_[3], o1);
    };

    STAGE(KA, 0);
    __syncthreads();
    for (int kc = 0; kc < 64; kc += 2) {
        STAGE(KB, kc + 1);          // next chunk's loads fly under compute
        comp(KA);
        __syncthreads();            // publishes KB, guards KA reuse
        if (kc + 2 < 64) STAGE(KA, kc + 2);
        comp(KB);
        __syncthreads();
    }

    int b_ = bh >> 4, h = bh & 15;
#pragma unroll
    for (int r = 0; r < 16; r++) {
        int crow = (r & 3) + 8*(r >> 2) + 4*hi;
        float inv = 1.0f / rowsum[bh * 2048 + qb + crow];
        size_t base = ((size_t)(b_*2048 + qb + crow)) * 1024 + h*64;
        concat[base + lq]      = f2bf(o0[r] * inv);
        concat[base + 32 + lq] = f2bf(o1[r] * inv);
    }
}

extern "C" void kernel_launch(void* const* d_in, const int* in_sizes, int n_in,
                              void* d_out, int out_size, void* d_ws, size_t ws_size,
                              hipStream_t stream)
{
    const float* q  = (const float*)d_in[0];
    const float* k  = (const float*)d_in[1];
    const float* v  = (const float*)d_in[2];
    const float* Wq = (const float*)d_in[3];
    const float* bq = (const float*)d_in[4];
    const float* Wk = (const float*)d_in[5];
    const float* bk = (const float*)d_in[6];
    const float* Wv = (const float*)d_in[7];
    const float* bv = (const float*)d_in[8];
    const float* Wo = (const float*)d_in[9];
    const float* bo = (const float*)d_in[10];

    char* ws = (char*)d_ws;
    size_t off = 0;
    auto alloc = [&](size_t bytes) -> void* {
        void* p = ws + off;
        off += (bytes + 255) & ~(size_t)255;
        return p;
    };
    const size_t ASZ = (size_t)4096 * 1024 * 2;   // 8.4 MB bf16 activation
    const size_t WSZ = (size_t)1024 * 1024 * 2;   // 2 MB bf16 weight
    unsigned short* qh_ = (unsigned short*)alloc(ASZ);
    unsigned short* ql_ = (unsigned short*)alloc(ASZ);
    unsigned short* kh_ = (unsigned short*)alloc(ASZ);
    unsigned short* kl_ = (unsigned short*)alloc(ASZ);
    unsigned short* vh_ = (unsigned short*)alloc(ASZ);
    unsigned short* vl_ = (unsigned short*)alloc(ASZ);
    unsigned short* wqh = (unsigned short*)alloc(WSZ);
    unsigned short* wql = (unsigned short*)alloc(WSZ);
    unsigned short* wkh = (unsigned short*)alloc(WSZ);
    unsigned short* wkl = (unsigned short*)alloc(WSZ);
    unsigned short* wvh = (unsigned short*)alloc(WSZ);
    unsigned short* wvl = (unsigned short*)alloc(WSZ);
    unsigned short* woh = (unsigned short*)alloc(WSZ);
    unsigned short* wol = (unsigned short*)alloc(WSZ);
    short* Qhi = (short*)alloc(ASZ);
    short* Qlo = (short*)alloc(ASZ);
    short* Khi = (short*)alloc(ASZ);   // frag-major
    short* Klo = (short*)alloc(ASZ);   // frag-major
    short* Vt  = (short*)alloc(ASZ);   // frag-major
    float* rowsum = (float*)alloc((size_t)32 * 2048 * 4);
    float* colsum = (float*)alloc((size_t)32 * 2048 * 4);
    float* maskf  = (float*)alloc((size_t)32 * 2048 * 4);
    unsigned short* concat = (unsigned short*)alloc(ASZ);
    // total ~118 MB (known-safe)

    dim3 blk(256);
    const int An4 = 4096 * 1024 / 4, Wn4 = 1024 * 1024 / 4;

    cvt_split<<<An4/256, blk, 0, stream>>>(q,  qh_, ql_, An4);
    cvt_split<<<An4/256, blk, 0, stream>>>(k,  kh_, kl_, An4);
    cvt_split<<<An4/256, blk, 0, stream>>>(v,  vh_, vl_, An4);
    cvt_split<<<Wn4/256, blk, 0, stream>>>(Wq, wqh, wql, Wn4);
    cvt_split<<<Wn4/256, blk, 0, stream>>>(Wk, wkh, wkl, Wn4);
    cvt_split<<<Wn4/256, blk, 0, stream>>>(Wv, wvh, wvl, Wn4);
    cvt_split<<<Wn4/256, blk, 0, stream>>>(Wo, woh, wol, Wn4);
    zero_f32 <<<dim3(512), blk, 0, stream>>>(rowsum, 2 * 32 * 2048);  // rowsum+colsum

    gemm_qkv<<<dim3(8, 32, 3), blk, 0, stream>>>(
        (const short*)qh_, (const short*)ql_, (const short*)kh_, (const short*)kl_,
        (const short*)vh_, (const short*)vl_,
        (const short*)wqh, (const short*)wql, (const short*)wkh, (const short*)wkl,
        (const short*)wvh, (const short*)wvl,
        bq, bk, bv,
        (unsigned short*)Qhi, (unsigned short*)Qlo,
        (unsigned short*)Khi, (unsigned short*)Klo, (unsigned short*)Vt);

    attn_rowsum<<<dim3(8, 4, 32), blk, 0, stream>>>(Qhi, Khi, rowsum);
    attn_colsum<<<dim3(8, 4, 32), blk, 0, stream>>>(Qhi, Qlo, Khi, Klo, rowsum, colsum);
    topk_mask  <<<dim3(32),   blk, 0, stream>>>(colsum, maskf);
    mask_v     <<<dim3(2048), blk, 0, stream>>>((unsigned short*)Vt, maskf);
    attn_av    <<<dim3(16, 32), blk, 0, stream>>>(Qhi, Khi, Vt, rowsum, concat);

    gemm_out<<<dim3(8, 32), blk, 0, stream>>>((const short*)concat,
        (const short*)woh, (const short*)wol, bo, (float*)d_out);
}

// Round 6
// 464.427 us; speedup vs baseline: 1.5383x; 1.0406x over previous
//
#include <hip/hip_runtime.h>

// ---------------------------------------------------------------------------
// Pruned multi-head attention. fp32 I/O, split-bf16 (hi+lo) MFMA compute.
// B=2, S=2048, D_MODEL=1024, H=16, d_k=64, keep=int(2048*0.9)=1843
//
// Round 14: Q is now stored FRAG-MAJOR (same layout as K) by gemm_qkv.
// attn_colsum's per-iteration Q loads were the last strided-gather pattern
// (128B-stride short8 x4 per iter = ~32 txns each — same disease attn_av
// had pre-R12). Now all Q/K fragment loads are contiguous 256B segments.
// Numerically bit-identical to R13 (layout-only; absmax must stay 5.19e-4).
// R13 confirmed: swizzle killed all LDS bank conflicts, XCD remap brought
// FETCH to ideal (59.6MB); gemm_qkv sits at its 2-barrier ceiling (~29%
// MfmaUtil) — deeper pipeline is a future round if colsum wasn't the cost.
// ---------------------------------------------------------------------------

typedef __attribute__((ext_vector_type(8))) short short8;   // 8 bf16 (4 VGPRs)
typedef __attribute__((ext_vector_type(4))) short short4v;
typedef __attribute__((ext_vector_type(4))) float f32x4;
typedef __attribute__((ext_vector_type(16))) float f32x16;
typedef __attribute__((ext_vector_type(4))) unsigned int u32x4;

#define KEEP 1843

#if __has_builtin(__builtin_amdgcn_exp2f)
  #define PEXP(x) __builtin_amdgcn_exp2f(x)
  #define QSC 0.18033688011112042f   // log2(e)/8 folded into Q projection
#else
  #define PEXP(x) __expf(x)
  #define QSC 0.125f
#endif

#define AS1(p) ((const __attribute__((address_space(1))) void*)(p))
#define AS3(p) ((__attribute__((address_space(3))) void*)(p))

static __device__ __forceinline__ float bf2f(unsigned short s) {
    union { unsigned u; float f; } v; v.u = ((unsigned)s) << 16; return v.f;
}
static __device__ __forceinline__ unsigned short f2bf(float f) {
    union { float f; unsigned u; } v; v.f = f;
    unsigned u = v.u;
    unsigned r = (u + 0x7FFFu + ((u >> 16) & 1u)) >> 16;   // RNE
    return (unsigned short)r;
}

#define MFMA(A, B, C)   __builtin_amdgcn_mfma_f32_16x16x32_bf16(A, B, C, 0, 0, 0)
#define MFMA32(A, B, C) __builtin_amdgcn_mfma_f32_32x32x16_bf16(A, B, C, 0, 0, 0)

// Fragment-major layout for Q and K (per bh, 131072 shorts):
//   (s,d) -> (s>>5)*2048 + (((d>>4)*2 + ((d>>3)&1))*32 + (s&31))*8 + (d&7)
// Fragment-major V layout (per bh):
//   (s,d) -> (s>>5)*2048 + ((((((s>>4)&1)*2 + (d>>5))*2 + ((s>>3)&1))*32) + (d&31))*8 + (s&7)

// fp32 array -> hi/lo bf16 arrays (x = hi + lo to ~2^-17 relative)
__global__ __launch_bounds__(256) void cvt_split(
    const float* __restrict__ in, unsigned short* __restrict__ hi,
    unsigned short* __restrict__ lo, int n4)
{
    int i = blockIdx.x * 256 + threadIdx.x;
    if (i >= n4) return;
    f32x4 x = ((const f32x4*)in)[i];
    short4v h, l;
#pragma unroll
    for (int j = 0; j < 4; j++) {
        unsigned short hv = f2bf(x[j]);
        h[j] = (short)hv;
        l[j] = (short)f2bf(x[j] - bf2f(hv));
    }
    ((short4v*)hi)[i] = h;
    ((short4v*)lo)[i] = l;
}

__global__ __launch_bounds__(256) void zero_f32(float* __restrict__ p, int n) {
    int i = blockIdx.x * 256 + threadIdx.x;
    if (i < n) p[i] = 0.f;
}

// Fused Q/K/V projections, LDS-staged, bank-conflict-swizzled. 128x128, BK=32.
// z=0: Q frag-major hi+lo scaled QSC; z=1: K frag-major hi+lo; z=2: V frag-major.
__global__ __launch_bounds__(256) void gemm_qkv(
    const short* __restrict__ A0, const short* __restrict__ Al0,
    const short* __restrict__ A1, const short* __restrict__ Al1,
    const short* __restrict__ A2, const short* __restrict__ Al2,
    const short* __restrict__ W0, const short* __restrict__ Wl0,
    const short* __restrict__ W1, const short* __restrict__ Wl1,
    const short* __restrict__ W2, const short* __restrict__ Wl2,
    const float* __restrict__ b0, const float* __restrict__ b1,
    const float* __restrict__ b2,
    unsigned short* __restrict__ Qhi, unsigned short* __restrict__ Qlo,
    unsigned short* __restrict__ Khi, unsigned short* __restrict__ Klo,
    unsigned short* __restrict__ Vt)
{
    // XCD-chunked remap: consecutive hardware ids (lin%8 = XCD) own a
    // contiguous tile range; each A-row-panel (8 x-tiles) stays on one XCD.
    int lin = blockIdx.x + (blockIdx.y << 3) + (blockIdx.z << 8);   // [0,768)
    int tile = (lin & 7) * 96 + (lin >> 3);
    int bx = tile & 7, by = (tile >> 3) & 31, bz = tile >> 8;

    const short *Ahg, *Alg, *Whg, *Wlg; const float* bias;
    unsigned short *oh = 0, *ol = 0; float scale; int mode;
    if (bz == 0)      { Ahg=A0; Alg=Al0; Whg=W0; Wlg=Wl0; bias=b0; oh=Qhi; ol=Qlo; scale=QSC;  mode=0; }
    else if (bz == 1) { Ahg=A1; Alg=Al1; Whg=W1; Wlg=Wl1; bias=b1; oh=Khi; ol=Klo; scale=1.0f; mode=0; }
    else              { Ahg=A2; Alg=Al2; Whg=W2; Wlg=Wl2; bias=b2; oh=Vt;          scale=1.0f; mode=2; }

    __shared__ __align__(16) short Ah_l[128*32];
    __shared__ __align__(16) short Al_l[128*32];
    __shared__ __align__(16) short Wh_l[128*32];
    __shared__ __align__(16) short Wl_l[128*32];

    int tid  = threadIdx.x;
    int w    = tid >> 6;
    int lane = tid & 63;
    int ln   = lane & 15;
    int quad = lane >> 4;
    int rowBase = by * 128;
    int colBase = bx * 128;
    int mBase = (w & 1) * 64;        // wave's quadrant inside 128x128
    int nBase = (w >> 1) * 64;

    // staging: lane -> row r0+(lane>>2); source chunk pre-swizzled so the
    // linear LDS dest holds chunk c' = c ^ ((row>>1)&3)  (involution).
    int srow = (lane >> 2);
    int scol = (((lane & 3) ^ ((lane >> 3) & 3))) * 8;
    // read-side swizzled chunk offset (shorts): rows differ by 16 per frag,
    // so (r>>1)&3 == (ln>>1)&3 for every fragment row.
    int cs = ((quad ^ ((ln >> 1) & 3))) * 8;

    const short* Ag_h = Ahg + (size_t)rowBase * 1024;
    const short* Ag_l = Alg + (size_t)rowBase * 1024;
    const short* Wg_h = Whg + (size_t)colBase * 1024;
    const short* Wg_l = Wlg + (size_t)colBase * 1024;

    f32x4 acc[4][4];
#pragma unroll
    for (int i = 0; i < 4; i++)
#pragma unroll
        for (int j = 0; j < 4; j++) acc[i][j] = (f32x4){0.f, 0.f, 0.f, 0.f};

    for (int kk = 0; kk < 1024; kk += 32) {
#pragma unroll
        for (int j = 0; j < 2; j++) {
            int r = w*32 + j*16;
            size_t go = (size_t)(r + srow) * 1024 + kk + scol;
            __builtin_amdgcn_global_load_lds(AS1(Ag_h + go), AS3(Ah_l + r*32), 16, 0, 0);
            __builtin_amdgcn_global_load_lds(AS1(Ag_l + go), AS3(Al_l + r*32), 16, 0, 0);
            __builtin_amdgcn_global_load_lds(AS1(Wg_h + go), AS3(Wh_l + r*32), 16, 0, 0);
            __builtin_amdgcn_global_load_lds(AS1(Wg_l + go), AS3(Wl_l + r*32), 16, 0, 0);
        }
        __syncthreads();

        short8 ah[4], al[4], bh[4], bl[4];
#pragma unroll
        for (int mt = 0; mt < 4; mt++) {
            int r = mBase + mt*16 + ln;
            ah[mt] = *(const short8*)(Ah_l + r*32 + cs);
            al[mt] = *(const short8*)(Al_l + r*32 + cs);
        }
#pragma unroll
        for (int nt = 0; nt < 4; nt++) {
            int c = nBase + nt*16 + ln;
            bh[nt] = *(const short8*)(Wh_l + c*32 + cs);
            bl[nt] = *(const short8*)(Wl_l + c*32 + cs);
        }
#pragma unroll
        for (int mt = 0; mt < 4; mt++)
#pragma unroll
            for (int nt = 0; nt < 4; nt++) {
                acc[mt][nt] = MFMA(ah[mt], bh[nt], acc[mt][nt]);
                acc[mt][nt] = MFMA(ah[mt], bl[nt], acc[mt][nt]);
                acc[mt][nt] = MFMA(al[mt], bh[nt], acc[mt][nt]);
            }
        __syncthreads();
    }

#pragma unroll
    for (int mt = 0; mt < 4; mt++) {
#pragma unroll
        for (int nt = 0; nt < 4; nt++) {
            int col = colBase + nBase + nt*16 + ln;
            float bv = bias[col];
#pragma unroll
            for (int i = 0; i < 4; i++) {
                int row = rowBase + mBase + mt*16 + quad*4 + i;   // D: row=quad*4+reg
                float val = (acc[mt][nt][i] + bv) * scale;
                int b_  = row >> 11, s = row & 2047;
                int h   = col >> 6,  d = col & 63;
                int bh_ = b_ * 16 + h;
                if (mode == 2) {
                    size_t idx = (size_t)bh_ * 131072 + (size_t)(s >> 5) * 2048
                        + ((size_t)((((((s >> 4) & 1) * 2 + (d >> 5)) * 2 + ((s >> 3) & 1)) * 32)
                                    + (d & 31))) * 8 + (s & 7);
                    oh[idx] = f2bf(val);
                } else {
                    size_t idx = (size_t)bh_ * 131072 + (size_t)(s >> 5) * 2048
                        + ((size_t)(((d >> 4) * 2 + ((d >> 3) & 1)) * 32 + (s & 31))) * 8 + (d & 7);
                    unsigned short hv = f2bf(val);
                    oh[idx] = hv;
                    ol[idx] = f2bf(val - bf2f(hv));
                }
            }
        }
    }
}

// out = concat(bf16) @ Wo^T + bo (split Wo, fp32 out), LDS-staged + swizzled.
__global__ __launch_bounds__(256) void gemm_out(
    const short* __restrict__ Ag, const short* __restrict__ Whg,
    const short* __restrict__ Wlg, const float* __restrict__ bias,
    float* __restrict__ out)
{
    int lin = blockIdx.x + (blockIdx.y << 3);                  // [0,256)
    int tile = (lin & 7) * 32 + (lin >> 3);
    int bx = tile & 7, by = tile >> 3;

    __shared__ __align__(16) short A_l[128*32];
    __shared__ __align__(16) short Wh_l[128*32];
    __shared__ __align__(16) short Wl_l[128*32];

    int tid  = threadIdx.x;
    int w    = tid >> 6;
    int lane = tid & 63;
    int ln   = lane & 15;
    int quad = lane >> 4;
    int rowBase = by * 128;
    int colBase = bx * 128;
    int mBase = (w & 1) * 64;
    int nBase = (w >> 1) * 64;

    int srow = (lane >> 2);
    int scol = (((lane & 3) ^ ((lane >> 3) & 3))) * 8;
    int cs = ((quad ^ ((ln >> 1) & 3))) * 8;
    const short* Abase = Ag  + (size_t)rowBase * 1024;
    const short* Whb   = Whg + (size_t)colBase * 1024;
    const short* Wlb   = Wlg + (size_t)colBase * 1024;

    f32x4 acc[4][4];
#pragma unroll
    for (int i = 0; i < 4; i++)
#pragma unroll
        for (int j = 0; j < 4; j++) acc[i][j] = (f32x4){0.f, 0.f, 0.f, 0.f};

    for (int kk = 0; kk < 1024; kk += 32) {
#pragma unroll
        for (int j = 0; j < 2; j++) {
            int r = w*32 + j*16;
            size_t go = (size_t)(r + srow) * 1024 + kk + scol;
            __builtin_amdgcn_global_load_lds(AS1(Abase + go), AS3(A_l  + r*32), 16, 0, 0);
            __builtin_amdgcn_global_load_lds(AS1(Whb   + go), AS3(Wh_l + r*32), 16, 0, 0);
            __builtin_amdgcn_global_load_lds(AS1(Wlb   + go), AS3(Wl_l + r*32), 16, 0, 0);
        }
        __syncthreads();

        short8 a[4], bh[4], bl[4];
#pragma unroll
        for (int mt = 0; mt < 4; mt++)
            a[mt] = *(const short8*)(A_l + (mBase + mt*16 + ln)*32 + cs);
#pragma unroll
        for (int nt = 0; nt < 4; nt++) {
            int c = nBase + nt*16 + ln;
            bh[nt] = *(const short8*)(Wh_l + c*32 + cs);
            bl[nt] = *(const short8*)(Wl_l + c*32 + cs);
        }
#pragma unroll
        for (int mt = 0; mt < 4; mt++)
#pragma unroll
            for (int nt = 0; nt < 4; nt++) {
                acc[mt][nt] = MFMA(a[mt], bh[nt], acc[mt][nt]);
                acc[mt][nt] = MFMA(a[mt], bl[nt], acc[mt][nt]);
            }
        __syncthreads();
    }

#pragma unroll
    for (int mt = 0; mt < 4; mt++) {
#pragma unroll
        for (int nt = 0; nt < 4; nt++) {
            int col = colBase + nBase + nt*16 + ln;
            float bv = bias[col];
#pragma unroll
            for (int i = 0; i < 4; i++) {
                int row = rowBase + mBase + mt*16 + quad*4 + i;
                out[(size_t)row * 1024 + col] = acc[mt][nt][i] + bv;
            }
        }
    }
}

// rowsum[q] += sum over this block's k-quarter of 2^(c_qk), HI-ONLY scores.
// Q and K both frag-major.
__global__ __launch_bounds__(256) void attn_rowsum(
    const short* __restrict__ Qhi, const short* __restrict__ Khi,
    float* __restrict__ rowsum)
{
    int bh = blockIdx.z, tid = threadIdx.x;
    int w = tid >> 6, lane = tid & 63, ln = lane & 15, quad = lane >> 4;
    int qb  = blockIdx.x * 256 + w * 64;
    int kt0 = blockIdx.y * 32;            // 32 k-tiles of 16 = 512 keys
    const short* QH = Qhi + (size_t)bh * 131072;
    const short* KH = Khi + (size_t)bh * 131072;

    short8 qh[4][2];
#pragma unroll
    for (int mt = 0; mt < 4; mt++)
#pragma unroll
        for (int half = 0; half < 2; half++) {
            size_t o = (size_t)((qb >> 5) + (mt >> 1)) * 2048
                     + (size_t)(half * 4 + quad) * 256 + ((mt & 1) * 16 + ln) * 8;
            qh[mt][half] = *(const short8*)(QH + o);
        }

    short8 kh[2][2];   // [buf][dchunk]
    auto loadK = [&](int buf, int kt) {
        size_t ko = (size_t)(kt >> 1) * 2048 + (size_t)quad * 256 + ((kt & 1) * 16 + ln) * 8;
        kh[buf][0] = *(const short8*)(KH + ko);
        kh[buf][1] = *(const short8*)(KH + ko + 1024);
    };

    float racc[4][4] = {};
    auto comp = [&](int buf) {
#pragma unroll
        for (int mt = 0; mt < 4; mt++) {
            f32x4 c1 = (f32x4){0.f,0.f,0.f,0.f};
            c1 = MFMA(qh[mt][0], kh[buf][0], c1);
            c1 = MFMA(qh[mt][1], kh[buf][1], c1);
#pragma unroll
            for (int i = 0; i < 4; i++)
                racc[mt][i] += PEXP(c1[i]);
        }
    };

    loadK(0, kt0);
    for (int t = 0; t < 32; t += 2) {
        loadK(1, kt0 + t + 1);
        comp(0);
        if (t + 2 < 32) loadK(0, kt0 + t + 2);
        comp(1);
    }
#pragma unroll
    for (int mt = 0; mt < 4; mt++)
#pragma unroll
        for (int i = 0; i < 4; i++)
            for (int d = 1; d < 16; d <<= 1)
                racc[mt][i] += __shfl_xor(racc[mt][i], d, 64);
    if (ln == 0) {
#pragma unroll
        for (int mt = 0; mt < 4; mt++)
#pragma unroll
            for (int i = 0; i < 4; i++)
                atomicAdd(&rowsum[bh * 2048 + qb + mt*16 + quad*4 + i], racc[mt][i]);
    }
}

// colsum[k] += sum over this block's q-quarter of 2^(c_qk)/rowsum[q].
// 3-term split kept (feeds the top-k ranking). Q and K both frag-major.
__global__ __launch_bounds__(256) void attn_colsum(
    const short* __restrict__ Qhi, const short* __restrict__ Qlo,
    const short* __restrict__ Khi, const short* __restrict__ Klo,
    const float* __restrict__ rowsum, float* __restrict__ colsum)
{
    __shared__ float sli[512];
    int bh = blockIdx.z, tid = threadIdx.x;
    int q0 = blockIdx.y * 512;
    for (int j = tid; j < 512; j += 256)
        sli[j] = 1.0f / rowsum[bh * 2048 + q0 + j];
    __syncthreads();

    int w = tid >> 6, lane = tid & 63, ln = lane & 15, quad = lane >> 4;
    int kb  = blockIdx.x * 256 + w * 64;
    int qt0 = blockIdx.y * 32;            // 32 q-tiles of 16
    const short* QH = Qhi + (size_t)bh * 131072;
    const short* QL = Qlo + (size_t)bh * 131072;
    const short* KH = Khi + (size_t)bh * 131072;
    const short* KL = Klo + (size_t)bh * 131072;

    short8 kh[4][2], kl[4][2];
#pragma unroll
    for (int nt = 0; nt < 4; nt++)
#pragma unroll
        for (int half = 0; half < 2; half++) {
            size_t o = (size_t)((kb >> 5) + (nt >> 1)) * 2048 + (size_t)half * 1024
                     + (size_t)quad * 256 + ((nt & 1) * 16 + ln) * 8;
            kh[nt][half] = *(const short8*)(KH + o);
            kl[nt][half] = *(const short8*)(KL + o);
        }

    short8 qh[2][2], ql[2][2];   // [buf][half]
    auto loadQ = [&](int buf, int qt) {
        int qtt = qt0 + qt;
        size_t base = (size_t)(qtt >> 1) * 2048 + ((qtt & 1) * 16 + ln) * 8;
        qh[buf][0] = *(const short8*)(QH + base + (size_t)quad * 256);
        qh[buf][1] = *(const short8*)(QH + base + (size_t)(4 + quad) * 256);
        ql[buf][0] = *(const short8*)(QL + base + (size_t)quad * 256);
        ql[buf][1] = *(const short8*)(QL + base + (size_t)(4 + quad) * 256);
    };

    float cacc[4] = {0.f, 0.f, 0.f, 0.f};
    auto comp = [&](int buf, int qt) {
#pragma unroll
        for (int nt = 0; nt < 4; nt++) {
            f32x4 c1 = (f32x4){0.f,0.f,0.f,0.f};
            f32x4 c2 = (f32x4){0.f,0.f,0.f,0.f};
            c1 = MFMA(qh[buf][0], kh[nt][0], c1); c1 = MFMA(qh[buf][1], kh[nt][1], c1);
            c2 = MFMA(qh[buf][0], kl[nt][0], c2); c2 = MFMA(qh[buf][1], kl[nt][1], c2);
            c2 = MFMA(ql[buf][0], kh[nt][0], c2); c2 = MFMA(ql[buf][1], kh[nt][1], c2);
#pragma unroll
            for (int i = 0; i < 4; i++) {
                int r = qt*16 + quad*4 + i;
                cacc[nt] += PEXP(c1[i] + c2[i]) * sli[r];
            }
        }
    };

    loadQ(0, 0);
    for (int qt = 0; qt < 32; qt += 2) {
        loadQ(1, qt + 1);
        comp(0, qt);
        if (qt + 2 < 32) loadQ(0, qt + 2);
        comp(1, qt + 1);
    }
#pragma unroll
    for (int nt = 0; nt < 4; nt++) {
        cacc[nt] += __shfl_xor(cacc[nt], 16, 64);
        cacc[nt] += __shfl_xor(cacc[nt], 32, 64);
        if (lane < 16) atomicAdd(&colsum[bh * 2048 + kb + nt*16 + lane], cacc[nt]);
    }
}

// Per (b,h): threshold = KEEP-th largest col_sum; mask = col_sum >= threshold.
__global__ __launch_bounds__(256) void topk_mask(
    const float* __restrict__ colsum, float* __restrict__ maskf)
{
    __shared__ unsigned keys[2048];
    __shared__ int cnt;
    int bh = blockIdx.x, tid = threadIdx.x;
    for (int j = tid; j < 2048; j += 256) {
        unsigned u = __float_as_uint(colsum[bh * 2048 + j]);
        keys[j] = (u & 0x80000000u) ? ~u : (u | 0x80000000u);
    }
    __syncthreads();
    unsigned long long lo = 0, hi = 0x100000000ULL;
    while (hi - lo > 1) {
        unsigned long long mid = (lo + hi) >> 1;
        if (tid == 0) cnt = 0;
        __syncthreads();
        int local = 0;
        for (int j = tid; j < 2048; j += 256) local += (keys[j] >= (unsigned)mid) ? 1 : 0;
        atomicAdd(&cnt, local);
        __syncthreads();
        int c = cnt;
        __syncthreads();
        if (c >= KEEP) lo = mid; else hi = mid;
    }
    unsigned thr = (unsigned)lo;
    for (int j = tid; j < 2048; j += 256)
        maskf[bh * 2048 + j] = (keys[j] >= thr) ? 1.0f : 0.0f;
}

// V (frag-major) *= mask. Group g of 8 shorts covers 8 consecutive k for one d:
// k0 = (g>>8)*32 + ((g>>7)&1)*16 + ((g>>5)&1)*8
__global__ __launch_bounds__(256) void mask_v(
    unsigned short* __restrict__ Vt, const float* __restrict__ maskf)
{
    int i = blockIdx.x * 256 + threadIdx.x;   // short8 group; 32 bh x 16384 groups
    int g  = i & 16383;
    int bh = i >> 14;
    int k0 = (g >> 8) * 32 + ((g >> 7) & 1) * 16 + ((g >> 5) & 1) * 8;
    const float* m = maskf + bh * 2048 + k0;
    short8 v = ((short8*)Vt)[i];
#pragma unroll
    for (int j = 0; j < 8; j++)
        if (m[j] == 0.0f) v[j] = 0;
    ((short8*)Vt)[i] = v;
}

// PV with swapped-operand QK^T, in-register P, block-level LDS staging of
// frag-major K/V chunks. XCD-chunked remap keeps a bh's blocks on one XCD.
__global__ __launch_bounds__(256) void attn_av(
    const short* __restrict__ Qhi, const short* __restrict__ Kf,
    const short* __restrict__ Vf, const float* __restrict__ rowsum,
    unsigned short* __restrict__ concat)
{
    __shared__ __align__(16) short KA[4096];   // [0,2048): K chunk, [2048,4096): V chunk
    __shared__ __align__(16) short KB[4096];
    int lin = blockIdx.x + (blockIdx.y << 4);          // [0,512)
    int tile = (lin & 7) * 64 + (lin >> 3);
    int bxx = tile & 15, bh = tile >> 4;
    int tid = threadIdx.x;
    int w = tid >> 6, lane = tid & 63;
    int lq = lane & 31, hi = lane >> 5;
    int qb = bxx * 128 + w * 32;
    const short* Qb = Qhi + (size_t)bh * 131072 + (size_t)(qb >> 5) * 2048;
    const short* Kg = Kf  + (size_t)bh * 131072;
    const short* Vg = Vf  + (size_t)bh * 131072;

    // Q^T B-frags (frag-major): lane holds Q[qb+lq][d*16 + hi*8 + j]
    short8 qf[4];
#pragma unroll
    for (int d = 0; d < 4; d++)
        qf[d] = *(const short8*)(Qb + (size_t)(d*2 + hi) * 256 + lq * 8);

    f32x16 o0, o1;
#pragma unroll
    for (int i = 0; i < 16; i++) { o0[i] = 0.f; o1[i] = 0.f; }

    auto STAGE = [&](short* B, int kc) {
        __builtin_amdgcn_global_load_lds(AS1(Kg + (size_t)kc*2048 + tid*8),
                                         AS3(B + w*512), 16, 0, 0);
        __builtin_amdgcn_global_load_lds(AS1(Vg + (size_t)kc*2048 + tid*8),
                                         AS3(B + 2048 + w*512), 16, 0, 0);
    };

    auto comp = [&](const short* B) {
        short8 kf_[4], vf_[4];
#pragma unroll
        for (int d = 0; d < 4; d++)
            kf_[d] = *(const short8*)(B + (d*2 + hi)*256 + lq*8);
#pragma unroll
        for (int ks = 0; ks < 2; ks++)
#pragma unroll
            for (int nt = 0; nt < 2; nt++)
                vf_[ks*2+nt] = *(const short8*)(B + 2048 + ((ks*2+nt)*2 + hi)*256 + lq*8);

        f32x16 s;
#pragma unroll
        for (int i = 0; i < 16; i++) s[i] = 0.f;
        s = MFMA32(kf_[0], qf[0], s);
        s = MFMA32(kf_[1], qf[1], s);
        s = MFMA32(kf_[2], qf[2], s);
        s = MFMA32(kf_[3], qf[3], s);

        float p[16];
#pragma unroll
        for (int i = 0; i < 16; i++) p[i] = PEXP(s[i]);

        short8 pa[2];
#pragma unroll
        for (int ks = 0; ks < 2; ks++) {
            unsigned w0, w1, w2, w3;
            int o8 = ks * 8;
            asm("v_cvt_pk_bf16_f32 %0, %1, %2" : "=v"(w0) : "v"(p[o8+0]), "v"(p[o8+1]));
            asm("v_cvt_pk_bf16_f32 %0, %1, %2" : "=v"(w1) : "v"(p[o8+2]), "v"(p[o8+3]));
            asm("v_cvt_pk_bf16_f32 %0, %1, %2" : "=v"(w2) : "v"(p[o8+4]), "v"(p[o8+5]));
            asm("v_cvt_pk_bf16_f32 %0, %1, %2" : "=v"(w3) : "v"(p[o8+6]), "v"(p[o8+7]));
            asm("v_permlane32_swap_b32 %0, %1" : "+v"(w0), "+v"(w2));
            asm("v_permlane32_swap_b32 %0, %1" : "+v"(w1), "+v"(w3));
            u32x4 pw = { w0, w1, w2, w3 };
            pa[ks] = __builtin_bit_cast(short8, pw);
        }

        o0 = MFMA32(pa[0], vf_[0], o0);
        o1 = MFMA32(pa[0], vf_[1], o1);
        o0 = MFMA32(pa[1], vf_[2], o0);
        o1 = MFMA32(pa[1], vf_[3], o1);
    };

    STAGE(KA, 0);
    __syncthreads();
    for (int kc = 0; kc < 64; kc += 2) {
        STAGE(KB, kc + 1);          // next chunk's loads fly under compute
        comp(KA);
        __syncthreads();            // publishes KB, guards KA reuse
        if (kc + 2 < 64) STAGE(KA, kc + 2);
        comp(KB);
        __syncthreads();
    }

    int b_ = bh >> 4, h = bh & 15;
#pragma unroll
    for (int r = 0; r < 16; r++) {
        int crow = (r & 3) + 8*(r >> 2) + 4*hi;
        float inv = 1.0f / rowsum[bh * 2048 + qb + crow];
        size_t base = ((size_t)(b_*2048 + qb + crow)) * 1024 + h*64;
        concat[base + lq]      = f2bf(o0[r] * inv);
        concat[base + 32 + lq] = f2bf(o1[r] * inv);
    }
}

extern "C" void kernel_launch(void* const* d_in, const int* in_sizes, int n_in,
                              void* d_out, int out_size, void* d_ws, size_t ws_size,
                              hipStream_t stream)
{
    const float* q  = (const float*)d_in[0];
    const float* k  = (const float*)d_in[1];
    const float* v  = (const float*)d_in[2];
    const float* Wq = (const float*)d_in[3];
    const float* bq = (const float*)d_in[4];
    const float* Wk = (const float*)d_in[5];
    const float* bk = (const float*)d_in[6];
    const float* Wv = (const float*)d_in[7];
    const float* bv = (const float*)d_in[8];
    const float* Wo = (const float*)d_in[9];
    const float* bo = (const float*)d_in[10];

    char* ws = (char*)d_ws;
    size_t off = 0;
    auto alloc = [&](size_t bytes) -> void* {
        void* p = ws + off;
        off += (bytes + 255) & ~(size_t)255;
        return p;
    };
    const size_t ASZ = (size_t)4096 * 1024 * 2;   // 8.4 MB bf16 activation
    const size_t WSZ = (size_t)1024 * 1024 * 2;   // 2 MB bf16 weight
    unsigned short* qh_ = (unsigned short*)alloc(ASZ);
    unsigned short* ql_ = (unsigned short*)alloc(ASZ);
    unsigned short* kh_ = (unsigned short*)alloc(ASZ);
    unsigned short* kl_ = (unsigned short*)alloc(ASZ);
    unsigned short* vh_ = (unsigned short*)alloc(ASZ);
    unsigned short* vl_ = (unsigned short*)alloc(ASZ);
    unsigned short* wqh = (unsigned short*)alloc(WSZ);
    unsigned short* wql = (unsigned short*)alloc(WSZ);
    unsigned short* wkh = (unsigned short*)alloc(WSZ);
    unsigned short* wkl = (unsigned short*)alloc(WSZ);
    unsigned short* wvh = (unsigned short*)alloc(WSZ);
    unsigned short* wvl = (unsigned short*)alloc(WSZ);
    unsigned short* woh = (unsigned short*)alloc(WSZ);
    unsigned short* wol = (unsigned short*)alloc(WSZ);
    short* Qhi = (short*)alloc(ASZ);   // frag-major
    short* Qlo = (short*)alloc(ASZ);   // frag-major
    short* Khi = (short*)alloc(ASZ);   // frag-major
    short* Klo = (short*)alloc(ASZ);   // frag-major
    short* Vt  = (short*)alloc(ASZ);   // frag-major
    float* rowsum = (float*)alloc((size_t)32 * 2048 * 4);
    float* colsum = (float*)alloc((size_t)32 * 2048 * 4);
    float* maskf  = (float*)alloc((size_t)32 * 2048 * 4);
    unsigned short* concat = (unsigned short*)alloc(ASZ);
    // total ~118 MB (known-safe)

    dim3 blk(256);
    const int An4 = 4096 * 1024 / 4, Wn4 = 1024 * 1024 / 4;

    cvt_split<<<An4/256, blk, 0, stream>>>(q,  qh_, ql_, An4);
    cvt_split<<<An4/256, blk, 0, stream>>>(k,  kh_, kl_, An4);
    cvt_split<<<An4/256, blk, 0, stream>>>(v,  vh_, vl_, An4);
    cvt_split<<<Wn4/256, blk, 0, stream>>>(Wq, wqh, wql, Wn4);
    cvt_split<<<Wn4/256, blk, 0, stream>>>(Wk, wkh, wkl, Wn4);
    cvt_split<<<Wn4/256, blk, 0, stream>>>(Wv, wvh, wvl, Wn4);
    cvt_split<<<Wn4/256, blk, 0, stream>>>(Wo, woh, wol, Wn4);
    zero_f32 <<<dim3(512), blk, 0, stream>>>(rowsum, 2 * 32 * 2048);  // rowsum+colsum

    gemm_qkv<<<dim3(8, 32, 3), blk, 0, stream>>>(
        (const short*)qh_, (const short*)ql_, (const short*)kh_, (const short*)kl_,
        (const short*)vh_, (const short*)vl_,
        (const short*)wqh, (const short*)wql, (const short*)wkh, (const short*)wkl,
        (const short*)wvh, (const short*)wvl,
        bq, bk, bv,
        (unsigned short*)Qhi, (unsigned short*)Qlo,
        (unsigned short*)Khi, (unsigned short*)Klo, (unsigned short*)Vt);

    attn_rowsum<<<dim3(8, 4, 32), blk, 0, stream>>>(Qhi, Khi, rowsum);
    attn_colsum<<<dim3(8, 4, 32), blk, 0, stream>>>(Qhi, Qlo, Khi, Klo, rowsum, colsum);
    topk_mask  <<<dim3(32),   blk, 0, stream>>>(colsum, maskf);
    mask_v     <<<dim3(2048), blk, 0, stream>>>((unsigned short*)Vt, maskf);
    attn_av    <<<dim3(16, 32), blk, 0, stream>>>(Qhi, Khi, Vt, rowsum, concat);

    gemm_out<<<dim3(8, 32), blk, 0, stream>>>((const short*)concat,
        (const short*)woh, (const short*)wol, bo, (float*)d_out);
}

// Round 7
// 408.805 us; speedup vs baseline: 1.7476x; 1.1361x over previous
//
#include <hip/hip_runtime.h>

// ---------------------------------------------------------------------------
// Pruned multi-head attention. fp32 I/O, split-bf16 (hi+lo) MFMA compute.
// B=2, S=2048, D_MODEL=1024, H=16, d_k=64, keep=int(2048*0.9)=1843
//
// Round 15: V projection split out as 1-term gemm_v (V enters the output
// linearly; its lo-correction terms are below bf16 output precision and
// average down ~1/sqrt(K) through PV). gemm_qkv now 2 slices (Q,K only).
// topk_mask rewritten as 4-level radix select (12 barriers vs ~96).
// cvt_split x7 merged into one cvt_all launch (V/Wv lo outputs skipped —
// never read). R14 confirmed frag-major Q bit-identical; gemm_qkv is at
// its 2-barrier ceiling (m99/m100: explicit dbuf neutral), so this round
// cuts WORK, not schedule.
// ---------------------------------------------------------------------------

typedef __attribute__((ext_vector_type(8))) short short8;   // 8 bf16 (4 VGPRs)
typedef __attribute__((ext_vector_type(4))) short short4v;
typedef __attribute__((ext_vector_type(4))) float f32x4;
typedef __attribute__((ext_vector_type(16))) float f32x16;
typedef __attribute__((ext_vector_type(4))) unsigned int u32x4;

#define KEEP 1843

#if __has_builtin(__builtin_amdgcn_exp2f)
  #define PEXP(x) __builtin_amdgcn_exp2f(x)
  #define QSC 0.18033688011112042f   // log2(e)/8 folded into Q projection
#else
  #define PEXP(x) __expf(x)
  #define QSC 0.125f
#endif

#define AS1(p) ((const __attribute__((address_space(1))) void*)(p))
#define AS3(p) ((__attribute__((address_space(3))) void*)(p))

static __device__ __forceinline__ float bf2f(unsigned short s) {
    union { unsigned u; float f; } v; v.u = ((unsigned)s) << 16; return v.f;
}
static __device__ __forceinline__ unsigned short f2bf(float f) {
    union { float f; unsigned u; } v; v.f = f;
    unsigned u = v.u;
    unsigned r = (u + 0x7FFFu + ((u >> 16) & 1u)) >> 16;   // RNE
    return (unsigned short)r;
}

#define MFMA(A, B, C)   __builtin_amdgcn_mfma_f32_16x16x32_bf16(A, B, C, 0, 0, 0)
#define MFMA32(A, B, C) __builtin_amdgcn_mfma_f32_32x32x16_bf16(A, B, C, 0, 0, 0)

// Fragment-major layout for Q and K (per bh, 131072 shorts):
//   (s,d) -> (s>>5)*2048 + (((d>>4)*2 + ((d>>3)&1))*32 + (s&31))*8 + (d&7)
// Fragment-major V layout (per bh):
//   (s,d) -> (s>>5)*2048 + ((((((s>>4)&1)*2 + (d>>5))*2 + ((s>>3)&1))*32) + (d&31))*8 + (s&7)

// All 7 fp32->bf16(hi/lo) conversions in one launch. Segments:
// 0:q 1:k 2:v(hi only) 3:Wq 4:Wk 5:Wv(hi only) 6:Wo
__global__ __launch_bounds__(256) void cvt_all(
    const float* __restrict__ q,  const float* __restrict__ k,
    const float* __restrict__ v,  const float* __restrict__ Wq,
    const float* __restrict__ Wk, const float* __restrict__ Wv,
    const float* __restrict__ Wo,
    unsigned short* __restrict__ qh, unsigned short* __restrict__ ql,
    unsigned short* __restrict__ kh, unsigned short* __restrict__ kl,
    unsigned short* __restrict__ vh,
    unsigned short* __restrict__ wqh, unsigned short* __restrict__ wql,
    unsigned short* __restrict__ wkh, unsigned short* __restrict__ wkl,
    unsigned short* __restrict__ wvh,
    unsigned short* __restrict__ woh, unsigned short* __restrict__ wol)
{
    int g = blockIdx.x * 256 + threadIdx.x;      // [0, 4194304)
    const float* in; unsigned short* oh; unsigned short* ol; int idx;
    if (g < 3145728) {                           // activations: 3 x 2^20 groups
        int seg = g >> 20; idx = g & 1048575;
        if (seg == 0)      { in = q; oh = qh;  ol = ql;  }
        else if (seg == 1) { in = k; oh = kh;  ol = kl;  }
        else               { in = v; oh = vh;  ol = 0;   }
    } else {                                     // weights: 4 x 2^18 groups
        int gw = g - 3145728; int seg = gw >> 18; idx = gw & 262143;
        if (seg == 0)      { in = Wq; oh = wqh; ol = wql; }
        else if (seg == 1) { in = Wk; oh = wkh; ol = wkl; }
        else if (seg == 2) { in = Wv; oh = wvh; ol = 0;   }
        else               { in = Wo; oh = woh; ol = wol; }
    }
    f32x4 x = ((const f32x4*)in)[idx];
    short4v h, l;
#pragma unroll
    for (int j = 0; j < 4; j++) {
        unsigned short hv = f2bf(x[j]);
        h[j] = (short)hv;
        l[j] = (short)f2bf(x[j] - bf2f(hv));
    }
    ((short4v*)oh)[idx] = h;
    if (ol) ((short4v*)ol)[idx] = l;
}

__global__ __launch_bounds__(256) void zero_f32(float* __restrict__ p, int n) {
    int i = blockIdx.x * 256 + threadIdx.x;
    if (i < n) p[i] = 0.f;
}

// Fused Q/K projections (split hi+lo, 3-term), LDS-staged + swizzled.
// 128x128 tile, BK=32. z=0: Q (scaled QSC); z=1: K. Both frag-major hi+lo.
__global__ __launch_bounds__(256) void gemm_qkv(
    const short* __restrict__ A0, const short* __restrict__ Al0,
    const short* __restrict__ A1, const short* __restrict__ Al1,
    const short* __restrict__ W0, const short* __restrict__ Wl0,
    const short* __restrict__ W1, const short* __restrict__ Wl1,
    const float* __restrict__ b0, const float* __restrict__ b1,
    unsigned short* __restrict__ Qhi, unsigned short* __restrict__ Qlo,
    unsigned short* __restrict__ Khi, unsigned short* __restrict__ Klo)
{
    // XCD-chunked remap over 512 blocks: each XCD owns 64 consecutive tiles.
    int lin = blockIdx.x + (blockIdx.y << 3) + (blockIdx.z << 8);   // [0,512)
    int tile = (lin & 7) * 64 + (lin >> 3);
    int bx = tile & 7, by = (tile >> 3) & 31, bz = tile >> 8;

    const short *Ahg, *Alg, *Whg, *Wlg; const float* bias;
    unsigned short *oh, *ol; float scale;
    if (bz == 0) { Ahg=A0; Alg=Al0; Whg=W0; Wlg=Wl0; bias=b0; oh=Qhi; ol=Qlo; scale=QSC;  }
    else         { Ahg=A1; Alg=Al1; Whg=W1; Wlg=Wl1; bias=b1; oh=Khi; ol=Klo; scale=1.0f; }

    __shared__ __align__(16) short Ah_l[128*32];
    __shared__ __align__(16) short Al_l[128*32];
    __shared__ __align__(16) short Wh_l[128*32];
    __shared__ __align__(16) short Wl_l[128*32];

    int tid  = threadIdx.x;
    int w    = tid >> 6;
    int lane = tid & 63;
    int ln   = lane & 15;
    int quad = lane >> 4;
    int rowBase = by * 128;
    int colBase = bx * 128;
    int mBase = (w & 1) * 64;        // wave's quadrant inside 128x128
    int nBase = (w >> 1) * 64;

    // staging: lane -> row r0+(lane>>2); source chunk pre-swizzled so the
    // linear LDS dest holds chunk c' = c ^ ((row>>1)&3)  (involution).
    int srow = (lane >> 2);
    int scol = (((lane & 3) ^ ((lane >> 3) & 3))) * 8;
    int cs = ((quad ^ ((ln >> 1) & 3))) * 8;

    const short* Ag_h = Ahg + (size_t)rowBase * 1024;
    const short* Ag_l = Alg + (size_t)rowBase * 1024;
    const short* Wg_h = Whg + (size_t)colBase * 1024;
    const short* Wg_l = Wlg + (size_t)colBase * 1024;

    f32x4 acc[4][4];
#pragma unroll
    for (int i = 0; i < 4; i++)
#pragma unroll
        for (int j = 0; j < 4; j++) acc[i][j] = (f32x4){0.f, 0.f, 0.f, 0.f};

    for (int kk = 0; kk < 1024; kk += 32) {
#pragma unroll
        for (int j = 0; j < 2; j++) {
            int r = w*32 + j*16;
            size_t go = (size_t)(r + srow) * 1024 + kk + scol;
            __builtin_amdgcn_global_load_lds(AS1(Ag_h + go), AS3(Ah_l + r*32), 16, 0, 0);
            __builtin_amdgcn_global_load_lds(AS1(Ag_l + go), AS3(Al_l + r*32), 16, 0, 0);
            __builtin_amdgcn_global_load_lds(AS1(Wg_h + go), AS3(Wh_l + r*32), 16, 0, 0);
            __builtin_amdgcn_global_load_lds(AS1(Wg_l + go), AS3(Wl_l + r*32), 16, 0, 0);
        }
        __syncthreads();

        short8 ah[4], al[4], bh[4], bl[4];
#pragma unroll
        for (int mt = 0; mt < 4; mt++) {
            int r = mBase + mt*16 + ln;
            ah[mt] = *(const short8*)(Ah_l + r*32 + cs);
            al[mt] = *(const short8*)(Al_l + r*32 + cs);
        }
#pragma unroll
        for (int nt = 0; nt < 4; nt++) {
            int c = nBase + nt*16 + ln;
            bh[nt] = *(const short8*)(Wh_l + c*32 + cs);
            bl[nt] = *(const short8*)(Wl_l + c*32 + cs);
        }
#pragma unroll
        for (int mt = 0; mt < 4; mt++)
#pragma unroll
            for (int nt = 0; nt < 4; nt++) {
                acc[mt][nt] = MFMA(ah[mt], bh[nt], acc[mt][nt]);
                acc[mt][nt] = MFMA(ah[mt], bl[nt], acc[mt][nt]);
                acc[mt][nt] = MFMA(al[mt], bh[nt], acc[mt][nt]);
            }
        __syncthreads();
    }

#pragma unroll
    for (int mt = 0; mt < 4; mt++) {
#pragma unroll
        for (int nt = 0; nt < 4; nt++) {
            int col = colBase + nBase + nt*16 + ln;
            float bv = bias[col];
#pragma unroll
            for (int i = 0; i < 4; i++) {
                int row = rowBase + mBase + mt*16 + quad*4 + i;   // D: row=quad*4+reg
                float val = (acc[mt][nt][i] + bv) * scale;
                int b_  = row >> 11, s = row & 2047;
                int h   = col >> 6,  d = col & 63;
                int bh_ = b_ * 16 + h;
                size_t idx = (size_t)bh_ * 131072 + (size_t)(s >> 5) * 2048
                    + ((size_t)(((d >> 4) * 2 + ((d >> 3) & 1)) * 32 + (s & 31))) * 8 + (d & 7);
                unsigned short hv = f2bf(val);
                oh[idx] = hv;
                ol[idx] = f2bf(val - bf2f(hv));
            }
        }
    }
}

// V projection, 1-term (hi x hi only): V enters PV linearly, so the lo
// correction is below bf16 output precision. Writes frag-major V bf16.
__global__ __launch_bounds__(256) void gemm_v(
    const short* __restrict__ Ag, const short* __restrict__ Whg,
    const float* __restrict__ bias, unsigned short* __restrict__ Vt)
{
    int lin = blockIdx.x + (blockIdx.y << 3);                  // [0,256)
    int tile = (lin & 7) * 32 + (lin >> 3);
    int bx = tile & 7, by = tile >> 3;

    __shared__ __align__(16) short A_l[128*32];
    __shared__ __align__(16) short Wh_l[128*32];

    int tid  = threadIdx.x;
    int w    = tid >> 6;
    int lane = tid & 63;
    int ln   = lane & 15;
    int quad = lane >> 4;
    int rowBase = by * 128;
    int colBase = bx * 128;
    int mBase = (w & 1) * 64;
    int nBase = (w >> 1) * 64;

    int srow = (lane >> 2);
    int scol = (((lane & 3) ^ ((lane >> 3) & 3))) * 8;
    int cs = ((quad ^ ((ln >> 1) & 3))) * 8;
    const short* Abase = Ag  + (size_t)rowBase * 1024;
    const short* Whb   = Whg + (size_t)colBase * 1024;

    f32x4 acc[4][4];
#pragma unroll
    for (int i = 0; i < 4; i++)
#pragma unroll
        for (int j = 0; j < 4; j++) acc[i][j] = (f32x4){0.f, 0.f, 0.f, 0.f};

    for (int kk = 0; kk < 1024; kk += 32) {
#pragma unroll
        for (int j = 0; j < 2; j++) {
            int r = w*32 + j*16;
            size_t go = (size_t)(r + srow) * 1024 + kk + scol;
            __builtin_amdgcn_global_load_lds(AS1(Abase + go), AS3(A_l  + r*32), 16, 0, 0);
            __builtin_amdgcn_global_load_lds(AS1(Whb   + go), AS3(Wh_l + r*32), 16, 0, 0);
        }
        __syncthreads();

        short8 a[4], bh[4];
#pragma unroll
        for (int mt = 0; mt < 4; mt++)
            a[mt] = *(const short8*)(A_l + (mBase + mt*16 + ln)*32 + cs);
#pragma unroll
        for (int nt = 0; nt < 4; nt++)
            bh[nt] = *(const short8*)(Wh_l + (nBase + nt*16 + ln)*32 + cs);
#pragma unroll
        for (int mt = 0; mt < 4; mt++)
#pragma unroll
            for (int nt = 0; nt < 4; nt++)
                acc[mt][nt] = MFMA(a[mt], bh[nt], acc[mt][nt]);
        __syncthreads();
    }

#pragma unroll
    for (int mt = 0; mt < 4; mt++) {
#pragma unroll
        for (int nt = 0; nt < 4; nt++) {
            int col = colBase + nBase + nt*16 + ln;
            float bv = bias[col];
#pragma unroll
            for (int i = 0; i < 4; i++) {
                int row = rowBase + mBase + mt*16 + quad*4 + i;
                float val = acc[mt][nt][i] + bv;
                int b_  = row >> 11, s = row & 2047;
                int h   = col >> 6,  d = col & 63;
                int bh_ = b_ * 16 + h;
                size_t idx = (size_t)bh_ * 131072 + (size_t)(s >> 5) * 2048
                    + ((size_t)((((((s >> 4) & 1) * 2 + (d >> 5)) * 2 + ((s >> 3) & 1)) * 32)
                                + (d & 31))) * 8 + (s & 7);
                Vt[idx] = f2bf(val);
            }
        }
    }
}

// out = concat(bf16) @ Wo^T + bo (split Wo, fp32 out), LDS-staged + swizzled.
__global__ __launch_bounds__(256) void gemm_out(
    const short* __restrict__ Ag, const short* __restrict__ Whg,
    const short* __restrict__ Wlg, const float* __restrict__ bias,
    float* __restrict__ out)
{
    int lin = blockIdx.x + (blockIdx.y << 3);                  // [0,256)
    int tile = (lin & 7) * 32 + (lin >> 3);
    int bx = tile & 7, by = tile >> 3;

    __shared__ __align__(16) short A_l[128*32];
    __shared__ __align__(16) short Wh_l[128*32];
    __shared__ __align__(16) short Wl_l[128*32];

    int tid  = threadIdx.x;
    int w    = tid >> 6;
    int lane = tid & 63;
    int ln   = lane & 15;
    int quad = lane >> 4;
    int rowBase = by * 128;
    int colBase = bx * 128;
    int mBase = (w & 1) * 64;
    int nBase = (w >> 1) * 64;

    int srow = (lane >> 2);
    int scol = (((lane & 3) ^ ((lane >> 3) & 3))) * 8;
    int cs = ((quad ^ ((ln >> 1) & 3))) * 8;
    const short* Abase = Ag  + (size_t)rowBase * 1024;
    const short* Whb   = Whg + (size_t)colBase * 1024;
    const short* Wlb   = Wlg + (size_t)colBase * 1024;

    f32x4 acc[4][4];
#pragma unroll
    for (int i = 0; i < 4; i++)
#pragma unroll
        for (int j = 0; j < 4; j++) acc[i][j] = (f32x4){0.f, 0.f, 0.f, 0.f};

    for (int kk = 0; kk < 1024; kk += 32) {
#pragma unroll
        for (int j = 0; j < 2; j++) {
            int r = w*32 + j*16;
            size_t go = (size_t)(r + srow) * 1024 + kk + scol;
            __builtin_amdgcn_global_load_lds(AS1(Abase + go), AS3(A_l  + r*32), 16, 0, 0);
            __builtin_amdgcn_global_load_lds(AS1(Whb   + go), AS3(Wh_l + r*32), 16, 0, 0);
            __builtin_amdgcn_global_load_lds(AS1(Wlb   + go), AS3(Wl_l + r*32), 16, 0, 0);
        }
        __syncthreads();

        short8 a[4], bh[4], bl[4];
#pragma unroll
        for (int mt = 0; mt < 4; mt++)
            a[mt] = *(const short8*)(A_l + (mBase + mt*16 + ln)*32 + cs);
#pragma unroll
        for (int nt = 0; nt < 4; nt++) {
            int c = nBase + nt*16 + ln;
            bh[nt] = *(const short8*)(Wh_l + c*32 + cs);
            bl[nt] = *(const short8*)(Wl_l + c*32 + cs);
        }
#pragma unroll
        for (int mt = 0; mt < 4; mt++)
#pragma unroll
            for (int nt = 0; nt < 4; nt++) {
                acc[mt][nt] = MFMA(a[mt], bh[nt], acc[mt][nt]);
                acc[mt][nt] = MFMA(a[mt], bl[nt], acc[mt][nt]);
            }
        __syncthreads();
    }

#pragma unroll
    for (int mt = 0; mt < 4; mt++) {
#pragma unroll
        for (int nt = 0; nt < 4; nt++) {
            int col = colBase + nBase + nt*16 + ln;
            float bv = bias[col];
#pragma unroll
            for (int i = 0; i < 4; i++) {
                int row = rowBase + mBase + mt*16 + quad*4 + i;
                out[(size_t)row * 1024 + col] = acc[mt][nt][i] + bv;
            }
        }
    }
}

// rowsum[q] += sum over this block's k-quarter of 2^(c_qk), HI-ONLY scores.
__global__ __launch_bounds__(256) void attn_rowsum(
    const short* __restrict__ Qhi, const short* __restrict__ Khi,
    float* __restrict__ rowsum)
{
    int bh = blockIdx.z, tid = threadIdx.x;
    int w = tid >> 6, lane = tid & 63, ln = lane & 15, quad = lane >> 4;
    int qb  = blockIdx.x * 256 + w * 64;
    int kt0 = blockIdx.y * 32;            // 32 k-tiles of 16 = 512 keys
    const short* QH = Qhi + (size_t)bh * 131072;
    const short* KH = Khi + (size_t)bh * 131072;

    short8 qh[4][2];
#pragma unroll
    for (int mt = 0; mt < 4; mt++)
#pragma unroll
        for (int half = 0; half < 2; half++) {
            size_t o = (size_t)((qb >> 5) + (mt >> 1)) * 2048
                     + (size_t)(half * 4 + quad) * 256 + ((mt & 1) * 16 + ln) * 8;
            qh[mt][half] = *(const short8*)(QH + o);
        }

    short8 kh[2][2];   // [buf][dchunk]
    auto loadK = [&](int buf, int kt) {
        size_t ko = (size_t)(kt >> 1) * 2048 + (size_t)quad * 256 + ((kt & 1) * 16 + ln) * 8;
        kh[buf][0] = *(const short8*)(KH + ko);
        kh[buf][1] = *(const short8*)(KH + ko + 1024);
    };

    float racc[4][4] = {};
    auto comp = [&](int buf) {
#pragma unroll
        for (int mt = 0; mt < 4; mt++) {
            f32x4 c1 = (f32x4){0.f,0.f,0.f,0.f};
            c1 = MFMA(qh[mt][0], kh[buf][0], c1);
            c1 = MFMA(qh[mt][1], kh[buf][1], c1);
#pragma unroll
            for (int i = 0; i < 4; i++)
                racc[mt][i] += PEXP(c1[i]);
        }
    };

    loadK(0, kt0);
    for (int t = 0; t < 32; t += 2) {
        loadK(1, kt0 + t + 1);
        comp(0);
        if (t + 2 < 32) loadK(0, kt0 + t + 2);
        comp(1);
    }
#pragma unroll
    for (int mt = 0; mt < 4; mt++)
#pragma unroll
        for (int i = 0; i < 4; i++)
            for (int d = 1; d < 16; d <<= 1)
                racc[mt][i] += __shfl_xor(racc[mt][i], d, 64);
    if (ln == 0) {
#pragma unroll
        for (int mt = 0; mt < 4; mt++)
#pragma unroll
            for (int i = 0; i < 4; i++)
                atomicAdd(&rowsum[bh * 2048 + qb + mt*16 + quad*4 + i], racc[mt][i]);
    }
}

// colsum[k] += sum over this block's q-quarter of 2^(c_qk)/rowsum[q].
// 3-term split kept (feeds the top-k ranking).
__global__ __launch_bounds__(256) void attn_colsum(
    const short* __restrict__ Qhi, const short* __restrict__ Qlo,
    const short* __restrict__ Khi, const short* __restrict__ Klo,
    const float* __restrict__ rowsum, float* __restrict__ colsum)
{
    __shared__ float sli[512];
    int bh = blockIdx.z, tid = threadIdx.x;
    int q0 = blockIdx.y * 512;
    for (int j = tid; j < 512; j += 256)
        sli[j] = 1.0f / rowsum[bh * 2048 + q0 + j];
    __syncthreads();

    int w = tid >> 6, lane = tid & 63, ln = lane & 15, quad = lane >> 4;
    int kb  = blockIdx.x * 256 + w * 64;
    int qt0 = blockIdx.y * 32;            // 32 q-tiles of 16
    const short* QH = Qhi + (size_t)bh * 131072;
    const short* QL = Qlo + (size_t)bh * 131072;
    const short* KH = Khi + (size_t)bh * 131072;
    const short* KL = Klo + (size_t)bh * 131072;

    short8 kh[4][2], kl[4][2];
#pragma unroll
    for (int nt = 0; nt < 4; nt++)
#pragma unroll
        for (int half = 0; half < 2; half++) {
            size_t o = (size_t)((kb >> 5) + (nt >> 1)) * 2048 + (size_t)half * 1024
                     + (size_t)quad * 256 + ((nt & 1) * 16 + ln) * 8;
            kh[nt][half] = *(const short8*)(KH + o);
            kl[nt][half] = *(const short8*)(KL + o);
        }

    short8 qh[2][2], ql[2][2];   // [buf][half]
    auto loadQ = [&](int buf, int qt) {
        int qtt = qt0 + qt;
        size_t base = (size_t)(qtt >> 1) * 2048 + ((qtt & 1) * 16 + ln) * 8;
        qh[buf][0] = *(const short8*)(QH + base + (size_t)quad * 256);
        qh[buf][1] = *(const short8*)(QH + base + (size_t)(4 + quad) * 256);
        ql[buf][0] = *(const short8*)(QL + base + (size_t)quad * 256);
        ql[buf][1] = *(const short8*)(QL + base + (size_t)(4 + quad) * 256);
    };

    float cacc[4] = {0.f, 0.f, 0.f, 0.f};
    auto comp = [&](int buf, int qt) {
#pragma unroll
        for (int nt = 0; nt < 4; nt++) {
            f32x4 c1 = (f32x4){0.f,0.f,0.f,0.f};
            f32x4 c2 = (f32x4){0.f,0.f,0.f,0.f};
            c1 = MFMA(qh[buf][0], kh[nt][0], c1); c1 = MFMA(qh[buf][1], kh[nt][1], c1);
            c2 = MFMA(qh[buf][0], kl[nt][0], c2); c2 = MFMA(qh[buf][1], kl[nt][1], c2);
            c2 = MFMA(ql[buf][0], kh[nt][0], c2); c2 = MFMA(ql[buf][1], kh[nt][1], c2);
#pragma unroll
            for (int i = 0; i < 4; i++) {
                int r = qt*16 + quad*4 + i;
                cacc[nt] += PEXP(c1[i] + c2[i]) * sli[r];
            }
        }
    };

    loadQ(0, 0);
    for (int qt = 0; qt < 32; qt += 2) {
        loadQ(1, qt + 1);
        comp(0, qt);
        if (qt + 2 < 32) loadQ(0, qt + 2);
        comp(1, qt + 1);
    }
#pragma unroll
    for (int nt = 0; nt < 4; nt++) {
        cacc[nt] += __shfl_xor(cacc[nt], 16, 64);
        cacc[nt] += __shfl_xor(cacc[nt], 32, 64);
        if (lane < 16) atomicAdd(&colsum[bh * 2048 + kb + nt*16 + lane], cacc[nt]);
    }
}

// Per (b,h): threshold = KEEP-th largest colsum via 4-level radix select.
// mask = colsum >= threshold (same tie semantics as the old binary search:
// the threshold is exactly the KEEP-th largest monotone key).
__global__ __launch_bounds__(256) void topk_mask(
    const float* __restrict__ colsum, float* __restrict__ maskf)
{
    __shared__ unsigned keys[2048];
    __shared__ int hist[256];
    __shared__ unsigned sh_pref;
    __shared__ int sh_need;
    int bh = blockIdx.x, tid = threadIdx.x;
    for (int j = tid; j < 2048; j += 256) {
        unsigned u = __float_as_uint(colsum[bh * 2048 + j]);
        keys[j] = (u & 0x80000000u) ? ~u : (u | 0x80000000u);
    }
    if (tid == 0) { sh_pref = 0; sh_need = KEEP; }
    __syncthreads();
#pragma unroll
    for (int shift = 24; shift >= 0; shift -= 8) {
        hist[tid & 255] = 0;
        __syncthreads();
        unsigned pref = sh_pref;
        unsigned hmask = (shift == 24) ? 0u : (0xFFFFFFFFu << (shift + 8));
        for (int j = tid; j < 2048; j += 256) {
            unsigned ky = keys[j];
            if ((ky & hmask) == pref)
                atomicAdd(&hist[(ky >> shift) & 255], 1);
        }
        __syncthreads();
        if (tid == 0) {
            int need = sh_need, acc = 0, d = 255;
            for (; d >= 0; d--) {
                if (acc + hist[d] >= need) break;
                acc += hist[d];
            }
            sh_pref = pref | ((unsigned)d << shift);
            sh_need = need - acc;
        }
        __syncthreads();
    }
    unsigned thr = sh_pref;
    for (int j = tid; j < 2048; j += 256)
        maskf[bh * 2048 + j] = (keys[j] >= thr) ? 1.0f : 0.0f;
}

// V (frag-major) *= mask. Group g of 8 shorts covers 8 consecutive k for one d:
// k0 = (g>>8)*32 + ((g>>7)&1)*16 + ((g>>5)&1)*8
__global__ __launch_bounds__(256) void mask_v(
    unsigned short* __restrict__ Vt, const float* __restrict__ maskf)
{
    int i = blockIdx.x * 256 + threadIdx.x;   // short8 group; 32 bh x 16384 groups
    int g  = i & 16383;
    int bh = i >> 14;
    int k0 = (g >> 8) * 32 + ((g >> 7) & 1) * 16 + ((g >> 5) & 1) * 8;
    const float* m = maskf + bh * 2048 + k0;
    short8 v = ((short8*)Vt)[i];
#pragma unroll
    for (int j = 0; j < 8; j++)
        if (m[j] == 0.0f) v[j] = 0;
    ((short8*)Vt)[i] = v;
}

// PV with swapped-operand QK^T, in-register P, block-level LDS staging of
// frag-major K/V chunks. XCD-chunked remap keeps a bh's blocks on one XCD.
__global__ __launch_bounds__(256) void attn_av(
    const short* __restrict__ Qhi, const short* __restrict__ Kf,
    const short* __restrict__ Vf, const float* __restrict__ rowsum,
    unsigned short* __restrict__ concat)
{
    __shared__ __align__(16) short KA[4096];   // [0,2048): K chunk, [2048,4096): V chunk
    __shared__ __align__(16) short KB[4096];
    int lin = blockIdx.x + (blockIdx.y << 4);          // [0,512)
    int tile = (lin & 7) * 64 + (lin >> 3);
    int bxx = tile & 15, bh = tile >> 4;
    int tid = threadIdx.x;
    int w = tid >> 6, lane = tid & 63;
    int lq = lane & 31, hi = lane >> 5;
    int qb = bxx * 128 + w * 32;
    const short* Qb = Qhi + (size_t)bh * 131072 + (size_t)(qb >> 5) * 2048;
    const short* Kg = Kf  + (size_t)bh * 131072;
    const short* Vg = Vf  + (size_t)bh * 131072;

    short8 qf[4];
#pragma unroll
    for (int d = 0; d < 4; d++)
        qf[d] = *(const short8*)(Qb + (size_t)(d*2 + hi) * 256 + lq * 8);

    f32x16 o0, o1;
#pragma unroll
    for (int i = 0; i < 16; i++) { o0[i] = 0.f; o1[i] = 0.f; }

    auto STAGE = [&](short* B, int kc) {
        __builtin_amdgcn_global_load_lds(AS1(Kg + (size_t)kc*2048 + tid*8),
                                         AS3(B + w*512), 16, 0, 0);
        __builtin_amdgcn_global_load_lds(AS1(Vg + (size_t)kc*2048 + tid*8),
                                         AS3(B + 2048 + w*512), 16, 0, 0);
    };

    auto comp = [&](const short* B) {
        short8 kf_[4], vf_[4];
#pragma unroll
        for (int d = 0; d < 4; d++)
            kf_[d] = *(const short8*)(B + (d*2 + hi)*256 + lq*8);
#pragma unroll
        for (int ks = 0; ks < 2; ks++)
#pragma unroll
            for (int nt = 0; nt < 2; nt++)
                vf_[ks*2+nt] = *(const short8*)(B + 2048 + ((ks*2+nt)*2 + hi)*256 + lq*8);

        f32x16 s;
#pragma unroll
        for (int i = 0; i < 16; i++) s[i] = 0.f;
        s = MFMA32(kf_[0], qf[0], s);
        s = MFMA32(kf_[1], qf[1], s);
        s = MFMA32(kf_[2], qf[2], s);
        s = MFMA32(kf_[3], qf[3], s);

        float p[16];
#pragma unroll
        for (int i = 0; i < 16; i++) p[i] = PEXP(s[i]);

        short8 pa[2];
#pragma unroll
        for (int ks = 0; ks < 2; ks++) {
            unsigned w0, w1, w2, w3;
            int o8 = ks * 8;
            asm("v_cvt_pk_bf16_f32 %0, %1, %2" : "=v"(w0) : "v"(p[o8+0]), "v"(p[o8+1]));
            asm("v_cvt_pk_bf16_f32 %0, %1, %2" : "=v"(w1) : "v"(p[o8+2]), "v"(p[o8+3]));
            asm("v_cvt_pk_bf16_f32 %0, %1, %2" : "=v"(w2) : "v"(p[o8+4]), "v"(p[o8+5]));
            asm("v_cvt_pk_bf16_f32 %0, %1, %2" : "=v"(w3) : "v"(p[o8+6]), "v"(p[o8+7]));
            asm("v_permlane32_swap_b32 %0, %1" : "+v"(w0), "+v"(w2));
            asm("v_permlane32_swap_b32 %0, %1" : "+v"(w1), "+v"(w3));
            u32x4 pw = { w0, w1, w2, w3 };
            pa[ks] = __builtin_bit_cast(short8, pw);
        }

        o0 = MFMA32(pa[0], vf_[0], o0);
        o1 = MFMA32(pa[0], vf_[1], o1);
        o0 = MFMA32(pa[1], vf_[2], o0);
        o1 = MFMA32(pa[1], vf_[3], o1);
    };

    STAGE(KA, 0);
    __syncthreads();
    for (int kc = 0; kc < 64; kc += 2) {
        STAGE(KB, kc + 1);          // next chunk's loads fly under compute
        comp(KA);
        __syncthreads();            // publishes KB, guards KA reuse
        if (kc + 2 < 64) STAGE(KA, kc + 2);
        comp(KB);
        __syncthreads();
    }

    int b_ = bh >> 4, h = bh & 15;
#pragma unroll
    for (int r = 0; r < 16; r++) {
        int crow = (r & 3) + 8*(r >> 2) + 4*hi;
        float inv = 1.0f / rowsum[bh * 2048 + qb + crow];
        size_t base = ((size_t)(b_*2048 + qb + crow)) * 1024 + h*64;
        concat[base + lq]      = f2bf(o0[r] * inv);
        concat[base + 32 + lq] = f2bf(o1[r] * inv);
    }
}

extern "C" void kernel_launch(void* const* d_in, const int* in_sizes, int n_in,
                              void* d_out, int out_size, void* d_ws, size_t ws_size,
                              hipStream_t stream)
{
    const float* q  = (const float*)d_in[0];
    const float* k  = (const float*)d_in[1];
    const float* v  = (const float*)d_in[2];
    const float* Wq = (const float*)d_in[3];
    const float* bq = (const float*)d_in[4];
    const float* Wk = (const float*)d_in[5];
    const float* bk = (const float*)d_in[6];
    const float* Wv = (const float*)d_in[7];
    const float* bv = (const float*)d_in[8];
    const float* Wo = (const float*)d_in[9];
    const float* bo = (const float*)d_in[10];

    char* ws = (char*)d_ws;
    size_t off = 0;
    auto alloc = [&](size_t bytes) -> void* {
        void* p = ws + off;
        off += (bytes + 255) & ~(size_t)255;
        return p;
    };
    const size_t ASZ = (size_t)4096 * 1024 * 2;   // 8.4 MB bf16 activation
    const size_t WSZ = (size_t)1024 * 1024 * 2;   // 2 MB bf16 weight
    unsigned short* qh_ = (unsigned short*)alloc(ASZ);
    unsigned short* ql_ = (unsigned short*)alloc(ASZ);
    unsigned short* kh_ = (unsigned short*)alloc(ASZ);
    unsigned short* kl_ = (unsigned short*)alloc(ASZ);
    unsigned short* vh_ = (unsigned short*)alloc(ASZ);
    unsigned short* wqh = (unsigned short*)alloc(WSZ);
    unsigned short* wql = (unsigned short*)alloc(WSZ);
    unsigned short* wkh = (unsigned short*)alloc(WSZ);
    unsigned short* wkl = (unsigned short*)alloc(WSZ);
    unsigned short* wvh = (unsigned short*)alloc(WSZ);
    unsigned short* woh = (unsigned short*)alloc(WSZ);
    unsigned short* wol = (unsigned short*)alloc(WSZ);
    short* Qhi = (short*)alloc(ASZ);   // frag-major
    short* Qlo = (short*)alloc(ASZ);   // frag-major
    short* Khi = (short*)alloc(ASZ);   // frag-major
    short* Klo = (short*)alloc(ASZ);   // frag-major
    short* Vt  = (short*)alloc(ASZ);   // frag-major
    float* rowsum = (float*)alloc((size_t)32 * 2048 * 4);
    float* colsum = (float*)alloc((size_t)32 * 2048 * 4);
    float* maskf  = (float*)alloc((size_t)32 * 2048 * 4);
    unsigned short* concat = (unsigned short*)alloc(ASZ);
    // total ~110 MB (known-safe)

    dim3 blk(256);

    cvt_all<<<dim3(16384), blk, 0, stream>>>(
        q, k, v, Wq, Wk, Wv, Wo,
        qh_, ql_, kh_, kl_, vh_, wqh, wql, wkh, wkl, wvh, woh, wol);
    zero_f32<<<dim3(512), blk, 0, stream>>>(rowsum, 2 * 32 * 2048);  // rowsum+colsum

    gemm_qkv<<<dim3(8, 32, 2), blk, 0, stream>>>(
        (const short*)qh_, (const short*)ql_, (const short*)kh_, (const short*)kl_,
        (const short*)wqh, (const short*)wql, (const short*)wkh, (const short*)wkl,
        bq, bk,
        (unsigned short*)Qhi, (unsigned short*)Qlo,
        (unsigned short*)Khi, (unsigned short*)Klo);
    gemm_v<<<dim3(8, 32), blk, 0, stream>>>(
        (const short*)vh_, (const short*)wvh, bv, (unsigned short*)Vt);

    attn_rowsum<<<dim3(8, 4, 32), blk, 0, stream>>>(Qhi, Khi, rowsum);
    attn_colsum<<<dim3(8, 4, 32), blk, 0, stream>>>(Qhi, Qlo, Khi, Klo, rowsum, colsum);
    topk_mask  <<<dim3(32),   blk, 0, stream>>>(colsum, maskf);
    mask_v     <<<dim3(2048), blk, 0, stream>>>((unsigned short*)Vt, maskf);
    attn_av    <<<dim3(16, 32), blk, 0, stream>>>(Qhi, Khi, Vt, rowsum, concat);

    gemm_out<<<dim3(8, 32), blk, 0, stream>>>((const short*)concat,
        (const short*)woh, (const short*)wol, bo, (float*)d_out);
}

// Round 8
// 394.000 us; speedup vs baseline: 1.8133x; 1.0376x over previous
//
#include <hip/hip_runtime.h>

// ---------------------------------------------------------------------------
// Pruned multi-head attention. fp32 I/O, split-bf16 (hi+lo) MFMA compute.
// B=2, S=2048, D_MODEL=1024, H=16, d_k=64, keep=int(2048*0.9)=1843
//
// Round 16: gemm_v and gemm_out were launching 256 blocks = 1 block/CU =
// 1 wave/SIMD (zero latency hiding). Both rebuilt as 128x64 tiles ->
// 512 blocks (2 blocks/CU). gemm_v additionally moved AFTER topk_mask with
// the prune mask fused into its epilogue (val *= mask before f2bf; f2bf(0)=0
// so bit-identical to the old mask_v post-pass) — mask_v kernel deleted.
// gemm_qkv untouched (817 TF effective, at its 2-barrier ceiling).
// ---------------------------------------------------------------------------

typedef __attribute__((ext_vector_type(8))) short short8;   // 8 bf16 (4 VGPRs)
typedef __attribute__((ext_vector_type(4))) short short4v;
typedef __attribute__((ext_vector_type(4))) float f32x4;
typedef __attribute__((ext_vector_type(16))) float f32x16;
typedef __attribute__((ext_vector_type(4))) unsigned int u32x4;

#define KEEP 1843

#if __has_builtin(__builtin_amdgcn_exp2f)
  #define PEXP(x) __builtin_amdgcn_exp2f(x)
  #define QSC 0.18033688011112042f   // log2(e)/8 folded into Q projection
#else
  #define PEXP(x) __expf(x)
  #define QSC 0.125f
#endif

#define AS1(p) ((const __attribute__((address_space(1))) void*)(p))
#define AS3(p) ((__attribute__((address_space(3))) void*)(p))

static __device__ __forceinline__ float bf2f(unsigned short s) {
    union { unsigned u; float f; } v; v.u = ((unsigned)s) << 16; return v.f;
}
static __device__ __forceinline__ unsigned short f2bf(float f) {
    union { float f; unsigned u; } v; v.f = f;
    unsigned u = v.u;
    unsigned r = (u + 0x7FFFu + ((u >> 16) & 1u)) >> 16;   // RNE
    return (unsigned short)r;
}

#define MFMA(A, B, C)   __builtin_amdgcn_mfma_f32_16x16x32_bf16(A, B, C, 0, 0, 0)
#define MFMA32(A, B, C) __builtin_amdgcn_mfma_f32_32x32x16_bf16(A, B, C, 0, 0, 0)

// Fragment-major layout for Q and K (per bh, 131072 shorts):
//   (s,d) -> (s>>5)*2048 + (((d>>4)*2 + ((d>>3)&1))*32 + (s&31))*8 + (d&7)
// Fragment-major V layout (per bh):
//   (s,d) -> (s>>5)*2048 + ((((((s>>4)&1)*2 + (d>>5))*2 + ((s>>3)&1))*32) + (d&31))*8 + (s&7)

// All 7 fp32->bf16(hi/lo) conversions in one launch. Segments:
// 0:q 1:k 2:v(hi only) 3:Wq 4:Wk 5:Wv(hi only) 6:Wo
__global__ __launch_bounds__(256) void cvt_all(
    const float* __restrict__ q,  const float* __restrict__ k,
    const float* __restrict__ v,  const float* __restrict__ Wq,
    const float* __restrict__ Wk, const float* __restrict__ Wv,
    const float* __restrict__ Wo,
    unsigned short* __restrict__ qh, unsigned short* __restrict__ ql,
    unsigned short* __restrict__ kh, unsigned short* __restrict__ kl,
    unsigned short* __restrict__ vh,
    unsigned short* __restrict__ wqh, unsigned short* __restrict__ wql,
    unsigned short* __restrict__ wkh, unsigned short* __restrict__ wkl,
    unsigned short* __restrict__ wvh,
    unsigned short* __restrict__ woh, unsigned short* __restrict__ wol)
{
    int g = blockIdx.x * 256 + threadIdx.x;      // [0, 4194304)
    const float* in; unsigned short* oh; unsigned short* ol; int idx;
    if (g < 3145728) {                           // activations: 3 x 2^20 groups
        int seg = g >> 20; idx = g & 1048575;
        if (seg == 0)      { in = q; oh = qh;  ol = ql;  }
        else if (seg == 1) { in = k; oh = kh;  ol = kl;  }
        else               { in = v; oh = vh;  ol = 0;   }
    } else {                                     // weights: 4 x 2^18 groups
        int gw = g - 3145728; int seg = gw >> 18; idx = gw & 262143;
        if (seg == 0)      { in = Wq; oh = wqh; ol = wql; }
        else if (seg == 1) { in = Wk; oh = wkh; ol = wkl; }
        else if (seg == 2) { in = Wv; oh = wvh; ol = 0;   }
        else               { in = Wo; oh = woh; ol = wol; }
    }
    f32x4 x = ((const f32x4*)in)[idx];
    short4v h, l;
#pragma unroll
    for (int j = 0; j < 4; j++) {
        unsigned short hv = f2bf(x[j]);
        h[j] = (short)hv;
        l[j] = (short)f2bf(x[j] - bf2f(hv));
    }
    ((short4v*)oh)[idx] = h;
    if (ol) ((short4v*)ol)[idx] = l;
}

__global__ __launch_bounds__(256) void zero_f32(float* __restrict__ p, int n) {
    int i = blockIdx.x * 256 + threadIdx.x;
    if (i < n) p[i] = 0.f;
}

// Fused Q/K projections (split hi+lo, 3-term), LDS-staged + swizzled.
// 128x128 tile, BK=32. z=0: Q (scaled QSC); z=1: K. Both frag-major hi+lo.
__global__ __launch_bounds__(256) void gemm_qkv(
    const short* __restrict__ A0, const short* __restrict__ Al0,
    const short* __restrict__ A1, const short* __restrict__ Al1,
    const short* __restrict__ W0, const short* __restrict__ Wl0,
    const short* __restrict__ W1, const short* __restrict__ Wl1,
    const float* __restrict__ b0, const float* __restrict__ b1,
    unsigned short* __restrict__ Qhi, unsigned short* __restrict__ Qlo,
    unsigned short* __restrict__ Khi, unsigned short* __restrict__ Klo)
{
    // XCD-chunked remap over 512 blocks: each XCD owns 64 consecutive tiles.
    int lin = blockIdx.x + (blockIdx.y << 3) + (blockIdx.z << 8);   // [0,512)
    int tile = (lin & 7) * 64 + (lin >> 3);
    int bx = tile & 7, by = (tile >> 3) & 31, bz = tile >> 8;

    const short *Ahg, *Alg, *Whg, *Wlg; const float* bias;
    unsigned short *oh, *ol; float scale;
    if (bz == 0) { Ahg=A0; Alg=Al0; Whg=W0; Wlg=Wl0; bias=b0; oh=Qhi; ol=Qlo; scale=QSC;  }
    else         { Ahg=A1; Alg=Al1; Whg=W1; Wlg=Wl1; bias=b1; oh=Khi; ol=Klo; scale=1.0f; }

    __shared__ __align__(16) short Ah_l[128*32];
    __shared__ __align__(16) short Al_l[128*32];
    __shared__ __align__(16) short Wh_l[128*32];
    __shared__ __align__(16) short Wl_l[128*32];

    int tid  = threadIdx.x;
    int w    = tid >> 6;
    int lane = tid & 63;
    int ln   = lane & 15;
    int quad = lane >> 4;
    int rowBase = by * 128;
    int colBase = bx * 128;
    int mBase = (w & 1) * 64;        // wave's quadrant inside 128x128
    int nBase = (w >> 1) * 64;

    int srow = (lane >> 2);
    int scol = (((lane & 3) ^ ((lane >> 3) & 3))) * 8;
    int cs = ((quad ^ ((ln >> 1) & 3))) * 8;

    const short* Ag_h = Ahg + (size_t)rowBase * 1024;
    const short* Ag_l = Alg + (size_t)rowBase * 1024;
    const short* Wg_h = Whg + (size_t)colBase * 1024;
    const short* Wg_l = Wlg + (size_t)colBase * 1024;

    f32x4 acc[4][4];
#pragma unroll
    for (int i = 0; i < 4; i++)
#pragma unroll
        for (int j = 0; j < 4; j++) acc[i][j] = (f32x4){0.f, 0.f, 0.f, 0.f};

    for (int kk = 0; kk < 1024; kk += 32) {
#pragma unroll
        for (int j = 0; j < 2; j++) {
            int r = w*32 + j*16;
            size_t go = (size_t)(r + srow) * 1024 + kk + scol;
            __builtin_amdgcn_global_load_lds(AS1(Ag_h + go), AS3(Ah_l + r*32), 16, 0, 0);
            __builtin_amdgcn_global_load_lds(AS1(Ag_l + go), AS3(Al_l + r*32), 16, 0, 0);
            __builtin_amdgcn_global_load_lds(AS1(Wg_h + go), AS3(Wh_l + r*32), 16, 0, 0);
            __builtin_amdgcn_global_load_lds(AS1(Wg_l + go), AS3(Wl_l + r*32), 16, 0, 0);
        }
        __syncthreads();

        short8 ah[4], al[4], bh[4], bl[4];
#pragma unroll
        for (int mt = 0; mt < 4; mt++) {
            int r = mBase + mt*16 + ln;
            ah[mt] = *(const short8*)(Ah_l + r*32 + cs);
            al[mt] = *(const short8*)(Al_l + r*32 + cs);
        }
#pragma unroll
        for (int nt = 0; nt < 4; nt++) {
            int c = nBase + nt*16 + ln;
            bh[nt] = *(const short8*)(Wh_l + c*32 + cs);
            bl[nt] = *(const short8*)(Wl_l + c*32 + cs);
        }
#pragma unroll
        for (int mt = 0; mt < 4; mt++)
#pragma unroll
            for (int nt = 0; nt < 4; nt++) {
                acc[mt][nt] = MFMA(ah[mt], bh[nt], acc[mt][nt]);
                acc[mt][nt] = MFMA(ah[mt], bl[nt], acc[mt][nt]);
                acc[mt][nt] = MFMA(al[mt], bh[nt], acc[mt][nt]);
            }
        __syncthreads();
    }

#pragma unroll
    for (int mt = 0; mt < 4; mt++) {
#pragma unroll
        for (int nt = 0; nt < 4; nt++) {
            int col = colBase + nBase + nt*16 + ln;
            float bv = bias[col];
#pragma unroll
            for (int i = 0; i < 4; i++) {
                int row = rowBase + mBase + mt*16 + quad*4 + i;   // D: row=quad*4+reg
                float val = (acc[mt][nt][i] + bv) * scale;
                int b_  = row >> 11, s = row & 2047;
                int h   = col >> 6,  d = col & 63;
                int bh_ = b_ * 16 + h;
                size_t idx = (size_t)bh_ * 131072 + (size_t)(s >> 5) * 2048
                    + ((size_t)(((d >> 4) * 2 + ((d >> 3) & 1)) * 32 + (s & 31))) * 8 + (d & 7);
                unsigned short hv = f2bf(val);
                oh[idx] = hv;
                ol[idx] = f2bf(val - bf2f(hv));
            }
        }
    }
}

// V projection, 1-term (hi x hi), 128x64 tile (512 blocks = 2/CU), with the
// prune mask fused into the epilogue (runs after topk_mask). Frag-major V.
__global__ __launch_bounds__(256) void gemm_v(
    const short* __restrict__ Ag, const short* __restrict__ Whg,
    const float* __restrict__ bias, const float* __restrict__ maskf,
    unsigned short* __restrict__ Vt)
{
    int lin = blockIdx.x + (blockIdx.y << 4);                  // [0,512)
    int tile = (lin & 7) * 64 + (lin >> 3);
    int bx = tile & 15, by = tile >> 4;

    __shared__ __align__(16) short A_l[128*32];
    __shared__ __align__(16) short Wh_l[64*32];

    int tid  = threadIdx.x;
    int w    = tid >> 6;
    int lane = tid & 63;
    int ln   = lane & 15;
    int quad = lane >> 4;
    int rowBase = by * 128;
    int colBase = bx * 64;
    int mBase = (w & 1) * 64;
    int nBase = (w >> 1) * 32;

    int srow = (lane >> 2);
    int scol = (((lane & 3) ^ ((lane >> 3) & 3))) * 8;
    int cs = ((quad ^ ((ln >> 1) & 3))) * 8;
    const short* Abase = Ag  + (size_t)rowBase * 1024;
    const short* Whb   = Whg + (size_t)colBase * 1024;

    f32x4 acc[4][2];
#pragma unroll
    for (int i = 0; i < 4; i++)
#pragma unroll
        for (int j = 0; j < 2; j++) acc[i][j] = (f32x4){0.f, 0.f, 0.f, 0.f};

    for (int kk = 0; kk < 1024; kk += 32) {
#pragma unroll
        for (int j = 0; j < 2; j++) {
            int r = w*32 + j*16;
            size_t go = (size_t)(r + srow) * 1024 + kk + scol;
            __builtin_amdgcn_global_load_lds(AS1(Abase + go), AS3(A_l + r*32), 16, 0, 0);
        }
        {
            int c = w * 16;   // wave stages 16 W-rows (64-row tile / 4 waves)
            size_t go = (size_t)(c + srow) * 1024 + kk + scol;
            __builtin_amdgcn_global_load_lds(AS1(Whb + go), AS3(Wh_l + c*32), 16, 0, 0);
        }
        __syncthreads();

        short8 a[4], bh2[2];
#pragma unroll
        for (int mt = 0; mt < 4; mt++)
            a[mt] = *(const short8*)(A_l + (mBase + mt*16 + ln)*32 + cs);
#pragma unroll
        for (int nt = 0; nt < 2; nt++)
            bh2[nt] = *(const short8*)(Wh_l + (nBase + nt*16 + ln)*32 + cs);
#pragma unroll
        for (int mt = 0; mt < 4; mt++)
#pragma unroll
            for (int nt = 0; nt < 2; nt++)
                acc[mt][nt] = MFMA(a[mt], bh2[nt], acc[mt][nt]);
        __syncthreads();
    }

#pragma unroll
    for (int mt = 0; mt < 4; mt++) {
#pragma unroll
        for (int nt = 0; nt < 2; nt++) {
            int col = colBase + nBase + nt*16 + ln;
            float bv = bias[col];
#pragma unroll
            for (int i = 0; i < 4; i++) {
                int row = rowBase + mBase + mt*16 + quad*4 + i;
                float val = acc[mt][nt][i] + bv;
                int b_  = row >> 11, s = row & 2047;
                int h   = col >> 6,  d = col & 63;
                int bh_ = b_ * 16 + h;
                val *= maskf[bh_ * 2048 + s];   // fused prune mask (0/1)
                size_t idx = (size_t)bh_ * 131072 + (size_t)(s >> 5) * 2048
                    + ((size_t)((((((s >> 4) & 1) * 2 + (d >> 5)) * 2 + ((s >> 3) & 1)) * 32)
                                + (d & 31))) * 8 + (s & 7);
                Vt[idx] = f2bf(val);
            }
        }
    }
}

// out = concat(bf16) @ Wo^T + bo (split Wo, fp32 out), 128x64 tile
// (512 blocks = 2/CU), LDS-staged + swizzled.
__global__ __launch_bounds__(256) void gemm_out(
    const short* __restrict__ Ag, const short* __restrict__ Whg,
    const short* __restrict__ Wlg, const float* __restrict__ bias,
    float* __restrict__ out)
{
    int lin = blockIdx.x + (blockIdx.y << 4);                  // [0,512)
    int tile = (lin & 7) * 64 + (lin >> 3);
    int bx = tile & 15, by = tile >> 4;

    __shared__ __align__(16) short A_l[128*32];
    __shared__ __align__(16) short Wh_l[64*32];
    __shared__ __align__(16) short Wl_l[64*32];

    int tid  = threadIdx.x;
    int w    = tid >> 6;
    int lane = tid & 63;
    int ln   = lane & 15;
    int quad = lane >> 4;
    int rowBase = by * 128;
    int colBase = bx * 64;
    int mBase = (w & 1) * 64;
    int nBase = (w >> 1) * 32;

    int srow = (lane >> 2);
    int scol = (((lane & 3) ^ ((lane >> 3) & 3))) * 8;
    int cs = ((quad ^ ((ln >> 1) & 3))) * 8;
    const short* Abase = Ag  + (size_t)rowBase * 1024;
    const short* Whb   = Whg + (size_t)colBase * 1024;
    const short* Wlb   = Wlg + (size_t)colBase * 1024;

    f32x4 acc[4][2];
#pragma unroll
    for (int i = 0; i < 4; i++)
#pragma unroll
        for (int j = 0; j < 2; j++) acc[i][j] = (f32x4){0.f, 0.f, 0.f, 0.f};

    for (int kk = 0; kk < 1024; kk += 32) {
#pragma unroll
        for (int j = 0; j < 2; j++) {
            int r = w*32 + j*16;
            size_t go = (size_t)(r + srow) * 1024 + kk + scol;
            __builtin_amdgcn_global_load_lds(AS1(Abase + go), AS3(A_l + r*32), 16, 0, 0);
        }
        {
            int c = w * 16;
            size_t go = (size_t)(c + srow) * 1024 + kk + scol;
            __builtin_amdgcn_global_load_lds(AS1(Whb + go), AS3(Wh_l + c*32), 16, 0, 0);
            __builtin_amdgcn_global_load_lds(AS1(Wlb + go), AS3(Wl_l + c*32), 16, 0, 0);
        }
        __syncthreads();

        short8 a[4], bh2[2], bl2[2];
#pragma unroll
        for (int mt = 0; mt < 4; mt++)
            a[mt] = *(const short8*)(A_l + (mBase + mt*16 + ln)*32 + cs);
#pragma unroll
        for (int nt = 0; nt < 2; nt++) {
            int c = nBase + nt*16 + ln;
            bh2[nt] = *(const short8*)(Wh_l + c*32 + cs);
            bl2[nt] = *(const short8*)(Wl_l + c*32 + cs);
        }
#pragma unroll
        for (int mt = 0; mt < 4; mt++)
#pragma unroll
            for (int nt = 0; nt < 2; nt++) {
                acc[mt][nt] = MFMA(a[mt], bh2[nt], acc[mt][nt]);
                acc[mt][nt] = MFMA(a[mt], bl2[nt], acc[mt][nt]);
            }
        __syncthreads();
    }

#pragma unroll
    for (int mt = 0; mt < 4; mt++) {
#pragma unroll
        for (int nt = 0; nt < 2; nt++) {
            int col = colBase + nBase + nt*16 + ln;
            float bv = bias[col];
#pragma unroll
            for (int i = 0; i < 4; i++) {
                int row = rowBase + mBase + mt*16 + quad*4 + i;
                out[(size_t)row * 1024 + col] = acc[mt][nt][i] + bv;
            }
        }
    }
}

// rowsum[q] += sum over this block's k-quarter of 2^(c_qk), HI-ONLY scores.
__global__ __launch_bounds__(256) void attn_rowsum(
    const short* __restrict__ Qhi, const short* __restrict__ Khi,
    float* __restrict__ rowsum)
{
    int bh = blockIdx.z, tid = threadIdx.x;
    int w = tid >> 6, lane = tid & 63, ln = lane & 15, quad = lane >> 4;
    int qb  = blockIdx.x * 256 + w * 64;
    int kt0 = blockIdx.y * 32;            // 32 k-tiles of 16 = 512 keys
    const short* QH = Qhi + (size_t)bh * 131072;
    const short* KH = Khi + (size_t)bh * 131072;

    short8 qh[4][2];
#pragma unroll
    for (int mt = 0; mt < 4; mt++)
#pragma unroll
        for (int half = 0; half < 2; half++) {
            size_t o = (size_t)((qb >> 5) + (mt >> 1)) * 2048
                     + (size_t)(half * 4 + quad) * 256 + ((mt & 1) * 16 + ln) * 8;
            qh[mt][half] = *(const short8*)(QH + o);
        }

    short8 kh[2][2];   // [buf][dchunk]
    auto loadK = [&](int buf, int kt) {
        size_t ko = (size_t)(kt >> 1) * 2048 + (size_t)quad * 256 + ((kt & 1) * 16 + ln) * 8;
        kh[buf][0] = *(const short8*)(KH + ko);
        kh[buf][1] = *(const short8*)(KH + ko + 1024);
    };

    float racc[4][4] = {};
    auto comp = [&](int buf) {
#pragma unroll
        for (int mt = 0; mt < 4; mt++) {
            f32x4 c1 = (f32x4){0.f,0.f,0.f,0.f};
            c1 = MFMA(qh[mt][0], kh[buf][0], c1);
            c1 = MFMA(qh[mt][1], kh[buf][1], c1);
#pragma unroll
            for (int i = 0; i < 4; i++)
                racc[mt][i] += PEXP(c1[i]);
        }
    };

    loadK(0, kt0);
    for (int t = 0; t < 32; t += 2) {
        loadK(1, kt0 + t + 1);
        comp(0);
        if (t + 2 < 32) loadK(0, kt0 + t + 2);
        comp(1);
    }
#pragma unroll
    for (int mt = 0; mt < 4; mt++)
#pragma unroll
        for (int i = 0; i < 4; i++)
            for (int d = 1; d < 16; d <<= 1)
                racc[mt][i] += __shfl_xor(racc[mt][i], d, 64);
    if (ln == 0) {
#pragma unroll
        for (int mt = 0; mt < 4; mt++)
#pragma unroll
            for (int i = 0; i < 4; i++)
                atomicAdd(&rowsum[bh * 2048 + qb + mt*16 + quad*4 + i], racc[mt][i]);
    }
}

// colsum[k] += sum over this block's q-quarter of 2^(c_qk)/rowsum[q].
// 3-term split kept (feeds the top-k ranking).
__global__ __launch_bounds__(256) void attn_colsum(
    const short* __restrict__ Qhi, const short* __restrict__ Qlo,
    const short* __restrict__ Khi, const short* __restrict__ Klo,
    const float* __restrict__ rowsum, float* __restrict__ colsum)
{
    __shared__ float sli[512];
    int bh = blockIdx.z, tid = threadIdx.x;
    int q0 = blockIdx.y * 512;
    for (int j = tid; j < 512; j += 256)
        sli[j] = 1.0f / rowsum[bh * 2048 + q0 + j];
    __syncthreads();

    int w = tid >> 6, lane = tid & 63, ln = lane & 15, quad = lane >> 4;
    int kb  = blockIdx.x * 256 + w * 64;
    int qt0 = blockIdx.y * 32;            // 32 q-tiles of 16
    const short* QH = Qhi + (size_t)bh * 131072;
    const short* QL = Qlo + (size_t)bh * 131072;
    const short* KH = Khi + (size_t)bh * 131072;
    const short* KL = Klo + (size_t)bh * 131072;

    short8 kh[4][2], kl[4][2];
#pragma unroll
    for (int nt = 0; nt < 4; nt++)
#pragma unroll
        for (int half = 0; half < 2; half++) {
            size_t o = (size_t)((kb >> 5) + (nt >> 1)) * 2048 + (size_t)half * 1024
                     + (size_t)quad * 256 + ((nt & 1) * 16 + ln) * 8;
            kh[nt][half] = *(const short8*)(KH + o);
            kl[nt][half] = *(const short8*)(KL + o);
        }

    short8 qh[2][2], ql[2][2];   // [buf][half]
    auto loadQ = [&](int buf, int qt) {
        int qtt = qt0 + qt;
        size_t base = (size_t)(qtt >> 1) * 2048 + ((qtt & 1) * 16 + ln) * 8;
        qh[buf][0] = *(const short8*)(QH + base + (size_t)quad * 256);
        qh[buf][1] = *(const short8*)(QH + base + (size_t)(4 + quad) * 256);
        ql[buf][0] = *(const short8*)(QL + base + (size_t)quad * 256);
        ql[buf][1] = *(const short8*)(QL + base + (size_t)(4 + quad) * 256);
    };

    float cacc[4] = {0.f, 0.f, 0.f, 0.f};
    auto comp = [&](int buf, int qt) {
#pragma unroll
        for (int nt = 0; nt < 4; nt++) {
            f32x4 c1 = (f32x4){0.f,0.f,0.f,0.f};
            f32x4 c2 = (f32x4){0.f,0.f,0.f,0.f};
            c1 = MFMA(qh[buf][0], kh[nt][0], c1); c1 = MFMA(qh[buf][1], kh[nt][1], c1);
            c2 = MFMA(qh[buf][0], kl[nt][0], c2); c2 = MFMA(qh[buf][1], kl[nt][1], c2);
            c2 = MFMA(ql[buf][0], kh[nt][0], c2); c2 = MFMA(ql[buf][1], kh[nt][1], c2);
#pragma unroll
            for (int i = 0; i < 4; i++) {
                int r = qt*16 + quad*4 + i;
                cacc[nt] += PEXP(c1[i] + c2[i]) * sli[r];
            }
        }
    };

    loadQ(0, 0);
    for (int qt = 0; qt < 32; qt += 2) {
        loadQ(1, qt + 1);
        comp(0, qt);
        if (qt + 2 < 32) loadQ(0, qt + 2);
        comp(1, qt + 1);
    }
#pragma unroll
    for (int nt = 0; nt < 4; nt++) {
        cacc[nt] += __shfl_xor(cacc[nt], 16, 64);
        cacc[nt] += __shfl_xor(cacc[nt], 32, 64);
        if (lane < 16) atomicAdd(&colsum[bh * 2048 + kb + nt*16 + lane], cacc[nt]);
    }
}

// Per (b,h): threshold = KEEP-th largest colsum via 4-level radix select.
__global__ __launch_bounds__(256) void topk_mask(
    const float* __restrict__ colsum, float* __restrict__ maskf)
{
    __shared__ unsigned keys[2048];
    __shared__ int hist[256];
    __shared__ unsigned sh_pref;
    __shared__ int sh_need;
    int bh = blockIdx.x, tid = threadIdx.x;
    for (int j = tid; j < 2048; j += 256) {
        unsigned u = __float_as_uint(colsum[bh * 2048 + j]);
        keys[j] = (u & 0x80000000u) ? ~u : (u | 0x80000000u);
    }
    if (tid == 0) { sh_pref = 0; sh_need = KEEP; }
    __syncthreads();
#pragma unroll
    for (int shift = 24; shift >= 0; shift -= 8) {
        hist[tid & 255] = 0;
        __syncthreads();
        unsigned pref = sh_pref;
        unsigned hmask = (shift == 24) ? 0u : (0xFFFFFFFFu << (shift + 8));
        for (int j = tid; j < 2048; j += 256) {
            unsigned ky = keys[j];
            if ((ky & hmask) == pref)
                atomicAdd(&hist[(ky >> shift) & 255], 1);
        }
        __syncthreads();
        if (tid == 0) {
            int need = sh_need, acc = 0, d = 255;
            for (; d >= 0; d--) {
                if (acc + hist[d] >= need) break;
                acc += hist[d];
            }
            sh_pref = pref | ((unsigned)d << shift);
            sh_need = need - acc;
        }
        __syncthreads();
    }
    unsigned thr = sh_pref;
    for (int j = tid; j < 2048; j += 256)
        maskf[bh * 2048 + j] = (keys[j] >= thr) ? 1.0f : 0.0f;
}

// PV with swapped-operand QK^T, in-register P, block-level LDS staging of
// frag-major K/V chunks. XCD-chunked remap keeps a bh's blocks on one XCD.
__global__ __launch_bounds__(256) void attn_av(
    const short* __restrict__ Qhi, const short* __restrict__ Kf,
    const short* __restrict__ Vf, const float* __restrict__ rowsum,
    unsigned short* __restrict__ concat)
{
    __shared__ __align__(16) short KA[4096];   // [0,2048): K chunk, [2048,4096): V chunk
    __shared__ __align__(16) short KB[4096];
    int lin = blockIdx.x + (blockIdx.y << 4);          // [0,512)
    int tile = (lin & 7) * 64 + (lin >> 3);
    int bxx = tile & 15, bh = tile >> 4;
    int tid = threadIdx.x;
    int w = tid >> 6, lane = tid & 63;
    int lq = lane & 31, hi = lane >> 5;
    int qb = bxx * 128 + w * 32;
    const short* Qb = Qhi + (size_t)bh * 131072 + (size_t)(qb >> 5) * 2048;
    const short* Kg = Kf  + (size_t)bh * 131072;
    const short* Vg = Vf  + (size_t)bh * 131072;

    short8 qf[4];
#pragma unroll
    for (int d = 0; d < 4; d++)
        qf[d] = *(const short8*)(Qb + (size_t)(d*2 + hi) * 256 + lq * 8);

    f32x16 o0, o1;
#pragma unroll
    for (int i = 0; i < 16; i++) { o0[i] = 0.f; o1[i] = 0.f; }

    auto STAGE = [&](short* B, int kc) {
        __builtin_amdgcn_global_load_lds(AS1(Kg + (size_t)kc*2048 + tid*8),
                                         AS3(B + w*512), 16, 0, 0);
        __builtin_amdgcn_global_load_lds(AS1(Vg + (size_t)kc*2048 + tid*8),
                                         AS3(B + 2048 + w*512), 16, 0, 0);
    };

    auto comp = [&](const short* B) {
        short8 kf_[4], vf_[4];
#pragma unroll
        for (int d = 0; d < 4; d++)
            kf_[d] = *(const short8*)(B + (d*2 + hi)*256 + lq*8);
#pragma unroll
        for (int ks = 0; ks < 2; ks++)
#pragma unroll
            for (int nt = 0; nt < 2; nt++)
                vf_[ks*2+nt] = *(const short8*)(B + 2048 + ((ks*2+nt)*2 + hi)*256 + lq*8);

        f32x16 s;
#pragma unroll
        for (int i = 0; i < 16; i++) s[i] = 0.f;
        s = MFMA32(kf_[0], qf[0], s);
        s = MFMA32(kf_[1], qf[1], s);
        s = MFMA32(kf_[2], qf[2], s);
        s = MFMA32(kf_[3], qf[3], s);

        float p[16];
#pragma unroll
        for (int i = 0; i < 16; i++) p[i] = PEXP(s[i]);

        short8 pa[2];
#pragma unroll
        for (int ks = 0; ks < 2; ks++) {
            unsigned w0, w1, w2, w3;
            int o8 = ks * 8;
            asm("v_cvt_pk_bf16_f32 %0, %1, %2" : "=v"(w0) : "v"(p[o8+0]), "v"(p[o8+1]));
            asm("v_cvt_pk_bf16_f32 %0, %1, %2" : "=v"(w1) : "v"(p[o8+2]), "v"(p[o8+3]));
            asm("v_cvt_pk_bf16_f32 %0, %1, %2" : "=v"(w2) : "v"(p[o8+4]), "v"(p[o8+5]));
            asm("v_cvt_pk_bf16_f32 %0, %1, %2" : "=v"(w3) : "v"(p[o8+6]), "v"(p[o8+7]));
            asm("v_permlane32_swap_b32 %0, %1" : "+v"(w0), "+v"(w2));
            asm("v_permlane32_swap_b32 %0, %1" : "+v"(w1), "+v"(w3));
            u32x4 pw = { w0, w1, w2, w3 };
            pa[ks] = __builtin_bit_cast(short8, pw);
        }

        o0 = MFMA32(pa[0], vf_[0], o0);
        o1 = MFMA32(pa[0], vf_[1], o1);
        o0 = MFMA32(pa[1], vf_[2], o0);
        o1 = MFMA32(pa[1], vf_[3], o1);
    };

    STAGE(KA, 0);
    __syncthreads();
    for (int kc = 0; kc < 64; kc += 2) {
        STAGE(KB, kc + 1);          // next chunk's loads fly under compute
        comp(KA);
        __syncthreads();            // publishes KB, guards KA reuse
        if (kc + 2 < 64) STAGE(KA, kc + 2);
        comp(KB);
        __syncthreads();
    }

    int b_ = bh >> 4, h = bh & 15;
#pragma unroll
    for (int r = 0; r < 16; r++) {
        int crow = (r & 3) + 8*(r >> 2) + 4*hi;
        float inv = 1.0f / rowsum[bh * 2048 + qb + crow];
        size_t base = ((size_t)(b_*2048 + qb + crow)) * 1024 + h*64;
        concat[base + lq]      = f2bf(o0[r] * inv);
        concat[base + 32 + lq] = f2bf(o1[r] * inv);
    }
}

extern "C" void kernel_launch(void* const* d_in, const int* in_sizes, int n_in,
                              void* d_out, int out_size, void* d_ws, size_t ws_size,
                              hipStream_t stream)
{
    const float* q  = (const float*)d_in[0];
    const float* k  = (const float*)d_in[1];
    const float* v  = (const float*)d_in[2];
    const float* Wq = (const float*)d_in[3];
    const float* bq = (const float*)d_in[4];
    const float* Wk = (const float*)d_in[5];
    const float* bk = (const float*)d_in[6];
    const float* Wv = (const float*)d_in[7];
    const float* bv = (const float*)d_in[8];
    const float* Wo = (const float*)d_in[9];
    const float* bo = (const float*)d_in[10];

    char* ws = (char*)d_ws;
    size_t off = 0;
    auto alloc = [&](size_t bytes) -> void* {
        void* p = ws + off;
        off += (bytes + 255) & ~(size_t)255;
        return p;
    };
    const size_t ASZ = (size_t)4096 * 1024 * 2;   // 8.4 MB bf16 activation
    const size_t WSZ = (size_t)1024 * 1024 * 2;   // 2 MB bf16 weight
    unsigned short* qh_ = (unsigned short*)alloc(ASZ);
    unsigned short* ql_ = (unsigned short*)alloc(ASZ);
    unsigned short* kh_ = (unsigned short*)alloc(ASZ);
    unsigned short* kl_ = (unsigned short*)alloc(ASZ);
    unsigned short* vh_ = (unsigned short*)alloc(ASZ);
    unsigned short* wqh = (unsigned short*)alloc(WSZ);
    unsigned short* wql = (unsigned short*)alloc(WSZ);
    unsigned short* wkh = (unsigned short*)alloc(WSZ);
    unsigned short* wkl = (unsigned short*)alloc(WSZ);
    unsigned short* wvh = (unsigned short*)alloc(WSZ);
    unsigned short* woh = (unsigned short*)alloc(WSZ);
    unsigned short* wol = (unsigned short*)alloc(WSZ);
    short* Qhi = (short*)alloc(ASZ);   // frag-major
    short* Qlo = (short*)alloc(ASZ);   // frag-major
    short* Khi = (short*)alloc(ASZ);   // frag-major
    short* Klo = (short*)alloc(ASZ);   // frag-major
    short* Vt  = (short*)alloc(ASZ);   // frag-major
    float* rowsum = (float*)alloc((size_t)32 * 2048 * 4);
    float* colsum = (float*)alloc((size_t)32 * 2048 * 4);
    float* maskf  = (float*)alloc((size_t)32 * 2048 * 4);
    unsigned short* concat = (unsigned short*)alloc(ASZ);
    // total ~110 MB (known-safe)

    dim3 blk(256);

    cvt_all<<<dim3(16384), blk, 0, stream>>>(
        q, k, v, Wq, Wk, Wv, Wo,
        qh_, ql_, kh_, kl_, vh_, wqh, wql, wkh, wkl, wvh, woh, wol);
    zero_f32<<<dim3(512), blk, 0, stream>>>(rowsum, 2 * 32 * 2048);  // rowsum+colsum

    gemm_qkv<<<dim3(8, 32, 2), blk, 0, stream>>>(
        (const short*)qh_, (const short*)ql_, (const short*)kh_, (const short*)kl_,
        (const short*)wqh, (const short*)wql, (const short*)wkh, (const short*)wkl,
        bq, bk,
        (unsigned short*)Qhi, (unsigned short*)Qlo,
        (unsigned short*)Khi, (unsigned short*)Klo);

    attn_rowsum<<<dim3(8, 4, 32), blk, 0, stream>>>(Qhi, Khi, rowsum);
    attn_colsum<<<dim3(8, 4, 32), blk, 0, stream>>>(Qhi, Qlo, Khi, Klo, rowsum, colsum);
    topk_mask  <<<dim3(32),   blk, 0, stream>>>(colsum, maskf);

    gemm_v<<<dim3(16, 32), blk, 0, stream>>>(
        (const short*)vh_, (const short*)wvh, bv, maskf, (unsigned short*)Vt);

    attn_av    <<<dim3(16, 32), blk, 0, stream>>>(Qhi, Khi, Vt, rowsum, concat);

    gemm_out<<<dim3(16, 32), blk, 0, stream>>>((const short*)concat,
        (const short*)woh, (const short*)wol, bo, (float*)d_out);
}

// Round 10
// 387.934 us; speedup vs baseline: 1.8417x; 1.0156x over previous
//
#include <hip/hip_runtime.h>

// ---------------------------------------------------------------------------
// Pruned multi-head attention. fp32 I/O, split-bf16 (hi+lo) MFMA compute.
// B=2, S=2048, D_MODEL=1024, H=16, d_k=64, keep=int(2048*0.9)=1843
//
// Round 18: REVERT of R17's hi-only colsum (failed: mask flips from
// ~3e-5 colsum perturbation carry ~1e-3 output error — top-k is a
// discrete decision; its input needs the full 3-term score precision).
// Restored: 3-term colsum + gemm_qkv hi+lo outputs (R16-passing state).
// Kept from R17: rowsum/colsum zeroing fused into cvt_all.
// Precision-cut rule learned: linear paths (V, rowsum) tolerate hi-only;
// anything feeding the top-k ranking does not.
// ---------------------------------------------------------------------------

typedef __attribute__((ext_vector_type(8))) short short8;   // 8 bf16 (4 VGPRs)
typedef __attribute__((ext_vector_type(4))) short short4v;
typedef __attribute__((ext_vector_type(4))) float f32x4;
typedef __attribute__((ext_vector_type(16))) float f32x16;
typedef __attribute__((ext_vector_type(4))) unsigned int u32x4;

#define KEEP 1843

#if __has_builtin(__builtin_amdgcn_exp2f)
  #define PEXP(x) __builtin_amdgcn_exp2f(x)
  #define QSC 0.18033688011112042f   // log2(e)/8 folded into Q projection
#else
  #define PEXP(x) __expf(x)
  #define QSC 0.125f
#endif

#define AS1(p) ((const __attribute__((address_space(1))) void*)(p))
#define AS3(p) ((__attribute__((address_space(3))) void*)(p))

static __device__ __forceinline__ float bf2f(unsigned short s) {
    union { unsigned u; float f; } v; v.u = ((unsigned)s) << 16; return v.f;
}
static __device__ __forceinline__ unsigned short f2bf(float f) {
    union { float f; unsigned u; } v; v.f = f;
    unsigned u = v.u;
    unsigned r = (u + 0x7FFFu + ((u >> 16) & 1u)) >> 16;   // RNE
    return (unsigned short)r;
}

#define MFMA(A, B, C)   __builtin_amdgcn_mfma_f32_16x16x32_bf16(A, B, C, 0, 0, 0)
#define MFMA32(A, B, C) __builtin_amdgcn_mfma_f32_32x32x16_bf16(A, B, C, 0, 0, 0)

// Fragment-major layout for Q and K (per bh, 131072 shorts):
//   (s,d) -> (s>>5)*2048 + (((d>>4)*2 + ((d>>3)&1))*32 + (s&31))*8 + (d&7)
// Fragment-major V layout (per bh):
//   (s,d) -> (s>>5)*2048 + ((((((s>>4)&1)*2 + (d>>5))*2 + ((s>>3)&1))*32) + (d&31))*8 + (s&7)

// All fp32->bf16(hi/lo) conversions + rowsum/colsum zeroing in one launch.
__global__ __launch_bounds__(256) void cvt_all(
    const float* __restrict__ q,  const float* __restrict__ k,
    const float* __restrict__ v,  const float* __restrict__ Wq,
    const float* __restrict__ Wk, const float* __restrict__ Wv,
    const float* __restrict__ Wo,
    unsigned short* __restrict__ qh, unsigned short* __restrict__ ql,
    unsigned short* __restrict__ kh, unsigned short* __restrict__ kl,
    unsigned short* __restrict__ vh,
    unsigned short* __restrict__ wqh, unsigned short* __restrict__ wql,
    unsigned short* __restrict__ wkh, unsigned short* __restrict__ wkl,
    unsigned short* __restrict__ wvh,
    unsigned short* __restrict__ woh, unsigned short* __restrict__ wol,
    float* __restrict__ zbuf)
{
    int g = blockIdx.x * 256 + threadIdx.x;      // [0, 4194304+32768)
    if (g >= 4194304) {                          // zero rowsum+colsum
        int idx = g - 4194304;                   // 32768 f32x4 groups
        ((f32x4*)zbuf)[idx] = (f32x4){0.f, 0.f, 0.f, 0.f};
        return;
    }
    const float* in; unsigned short* oh; unsigned short* ol; int idx;
    if (g < 3145728) {                           // activations: 3 x 2^20 groups
        int seg = g >> 20; idx = g & 1048575;
        if (seg == 0)      { in = q; oh = qh;  ol = ql;  }
        else if (seg == 1) { in = k; oh = kh;  ol = kl;  }
        else               { in = v; oh = vh;  ol = 0;   }
    } else {                                     // weights: 4 x 2^18 groups
        int gw = g - 3145728; int seg = gw >> 18; idx = gw & 262143;
        if (seg == 0)      { in = Wq; oh = wqh; ol = wql; }
        else if (seg == 1) { in = Wk; oh = wkh; ol = wkl; }
        else if (seg == 2) { in = Wv; oh = wvh; ol = 0;   }
        else               { in = Wo; oh = woh; ol = wol; }
    }
    f32x4 x = ((const f32x4*)in)[idx];
    short4v h, l;
#pragma unroll
    for (int j = 0; j < 4; j++) {
        unsigned short hv = f2bf(x[j]);
        h[j] = (short)hv;
        l[j] = (short)f2bf(x[j] - bf2f(hv));
    }
    ((short4v*)oh)[idx] = h;
    if (ol) ((short4v*)ol)[idx] = l;
}

// Fused Q/K projections (split hi+lo, 3-term), LDS-staged + swizzled.
// 128x128 tile, BK=32. z=0: Q (scaled QSC); z=1: K. Both frag-major hi+lo.
__global__ __launch_bounds__(256) void gemm_qkv(
    const short* __restrict__ A0, const short* __restrict__ Al0,
    const short* __restrict__ A1, const short* __restrict__ Al1,
    const short* __restrict__ W0, const short* __restrict__ Wl0,
    const short* __restrict__ W1, const short* __restrict__ Wl1,
    const float* __restrict__ b0, const float* __restrict__ b1,
    unsigned short* __restrict__ Qhi, unsigned short* __restrict__ Qlo,
    unsigned short* __restrict__ Khi, unsigned short* __restrict__ Klo)
{
    // XCD-chunked remap over 512 blocks: each XCD owns 64 consecutive tiles.
    int lin = blockIdx.x + (blockIdx.y << 3) + (blockIdx.z << 8);   // [0,512)
    int tile = (lin & 7) * 64 + (lin >> 3);
    int bx = tile & 7, by = (tile >> 3) & 31, bz = tile >> 8;

    const short *Ahg, *Alg, *Whg, *Wlg; const float* bias;
    unsigned short *oh, *ol; float scale;
    if (bz == 0) { Ahg=A0; Alg=Al0; Whg=W0; Wlg=Wl0; bias=b0; oh=Qhi; ol=Qlo; scale=QSC;  }
    else         { Ahg=A1; Alg=Al1; Whg=W1; Wlg=Wl1; bias=b1; oh=Khi; ol=Klo; scale=1.0f; }

    __shared__ __align__(16) short Ah_l[128*32];
    __shared__ __align__(16) short Al_l[128*32];
    __shared__ __align__(16) short Wh_l[128*32];
    __shared__ __align__(16) short Wl_l[128*32];

    int tid  = threadIdx.x;
    int w    = tid >> 6;
    int lane = tid & 63;
    int ln   = lane & 15;
    int quad = lane >> 4;
    int rowBase = by * 128;
    int colBase = bx * 128;
    int mBase = (w & 1) * 64;        // wave's quadrant inside 128x128
    int nBase = (w >> 1) * 64;

    int srow = (lane >> 2);
    int scol = (((lane & 3) ^ ((lane >> 3) & 3))) * 8;
    int cs = ((quad ^ ((ln >> 1) & 3))) * 8;

    const short* Ag_h = Ahg + (size_t)rowBase * 1024;
    const short* Ag_l = Alg + (size_t)rowBase * 1024;
    const short* Wg_h = Whg + (size_t)colBase * 1024;
    const short* Wg_l = Wlg + (size_t)colBase * 1024;

    f32x4 acc[4][4];
#pragma unroll
    for (int i = 0; i < 4; i++)
#pragma unroll
        for (int j = 0; j < 4; j++) acc[i][j] = (f32x4){0.f, 0.f, 0.f, 0.f};

    for (int kk = 0; kk < 1024; kk += 32) {
#pragma unroll
        for (int j = 0; j < 2; j++) {
            int r = w*32 + j*16;
            size_t go = (size_t)(r + srow) * 1024 + kk + scol;
            __builtin_amdgcn_global_load_lds(AS1(Ag_h + go), AS3(Ah_l + r*32), 16, 0, 0);
            __builtin_amdgcn_global_load_lds(AS1(Ag_l + go), AS3(Al_l + r*32), 16, 0, 0);
            __builtin_amdgcn_global_load_lds(AS1(Wg_h + go), AS3(Wh_l + r*32), 16, 0, 0);
            __builtin_amdgcn_global_load_lds(AS1(Wg_l + go), AS3(Wl_l + r*32), 16, 0, 0);
        }
        __syncthreads();

        short8 ah[4], al[4], bh[4], bl[4];
#pragma unroll
        for (int mt = 0; mt < 4; mt++) {
            int r = mBase + mt*16 + ln;
            ah[mt] = *(const short8*)(Ah_l + r*32 + cs);
            al[mt] = *(const short8*)(Al_l + r*32 + cs);
        }
#pragma unroll
        for (int nt = 0; nt < 4; nt++) {
            int c = nBase + nt*16 + ln;
            bh[nt] = *(const short8*)(Wh_l + c*32 + cs);
            bl[nt] = *(const short8*)(Wl_l + c*32 + cs);
        }
#pragma unroll
        for (int mt = 0; mt < 4; mt++)
#pragma unroll
            for (int nt = 0; nt < 4; nt++) {
                acc[mt][nt] = MFMA(ah[mt], bh[nt], acc[mt][nt]);
                acc[mt][nt] = MFMA(ah[mt], bl[nt], acc[mt][nt]);
                acc[mt][nt] = MFMA(al[mt], bh[nt], acc[mt][nt]);
            }
        __syncthreads();
    }

#pragma unroll
    for (int mt = 0; mt < 4; mt++) {
#pragma unroll
        for (int nt = 0; nt < 4; nt++) {
            int col = colBase + nBase + nt*16 + ln;
            float bv = bias[col];
#pragma unroll
            for (int i = 0; i < 4; i++) {
                int row = rowBase + mBase + mt*16 + quad*4 + i;   // D: row=quad*4+reg
                float val = (acc[mt][nt][i] + bv) * scale;
                int b_  = row >> 11, s = row & 2047;
                int h   = col >> 6,  d = col & 63;
                int bh_ = b_ * 16 + h;
                size_t idx = (size_t)bh_ * 131072 + (size_t)(s >> 5) * 2048
                    + ((size_t)(((d >> 4) * 2 + ((d >> 3) & 1)) * 32 + (s & 31))) * 8 + (d & 7);
                unsigned short hv = f2bf(val);
                oh[idx] = hv;
                ol[idx] = f2bf(val - bf2f(hv));
            }
        }
    }
}

// V projection, 1-term (hi x hi), 128x64 tile (512 blocks = 2/CU), with the
// prune mask fused into the epilogue (runs after topk_mask). Frag-major V.
__global__ __launch_bounds__(256) void gemm_v(
    const short* __restrict__ Ag, const short* __restrict__ Whg,
    const float* __restrict__ bias, const float* __restrict__ maskf,
    unsigned short* __restrict__ Vt)
{
    int lin = blockIdx.x + (blockIdx.y << 4);                  // [0,512)
    int tile = (lin & 7) * 64 + (lin >> 3);
    int bx = tile & 15, by = tile >> 4;

    __shared__ __align__(16) short A_l[128*32];
    __shared__ __align__(16) short Wh_l[64*32];

    int tid  = threadIdx.x;
    int w    = tid >> 6;
    int lane = tid & 63;
    int ln   = lane & 15;
    int quad = lane >> 4;
    int rowBase = by * 128;
    int colBase = bx * 64;
    int mBase = (w & 1) * 64;
    int nBase = (w >> 1) * 32;

    int srow = (lane >> 2);
    int scol = (((lane & 3) ^ ((lane >> 3) & 3))) * 8;
    int cs = ((quad ^ ((ln >> 1) & 3))) * 8;
    const short* Abase = Ag  + (size_t)rowBase * 1024;
    const short* Whb   = Whg + (size_t)colBase * 1024;

    f32x4 acc[4][2];
#pragma unroll
    for (int i = 0; i < 4; i++)
#pragma unroll
        for (int j = 0; j < 2; j++) acc[i][j] = (f32x4){0.f, 0.f, 0.f, 0.f};

    for (int kk = 0; kk < 1024; kk += 32) {
#pragma unroll
        for (int j = 0; j < 2; j++) {
            int r = w*32 + j*16;
            size_t go = (size_t)(r + srow) * 1024 + kk + scol;
            __builtin_amdgcn_global_load_lds(AS1(Abase + go), AS3(A_l + r*32), 16, 0, 0);
        }
        {
            int c = w * 16;   // wave stages 16 W-rows (64-row tile / 4 waves)
            size_t go = (size_t)(c + srow) * 1024 + kk + scol;
            __builtin_amdgcn_global_load_lds(AS1(Whb + go), AS3(Wh_l + c*32), 16, 0, 0);
        }
        __syncthreads();

        short8 a[4], bh2[2];
#pragma unroll
        for (int mt = 0; mt < 4; mt++)
            a[mt] = *(const short8*)(A_l + (mBase + mt*16 + ln)*32 + cs);
#pragma unroll
        for (int nt = 0; nt < 2; nt++)
            bh2[nt] = *(const short8*)(Wh_l + (nBase + nt*16 + ln)*32 + cs);
#pragma unroll
        for (int mt = 0; mt < 4; mt++)
#pragma unroll
            for (int nt = 0; nt < 2; nt++)
                acc[mt][nt] = MFMA(a[mt], bh2[nt], acc[mt][nt]);
        __syncthreads();
    }

#pragma unroll
    for (int mt = 0; mt < 4; mt++) {
#pragma unroll
        for (int nt = 0; nt < 2; nt++) {
            int col = colBase + nBase + nt*16 + ln;
            float bv = bias[col];
#pragma unroll
            for (int i = 0; i < 4; i++) {
                int row = rowBase + mBase + mt*16 + quad*4 + i;
                float val = acc[mt][nt][i] + bv;
                int b_  = row >> 11, s = row & 2047;
                int h   = col >> 6,  d = col & 63;
                int bh_ = b_ * 16 + h;
                val *= maskf[bh_ * 2048 + s];   // fused prune mask (0/1)
                size_t idx = (size_t)bh_ * 131072 + (size_t)(s >> 5) * 2048
                    + ((size_t)((((((s >> 4) & 1) * 2 + (d >> 5)) * 2 + ((s >> 3) & 1)) * 32)
                                + (d & 31))) * 8 + (s & 7);
                Vt[idx] = f2bf(val);
            }
        }
    }
}

// out = concat(bf16) @ Wo^T + bo (split Wo, fp32 out), 128x64 tile
// (512 blocks = 2/CU), LDS-staged + swizzled.
__global__ __launch_bounds__(256) void gemm_out(
    const short* __restrict__ Ag, const short* __restrict__ Whg,
    const short* __restrict__ Wlg, const float* __restrict__ bias,
    float* __restrict__ out)
{
    int lin = blockIdx.x + (blockIdx.y << 4);                  // [0,512)
    int tile = (lin & 7) * 64 + (lin >> 3);
    int bx = tile & 15, by = tile >> 4;

    __shared__ __align__(16) short A_l[128*32];
    __shared__ __align__(16) short Wh_l[64*32];
    __shared__ __align__(16) short Wl_l[64*32];

    int tid  = threadIdx.x;
    int w    = tid >> 6;
    int lane = tid & 63;
    int ln   = lane & 15;
    int quad = lane >> 4;
    int rowBase = by * 128;
    int colBase = bx * 64;
    int mBase = (w & 1) * 64;
    int nBase = (w >> 1) * 32;

    int srow = (lane >> 2);
    int scol = (((lane & 3) ^ ((lane >> 3) & 3))) * 8;
    int cs = ((quad ^ ((ln >> 1) & 3))) * 8;
    const short* Abase = Ag  + (size_t)rowBase * 1024;
    const short* Whb   = Whg + (size_t)colBase * 1024;
    const short* Wlb   = Wlg + (size_t)colBase * 1024;

    f32x4 acc[4][2];
#pragma unroll
    for (int i = 0; i < 4; i++)
#pragma unroll
        for (int j = 0; j < 2; j++) acc[i][j] = (f32x4){0.f, 0.f, 0.f, 0.f};

    for (int kk = 0; kk < 1024; kk += 32) {
#pragma unroll
        for (int j = 0; j < 2; j++) {
            int r = w*32 + j*16;
            size_t go = (size_t)(r + srow) * 1024 + kk + scol;
            __builtin_amdgcn_global_load_lds(AS1(Abase + go), AS3(A_l + r*32), 16, 0, 0);
        }
        {
            int c = w * 16;
            size_t go = (size_t)(c + srow) * 1024 + kk + scol;
            __builtin_amdgcn_global_load_lds(AS1(Whb + go), AS3(Wh_l + c*32), 16, 0, 0);
            __builtin_amdgcn_global_load_lds(AS1(Wlb + go), AS3(Wl_l + c*32), 16, 0, 0);
        }
        __syncthreads();

        short8 a[4], bh2[2], bl2[2];
#pragma unroll
        for (int mt = 0; mt < 4; mt++)
            a[mt] = *(const short8*)(A_l + (mBase + mt*16 + ln)*32 + cs);
#pragma unroll
        for (int nt = 0; nt < 2; nt++) {
            int c = nBase + nt*16 + ln;
            bh2[nt] = *(const short8*)(Wh_l + c*32 + cs);
            bl2[nt] = *(const short8*)(Wl_l + c*32 + cs);
        }
#pragma unroll
        for (int mt = 0; mt < 4; mt++)
#pragma unroll
            for (int nt = 0; nt < 2; nt++) {
                acc[mt][nt] = MFMA(a[mt], bh2[nt], acc[mt][nt]);
                acc[mt][nt] = MFMA(a[mt], bl2[nt], acc[mt][nt]);
            }
        __syncthreads();
    }

#pragma unroll
    for (int mt = 0; mt < 4; mt++) {
#pragma unroll
        for (int nt = 0; nt < 2; nt++) {
            int col = colBase + nBase + nt*16 + ln;
            float bv = bias[col];
#pragma unroll
            for (int i = 0; i < 4; i++) {
                int row = rowBase + mBase + mt*16 + quad*4 + i;
                out[(size_t)row * 1024 + col] = acc[mt][nt][i] + bv;
            }
        }
    }
}

// rowsum[q] += sum over this block's k-quarter of 2^(c_qk), HI-ONLY scores.
__global__ __launch_bounds__(256) void attn_rowsum(
    const short* __restrict__ Qhi, const short* __restrict__ Khi,
    float* __restrict__ rowsum)
{
    int bh = blockIdx.z, tid = threadIdx.x;
    int w = tid >> 6, lane = tid & 63, ln = lane & 15, quad = lane >> 4;
    int qb  = blockIdx.x * 256 + w * 64;
    int kt0 = blockIdx.y * 32;            // 32 k-tiles of 16 = 512 keys
    const short* QH = Qhi + (size_t)bh * 131072;
    const short* KH = Khi + (size_t)bh * 131072;

    short8 qh[4][2];
#pragma unroll
    for (int mt = 0; mt < 4; mt++)
#pragma unroll
        for (int half = 0; half < 2; half++) {
            size_t o = (size_t)((qb >> 5) + (mt >> 1)) * 2048
                     + (size_t)(half * 4 + quad) * 256 + ((mt & 1) * 16 + ln) * 8;
            qh[mt][half] = *(const short8*)(QH + o);
        }

    short8 kh[2][2];   // [buf][dchunk]
    auto loadK = [&](int buf, int kt) {
        size_t ko = (size_t)(kt >> 1) * 2048 + (size_t)quad * 256 + ((kt & 1) * 16 + ln) * 8;
        kh[buf][0] = *(const short8*)(KH + ko);
        kh[buf][1] = *(const short8*)(KH + ko + 1024);
    };

    float racc[4][4] = {};
    auto comp = [&](int buf) {
#pragma unroll
        for (int mt = 0; mt < 4; mt++) {
            f32x4 c1 = (f32x4){0.f,0.f,0.f,0.f};
            c1 = MFMA(qh[mt][0], kh[buf][0], c1);
            c1 = MFMA(qh[mt][1], kh[buf][1], c1);
#pragma unroll
            for (int i = 0; i < 4; i++)
                racc[mt][i] += PEXP(c1[i]);
        }
    };

    loadK(0, kt0);
    for (int t = 0; t < 32; t += 2) {
        loadK(1, kt0 + t + 1);
        comp(0);
        if (t + 2 < 32) loadK(0, kt0 + t + 2);
        comp(1);
    }
#pragma unroll
    for (int mt = 0; mt < 4; mt++)
#pragma unroll
        for (int i = 0; i < 4; i++)
            for (int d = 1; d < 16; d <<= 1)
                racc[mt][i] += __shfl_xor(racc[mt][i], d, 64);
    if (ln == 0) {
#pragma unroll
        for (int mt = 0; mt < 4; mt++)
#pragma unroll
            for (int i = 0; i < 4; i++)
                atomicAdd(&rowsum[bh * 2048 + qb + mt*16 + quad*4 + i], racc[mt][i]);
    }
}

// colsum[k] += sum over this block's q-quarter of 2^(c_qk)/rowsum[q].
// 3-term split (hi*hi + hi*lo + lo*hi) — feeds the top-k ranking, which
// needs per-score ~2^-17 precision (R17 proved hi-only flips the mask).
__global__ __launch_bounds__(256) void attn_colsum(
    const short* __restrict__ Qhi, const short* __restrict__ Qlo,
    const short* __restrict__ Khi, const short* __restrict__ Klo,
    const float* __restrict__ rowsum, float* __restrict__ colsum)
{
    __shared__ float sli[512];
    int bh = blockIdx.z, tid = threadIdx.x;
    int q0 = blockIdx.y * 512;
    for (int j = tid; j < 512; j += 256)
        sli[j] = 1.0f / rowsum[bh * 2048 + q0 + j];
    __syncthreads();

    int w = tid >> 6, lane = tid & 63, ln = lane & 15, quad = lane >> 4;
    int kb  = blockIdx.x * 256 + w * 64;
    int qt0 = blockIdx.y * 32;            // 32 q-tiles of 16
    const short* QH = Qhi + (size_t)bh * 131072;
    const short* QL = Qlo + (size_t)bh * 131072;
    const short* KH = Khi + (size_t)bh * 131072;
    const short* KL = Klo + (size_t)bh * 131072;

    short8 kh[4][2], kl[4][2];
#pragma unroll
    for (int nt = 0; nt < 4; nt++)
#pragma unroll
        for (int half = 0; half < 2; half++) {
            size_t o = (size_t)((kb >> 5) + (nt >> 1)) * 2048 + (size_t)half * 1024
                     + (size_t)quad * 256 + ((nt & 1) * 16 + ln) * 8;
            kh[nt][half] = *(const short8*)(KH + o);
            kl[nt][half] = *(const short8*)(KL + o);
        }

    short8 qh[2][2], ql[2][2];   // [buf][half]
    auto loadQ = [&](int buf, int qt) {
        int qtt = qt0 + qt;
        size_t base = (size_t)(qtt >> 1) * 2048 + ((qtt & 1) * 16 + ln) * 8;
        qh[buf][0] = *(const short8*)(QH + base + (size_t)quad * 256);
        qh[buf][1] = *(const short8*)(QH + base + (size_t)(4 + quad) * 256);
        ql[buf][0] = *(const short8*)(QL + base + (size_t)quad * 256);
        ql[buf][1] = *(const short8*)(QL + base + (size_t)(4 + quad) * 256);
    };

    float cacc[4] = {0.f, 0.f, 0.f, 0.f};
    auto comp = [&](int buf, int qt) {
#pragma unroll
        for (int nt = 0; nt < 4; nt++) {
            f32x4 c1 = (f32x4){0.f,0.f,0.f,0.f};
            f32x4 c2 = (f32x4){0.f,0.f,0.f,0.f};
            c1 = MFMA(qh[buf][0], kh[nt][0], c1); c1 = MFMA(qh[buf][1], kh[nt][1], c1);
            c2 = MFMA(qh[buf][0], kl[nt][0], c2); c2 = MFMA(qh[buf][1], kl[nt][1], c2);
            c2 = MFMA(ql[buf][0], kh[nt][0], c2); c2 = MFMA(ql[buf][1], kh[nt][1], c2);
#pragma unroll
            for (int i = 0; i < 4; i++) {
                int r = qt*16 + quad*4 + i;
                cacc[nt] += PEXP(c1[i] + c2[i]) * sli[r];
            }
        }
    };

    loadQ(0, 0);
    for (int qt = 0; qt < 32; qt += 2) {
        loadQ(1, qt + 1);
        comp(0, qt);
        if (qt + 2 < 32) loadQ(0, qt + 2);
        comp(1, qt + 1);
    }
#pragma unroll
    for (int nt = 0; nt < 4; nt++) {
        cacc[nt] += __shfl_xor(cacc[nt], 16, 64);
        cacc[nt] += __shfl_xor(cacc[nt], 32, 64);
        if (lane < 16) atomicAdd(&colsum[bh * 2048 + kb + nt*16 + lane], cacc[nt]);
    }
}

// Per (b,h): threshold = KEEP-th largest colsum via 4-level radix select.
__global__ __launch_bounds__(256) void topk_mask(
    const float* __restrict__ colsum, float* __restrict__ maskf)
{
    __shared__ unsigned keys[2048];
    __shared__ int hist[256];
    __shared__ unsigned sh_pref;
    __shared__ int sh_need;
    int bh = blockIdx.x, tid = threadIdx.x;
    for (int j = tid; j < 2048; j += 256) {
        unsigned u = __float_as_uint(colsum[bh * 2048 + j]);
        keys[j] = (u & 0x80000000u) ? ~u : (u | 0x80000000u);
    }
    if (tid == 0) { sh_pref = 0; sh_need = KEEP; }
    __syncthreads();
#pragma unroll
    for (int shift = 24; shift >= 0; shift -= 8) {
        hist[tid & 255] = 0;
        __syncthreads();
        unsigned pref = sh_pref;
        unsigned hmask = (shift == 24) ? 0u : (0xFFFFFFFFu << (shift + 8));
        for (int j = tid; j < 2048; j += 256) {
            unsigned ky = keys[j];
            if ((ky & hmask) == pref)
                atomicAdd(&hist[(ky >> shift) & 255], 1);
        }
        __syncthreads();
        if (tid == 0) {
            int need = sh_need, acc = 0, d = 255;
            for (; d >= 0; d--) {
                if (acc + hist[d] >= need) break;
                acc += hist[d];
            }
            sh_pref = pref | ((unsigned)d << shift);
            sh_need = need - acc;
        }
        __syncthreads();
    }
    unsigned thr = sh_pref;
    for (int j = tid; j < 2048; j += 256)
        maskf[bh * 2048 + j] = (keys[j] >= thr) ? 1.0f : 0.0f;
}

// PV with swapped-operand QK^T, in-register P, block-level LDS staging of
// frag-major K/V chunks. XCD-chunked remap keeps a bh's blocks on one XCD.
__global__ __launch_bounds__(256) void attn_av(
    const short* __restrict__ Qhi, const short* __restrict__ Kf,
    const short* __restrict__ Vf, const float* __restrict__ rowsum,
    unsigned short* __restrict__ concat)
{
    __shared__ __align__(16) short KA[4096];   // [0,2048): K chunk, [2048,4096): V chunk
    __shared__ __align__(16) short KB[4096];
    int lin = blockIdx.x + (blockIdx.y << 4);          // [0,512)
    int tile = (lin & 7) * 64 + (lin >> 3);
    int bxx = tile & 15, bh = tile >> 4;
    int tid = threadIdx.x;
    int w = tid >> 6, lane = tid & 63;
    int lq = lane & 31, hi = lane >> 5;
    int qb = bxx * 128 + w * 32;
    const short* Qb = Qhi + (size_t)bh * 131072 + (size_t)(qb >> 5) * 2048;
    const short* Kg = Kf  + (size_t)bh * 131072;
    const short* Vg = Vf  + (size_t)bh * 131072;

    short8 qf[4];
#pragma unroll
    for (int d = 0; d < 4; d++)
        qf[d] = *(const short8*)(Qb + (size_t)(d*2 + hi) * 256 + lq * 8);

    f32x16 o0, o1;
#pragma unroll
    for (int i = 0; i < 16; i++) { o0[i] = 0.f; o1[i] = 0.f; }

    auto STAGE = [&](short* B, int kc) {
        __builtin_amdgcn_global_load_lds(AS1(Kg + (size_t)kc*2048 + tid*8),
                                         AS3(B + w*512), 16, 0, 0);
        __builtin_amdgcn_global_load_lds(AS1(Vg + (size_t)kc*2048 + tid*8),
                                         AS3(B + 2048 + w*512), 16, 0, 0);
    };

    auto comp = [&](const short* B) {
        short8 kf_[4], vf_[4];
#pragma unroll
        for (int d = 0; d < 4; d++)
            kf_[d] = *(const short8*)(B + (d*2 + hi)*256 + lq*8);
#pragma unroll
        for (int ks = 0; ks < 2; ks++)
#pragma unroll
            for (int nt = 0; nt < 2; nt++)
                vf_[ks*2+nt] = *(const short8*)(B + 2048 + ((ks*2+nt)*2 + hi)*256 + lq*8);

        f32x16 s;
#pragma unroll
        for (int i = 0; i < 16; i++) s[i] = 0.f;
        s = MFMA32(kf_[0], qf[0], s);
        s = MFMA32(kf_[1], qf[1], s);
        s = MFMA32(kf_[2], qf[2], s);
        s = MFMA32(kf_[3], qf[3], s);

        float p[16];
#pragma unroll
        for (int i = 0; i < 16; i++) p[i] = PEXP(s[i]);

        short8 pa[2];
#pragma unroll
        for (int ks = 0; ks < 2; ks++) {
            unsigned w0, w1, w2, w3;
            int o8 = ks * 8;
            asm("v_cvt_pk_bf16_f32 %0, %1, %2" : "=v"(w0) : "v"(p[o8+0]), "v"(p[o8+1]));
            asm("v_cvt_pk_bf16_f32 %0, %1, %2" : "=v"(w1) : "v"(p[o8+2]), "v"(p[o8+3]));
            asm("v_cvt_pk_bf16_f32 %0, %1, %2" : "=v"(w2) : "v"(p[o8+4]), "v"(p[o8+5]));
            asm("v_cvt_pk_bf16_f32 %0, %1, %2" : "=v"(w3) : "v"(p[o8+6]), "v"(p[o8+7]));
            asm("v_permlane32_swap_b32 %0, %1" : "+v"(w0), "+v"(w2));
            asm("v_permlane32_swap_b32 %0, %1" : "+v"(w1), "+v"(w3));
            u32x4 pw = { w0, w1, w2, w3 };
            pa[ks] = __builtin_bit_cast(short8, pw);
        }

        o0 = MFMA32(pa[0], vf_[0], o0);
        o1 = MFMA32(pa[0], vf_[1], o1);
        o0 = MFMA32(pa[1], vf_[2], o0);
        o1 = MFMA32(pa[1], vf_[3], o1);
    };

    STAGE(KA, 0);
    __syncthreads();
    for (int kc = 0; kc < 64; kc += 2) {
        STAGE(KB, kc + 1);          // next chunk's loads fly under compute
        comp(KA);
        __syncthreads();            // publishes KB, guards KA reuse
        if (kc + 2 < 64) STAGE(KA, kc + 2);
        comp(KB);
        __syncthreads();
    }

    int b_ = bh >> 4, h = bh & 15;
#pragma unroll
    for (int r = 0; r < 16; r++) {
        int crow = (r & 3) + 8*(r >> 2) + 4*hi;
        float inv = 1.0f / rowsum[bh * 2048 + qb + crow];
        size_t base = ((size_t)(b_*2048 + qb + crow)) * 1024 + h*64;
        concat[base + lq]      = f2bf(o0[r] * inv);
        concat[base + 32 + lq] = f2bf(o1[r] * inv);
    }
}

extern "C" void kernel_launch(void* const* d_in, const int* in_sizes, int n_in,
                              void* d_out, int out_size, void* d_ws, size_t ws_size,
                              hipStream_t stream)
{
    const float* q  = (const float*)d_in[0];
    const float* k  = (const float*)d_in[1];
    const float* v  = (const float*)d_in[2];
    const float* Wq = (const float*)d_in[3];
    const float* bq = (const float*)d_in[4];
    const float* Wk = (const float*)d_in[5];
    const float* bk = (const float*)d_in[6];
    const float* Wv = (const float*)d_in[7];
    const float* bv = (const float*)d_in[8];
    const float* Wo = (const float*)d_in[9];
    const float* bo = (const float*)d_in[10];

    char* ws = (char*)d_ws;
    size_t off = 0;
    auto alloc = [&](size_t bytes) -> void* {
        void* p = ws + off;
        off += (bytes + 255) & ~(size_t)255;
        return p;
    };
    const size_t ASZ = (size_t)4096 * 1024 * 2;   // 8.4 MB bf16 activation
    const size_t WSZ = (size_t)1024 * 1024 * 2;   // 2 MB bf16 weight
    unsigned short* qh_ = (unsigned short*)alloc(ASZ);
    unsigned short* ql_ = (unsigned short*)alloc(ASZ);
    unsigned short* kh_ = (unsigned short*)alloc(ASZ);
    unsigned short* kl_ = (unsigned short*)alloc(ASZ);
    unsigned short* vh_ = (unsigned short*)alloc(ASZ);
    unsigned short* wqh = (unsigned short*)alloc(WSZ);
    unsigned short* wql = (unsigned short*)alloc(WSZ);
    unsigned short* wkh = (unsigned short*)alloc(WSZ);
    unsigned short* wkl = (unsigned short*)alloc(WSZ);
    unsigned short* wvh = (unsigned short*)alloc(WSZ);
    unsigned short* woh = (unsigned short*)alloc(WSZ);
    unsigned short* wol = (unsigned short*)alloc(WSZ);
    short* Qhi = (short*)alloc(ASZ);   // frag-major
    short* Qlo = (short*)alloc(ASZ);   // frag-major
    short* Khi = (short*)alloc(ASZ);   // frag-major
    short* Klo = (short*)alloc(ASZ);   // frag-major
    short* Vt  = (short*)alloc(ASZ);   // frag-major
    float* rowsum = (float*)alloc((size_t)32 * 2048 * 4);
    float* colsum = (float*)alloc((size_t)32 * 2048 * 4);   // contiguous after rowsum
    float* maskf  = (float*)alloc((size_t)32 * 2048 * 4);
    unsigned short* concat = (unsigned short*)alloc(ASZ);
    // total ~110 MB (known-safe)

    dim3 blk(256);

    cvt_all<<<dim3(16512), blk, 0, stream>>>(
        q, k, v, Wq, Wk, Wv, Wo,
        qh_, ql_, kh_, kl_, vh_, wqh, wql, wkh, wkl, wvh, woh, wol,
        rowsum /* zbuf: zeros rowsum+colsum (contiguous) */);

    gemm_qkv<<<dim3(8, 32, 2), blk, 0, stream>>>(
        (const short*)qh_, (const short*)ql_, (const short*)kh_, (const short*)kl_,
        (const short*)wqh, (const short*)wql, (const short*)wkh, (const short*)wkl,
        bq, bk,
        (unsigned short*)Qhi, (unsigned short*)Qlo,
        (unsigned short*)Khi, (unsigned short*)Klo);

    attn_rowsum<<<dim3(8, 4, 32), blk, 0, stream>>>(Qhi, Khi, rowsum);
    attn_colsum<<<dim3(8, 4, 32), blk, 0, stream>>>(Qhi, Qlo, Khi, Klo, rowsum, colsum);
    topk_mask  <<<dim3(32),   blk, 0, stream>>>(colsum, maskf);

    gemm_v<<<dim3(16, 32), blk, 0, stream>>>(
        (const short*)vh_, (const short*)wvh, bv, maskf, (unsigned short*)Vt);

    attn_av    <<<dim3(16, 32), blk, 0, stream>>>(Qhi, Khi, Vt, rowsum, concat);

    gemm_out<<<dim3(16, 32), blk, 0, stream>>>((const short*)concat,
        (const short*)woh, (const short*)wol, bo, (float*)d_out);
}

// Round 11
// 350.727 us; speedup vs baseline: 2.0370x; 1.1061x over previous
//
#include <hip/hip_runtime.h>

// ---------------------------------------------------------------------------
// Pruned multi-head attention. fp32 I/O, split-bf16 (hi+lo) MFMA compute.
// B=2, S=2048, D_MODEL=1024, H=16, d_k=64, keep=int(2048*0.9)=1843
//
// Round 19: tail optimization (GEMMs are at their structural ceiling for
// this shape — N=1024 caps grids at 512 blocks/128-col tiles; the 8-phase
// 256^2 template is inapplicable). (1) attn_av processes 64-key chunks
// (2x LDS chunk, 32 vs 64 barriers; same key order -> bit-identical).
// (2) topk_mask uses a parallel suffix-scan over the radix histogram
// (was tid0-serial 256-loop x4). Everything else identical to R18.
// ---------------------------------------------------------------------------

typedef __attribute__((ext_vector_type(8))) short short8;   // 8 bf16 (4 VGPRs)
typedef __attribute__((ext_vector_type(4))) short short4v;
typedef __attribute__((ext_vector_type(4))) float f32x4;
typedef __attribute__((ext_vector_type(16))) float f32x16;
typedef __attribute__((ext_vector_type(4))) unsigned int u32x4;

#define KEEP 1843

#if __has_builtin(__builtin_amdgcn_exp2f)
  #define PEXP(x) __builtin_amdgcn_exp2f(x)
  #define QSC 0.18033688011112042f   // log2(e)/8 folded into Q projection
#else
  #define PEXP(x) __expf(x)
  #define QSC 0.125f
#endif

#define AS1(p) ((const __attribute__((address_space(1))) void*)(p))
#define AS3(p) ((__attribute__((address_space(3))) void*)(p))

static __device__ __forceinline__ float bf2f(unsigned short s) {
    union { unsigned u; float f; } v; v.u = ((unsigned)s) << 16; return v.f;
}
static __device__ __forceinline__ unsigned short f2bf(float f) {
    union { float f; unsigned u; } v; v.f = f;
    unsigned u = v.u;
    unsigned r = (u + 0x7FFFu + ((u >> 16) & 1u)) >> 16;   // RNE
    return (unsigned short)r;
}

#define MFMA(A, B, C)   __builtin_amdgcn_mfma_f32_16x16x32_bf16(A, B, C, 0, 0, 0)
#define MFMA32(A, B, C) __builtin_amdgcn_mfma_f32_32x32x16_bf16(A, B, C, 0, 0, 0)

// Fragment-major layout for Q and K (per bh, 131072 shorts):
//   (s,d) -> (s>>5)*2048 + (((d>>4)*2 + ((d>>3)&1))*32 + (s&31))*8 + (d&7)
// Fragment-major V layout (per bh):
//   (s,d) -> (s>>5)*2048 + ((((((s>>4)&1)*2 + (d>>5))*2 + ((s>>3)&1))*32) + (d&31))*8 + (s&7)

// All fp32->bf16(hi/lo) conversions + rowsum/colsum zeroing in one launch.
__global__ __launch_bounds__(256) void cvt_all(
    const float* __restrict__ q,  const float* __restrict__ k,
    const float* __restrict__ v,  const float* __restrict__ Wq,
    const float* __restrict__ Wk, const float* __restrict__ Wv,
    const float* __restrict__ Wo,
    unsigned short* __restrict__ qh, unsigned short* __restrict__ ql,
    unsigned short* __restrict__ kh, unsigned short* __restrict__ kl,
    unsigned short* __restrict__ vh,
    unsigned short* __restrict__ wqh, unsigned short* __restrict__ wql,
    unsigned short* __restrict__ wkh, unsigned short* __restrict__ wkl,
    unsigned short* __restrict__ wvh,
    unsigned short* __restrict__ woh, unsigned short* __restrict__ wol,
    float* __restrict__ zbuf)
{
    int g = blockIdx.x * 256 + threadIdx.x;      // [0, 4194304+32768)
    if (g >= 4194304) {                          // zero rowsum+colsum
        int idx = g - 4194304;                   // 32768 f32x4 groups
        ((f32x4*)zbuf)[idx] = (f32x4){0.f, 0.f, 0.f, 0.f};
        return;
    }
    const float* in; unsigned short* oh; unsigned short* ol; int idx;
    if (g < 3145728) {                           // activations: 3 x 2^20 groups
        int seg = g >> 20; idx = g & 1048575;
        if (seg == 0)      { in = q; oh = qh;  ol = ql;  }
        else if (seg == 1) { in = k; oh = kh;  ol = kl;  }
        else               { in = v; oh = vh;  ol = 0;   }
    } else {                                     // weights: 4 x 2^18 groups
        int gw = g - 3145728; int seg = gw >> 18; idx = gw & 262143;
        if (seg == 0)      { in = Wq; oh = wqh; ol = wql; }
        else if (seg == 1) { in = Wk; oh = wkh; ol = wkl; }
        else if (seg == 2) { in = Wv; oh = wvh; ol = 0;   }
        else               { in = Wo; oh = woh; ol = wol; }
    }
    f32x4 x = ((const f32x4*)in)[idx];
    short4v h, l;
#pragma unroll
    for (int j = 0; j < 4; j++) {
        unsigned short hv = f2bf(x[j]);
        h[j] = (short)hv;
        l[j] = (short)f2bf(x[j] - bf2f(hv));
    }
    ((short4v*)oh)[idx] = h;
    if (ol) ((short4v*)ol)[idx] = l;
}

// Fused Q/K projections (split hi+lo, 3-term), LDS-staged + swizzled.
// 128x128 tile, BK=32. z=0: Q (scaled QSC); z=1: K. Both frag-major hi+lo.
__global__ __launch_bounds__(256) void gemm_qkv(
    const short* __restrict__ A0, const short* __restrict__ Al0,
    const short* __restrict__ A1, const short* __restrict__ Al1,
    const short* __restrict__ W0, const short* __restrict__ Wl0,
    const short* __restrict__ W1, const short* __restrict__ Wl1,
    const float* __restrict__ b0, const float* __restrict__ b1,
    unsigned short* __restrict__ Qhi, unsigned short* __restrict__ Qlo,
    unsigned short* __restrict__ Khi, unsigned short* __restrict__ Klo)
{
    // XCD-chunked remap over 512 blocks: each XCD owns 64 consecutive tiles.
    int lin = blockIdx.x + (blockIdx.y << 3) + (blockIdx.z << 8);   // [0,512)
    int tile = (lin & 7) * 64 + (lin >> 3);
    int bx = tile & 7, by = (tile >> 3) & 31, bz = tile >> 8;

    const short *Ahg, *Alg, *Whg, *Wlg; const float* bias;
    unsigned short *oh, *ol; float scale;
    if (bz == 0) { Ahg=A0; Alg=Al0; Whg=W0; Wlg=Wl0; bias=b0; oh=Qhi; ol=Qlo; scale=QSC;  }
    else         { Ahg=A1; Alg=Al1; Whg=W1; Wlg=Wl1; bias=b1; oh=Khi; ol=Klo; scale=1.0f; }

    __shared__ __align__(16) short Ah_l[128*32];
    __shared__ __align__(16) short Al_l[128*32];
    __shared__ __align__(16) short Wh_l[128*32];
    __shared__ __align__(16) short Wl_l[128*32];

    int tid  = threadIdx.x;
    int w    = tid >> 6;
    int lane = tid & 63;
    int ln   = lane & 15;
    int quad = lane >> 4;
    int rowBase = by * 128;
    int colBase = bx * 128;
    int mBase = (w & 1) * 64;        // wave's quadrant inside 128x128
    int nBase = (w >> 1) * 64;

    int srow = (lane >> 2);
    int scol = (((lane & 3) ^ ((lane >> 3) & 3))) * 8;
    int cs = ((quad ^ ((ln >> 1) & 3))) * 8;

    const short* Ag_h = Ahg + (size_t)rowBase * 1024;
    const short* Ag_l = Alg + (size_t)rowBase * 1024;
    const short* Wg_h = Whg + (size_t)colBase * 1024;
    const short* Wg_l = Wlg + (size_t)colBase * 1024;

    f32x4 acc[4][4];
#pragma unroll
    for (int i = 0; i < 4; i++)
#pragma unroll
        for (int j = 0; j < 4; j++) acc[i][j] = (f32x4){0.f, 0.f, 0.f, 0.f};

    for (int kk = 0; kk < 1024; kk += 32) {
#pragma unroll
        for (int j = 0; j < 2; j++) {
            int r = w*32 + j*16;
            size_t go = (size_t)(r + srow) * 1024 + kk + scol;
            __builtin_amdgcn_global_load_lds(AS1(Ag_h + go), AS3(Ah_l + r*32), 16, 0, 0);
            __builtin_amdgcn_global_load_lds(AS1(Ag_l + go), AS3(Al_l + r*32), 16, 0, 0);
            __builtin_amdgcn_global_load_lds(AS1(Wg_h + go), AS3(Wh_l + r*32), 16, 0, 0);
            __builtin_amdgcn_global_load_lds(AS1(Wg_l + go), AS3(Wl_l + r*32), 16, 0, 0);
        }
        __syncthreads();

        short8 ah[4], al[4], bh[4], bl[4];
#pragma unroll
        for (int mt = 0; mt < 4; mt++) {
            int r = mBase + mt*16 + ln;
            ah[mt] = *(const short8*)(Ah_l + r*32 + cs);
            al[mt] = *(const short8*)(Al_l + r*32 + cs);
        }
#pragma unroll
        for (int nt = 0; nt < 4; nt++) {
            int c = nBase + nt*16 + ln;
            bh[nt] = *(const short8*)(Wh_l + c*32 + cs);
            bl[nt] = *(const short8*)(Wl_l + c*32 + cs);
        }
#pragma unroll
        for (int mt = 0; mt < 4; mt++)
#pragma unroll
            for (int nt = 0; nt < 4; nt++) {
                acc[mt][nt] = MFMA(ah[mt], bh[nt], acc[mt][nt]);
                acc[mt][nt] = MFMA(ah[mt], bl[nt], acc[mt][nt]);
                acc[mt][nt] = MFMA(al[mt], bh[nt], acc[mt][nt]);
            }
        __syncthreads();
    }

#pragma unroll
    for (int mt = 0; mt < 4; mt++) {
#pragma unroll
        for (int nt = 0; nt < 4; nt++) {
            int col = colBase + nBase + nt*16 + ln;
            float bv = bias[col];
#pragma unroll
            for (int i = 0; i < 4; i++) {
                int row = rowBase + mBase + mt*16 + quad*4 + i;   // D: row=quad*4+reg
                float val = (acc[mt][nt][i] + bv) * scale;
                int b_  = row >> 11, s = row & 2047;
                int h   = col >> 6,  d = col & 63;
                int bh_ = b_ * 16 + h;
                size_t idx = (size_t)bh_ * 131072 + (size_t)(s >> 5) * 2048
                    + ((size_t)(((d >> 4) * 2 + ((d >> 3) & 1)) * 32 + (s & 31))) * 8 + (d & 7);
                unsigned short hv = f2bf(val);
                oh[idx] = hv;
                ol[idx] = f2bf(val - bf2f(hv));
            }
        }
    }
}

// V projection, 1-term (hi x hi), 128x64 tile (512 blocks = 2/CU), with the
// prune mask fused into the epilogue (runs after topk_mask). Frag-major V.
__global__ __launch_bounds__(256) void gemm_v(
    const short* __restrict__ Ag, const short* __restrict__ Whg,
    const float* __restrict__ bias, const float* __restrict__ maskf,
    unsigned short* __restrict__ Vt)
{
    int lin = blockIdx.x + (blockIdx.y << 4);                  // [0,512)
    int tile = (lin & 7) * 64 + (lin >> 3);
    int bx = tile & 15, by = tile >> 4;

    __shared__ __align__(16) short A_l[128*32];
    __shared__ __align__(16) short Wh_l[64*32];

    int tid  = threadIdx.x;
    int w    = tid >> 6;
    int lane = tid & 63;
    int ln   = lane & 15;
    int quad = lane >> 4;
    int rowBase = by * 128;
    int colBase = bx * 64;
    int mBase = (w & 1) * 64;
    int nBase = (w >> 1) * 32;

    int srow = (lane >> 2);
    int scol = (((lane & 3) ^ ((lane >> 3) & 3))) * 8;
    int cs = ((quad ^ ((ln >> 1) & 3))) * 8;
    const short* Abase = Ag  + (size_t)rowBase * 1024;
    const short* Whb   = Whg + (size_t)colBase * 1024;

    f32x4 acc[4][2];
#pragma unroll
    for (int i = 0; i < 4; i++)
#pragma unroll
        for (int j = 0; j < 2; j++) acc[i][j] = (f32x4){0.f, 0.f, 0.f, 0.f};

    for (int kk = 0; kk < 1024; kk += 32) {
#pragma unroll
        for (int j = 0; j < 2; j++) {
            int r = w*32 + j*16;
            size_t go = (size_t)(r + srow) * 1024 + kk + scol;
            __builtin_amdgcn_global_load_lds(AS1(Abase + go), AS3(A_l + r*32), 16, 0, 0);
        }
        {
            int c = w * 16;   // wave stages 16 W-rows (64-row tile / 4 waves)
            size_t go = (size_t)(c + srow) * 1024 + kk + scol;
            __builtin_amdgcn_global_load_lds(AS1(Whb + go), AS3(Wh_l + c*32), 16, 0, 0);
        }
        __syncthreads();

        short8 a[4], bh2[2];
#pragma unroll
        for (int mt = 0; mt < 4; mt++)
            a[mt] = *(const short8*)(A_l + (mBase + mt*16 + ln)*32 + cs);
#pragma unroll
        for (int nt = 0; nt < 2; nt++)
            bh2[nt] = *(const short8*)(Wh_l + (nBase + nt*16 + ln)*32 + cs);
#pragma unroll
        for (int mt = 0; mt < 4; mt++)
#pragma unroll
            for (int nt = 0; nt < 2; nt++)
                acc[mt][nt] = MFMA(a[mt], bh2[nt], acc[mt][nt]);
        __syncthreads();
    }

#pragma unroll
    for (int mt = 0; mt < 4; mt++) {
#pragma unroll
        for (int nt = 0; nt < 2; nt++) {
            int col = colBase + nBase + nt*16 + ln;
            float bv = bias[col];
#pragma unroll
            for (int i = 0; i < 4; i++) {
                int row = rowBase + mBase + mt*16 + quad*4 + i;
                float val = acc[mt][nt][i] + bv;
                int b_  = row >> 11, s = row & 2047;
                int h   = col >> 6,  d = col & 63;
                int bh_ = b_ * 16 + h;
                val *= maskf[bh_ * 2048 + s];   // fused prune mask (0/1)
                size_t idx = (size_t)bh_ * 131072 + (size_t)(s >> 5) * 2048
                    + ((size_t)((((((s >> 4) & 1) * 2 + (d >> 5)) * 2 + ((s >> 3) & 1)) * 32)
                                + (d & 31))) * 8 + (s & 7);
                Vt[idx] = f2bf(val);
            }
        }
    }
}

// out = concat(bf16) @ Wo^T + bo (split Wo, fp32 out), 128x64 tile
// (512 blocks = 2/CU), LDS-staged + swizzled.
__global__ __launch_bounds__(256) void gemm_out(
    const short* __restrict__ Ag, const short* __restrict__ Whg,
    const short* __restrict__ Wlg, const float* __restrict__ bias,
    float* __restrict__ out)
{
    int lin = blockIdx.x + (blockIdx.y << 4);                  // [0,512)
    int tile = (lin & 7) * 64 + (lin >> 3);
    int bx = tile & 15, by = tile >> 4;

    __shared__ __align__(16) short A_l[128*32];
    __shared__ __align__(16) short Wh_l[64*32];
    __shared__ __align__(16) short Wl_l[64*32];

    int tid  = threadIdx.x;
    int w    = tid >> 6;
    int lane = tid & 63;
    int ln   = lane & 15;
    int quad = lane >> 4;
    int rowBase = by * 128;
    int colBase = bx * 64;
    int mBase = (w & 1) * 64;
    int nBase = (w >> 1) * 32;

    int srow = (lane >> 2);
    int scol = (((lane & 3) ^ ((lane >> 3) & 3))) * 8;
    int cs = ((quad ^ ((ln >> 1) & 3))) * 8;
    const short* Abase = Ag  + (size_t)rowBase * 1024;
    const short* Whb   = Whg + (size_t)colBase * 1024;
    const short* Wlb   = Wlg + (size_t)colBase * 1024;

    f32x4 acc[4][2];
#pragma unroll
    for (int i = 0; i < 4; i++)
#pragma unroll
        for (int j = 0; j < 2; j++) acc[i][j] = (f32x4){0.f, 0.f, 0.f, 0.f};

    for (int kk = 0; kk < 1024; kk += 32) {
#pragma unroll
        for (int j = 0; j < 2; j++) {
            int r = w*32 + j*16;
            size_t go = (size_t)(r + srow) * 1024 + kk + scol;
            __builtin_amdgcn_global_load_lds(AS1(Abase + go), AS3(A_l + r*32), 16, 0, 0);
        }
        {
            int c = w * 16;
            size_t go = (size_t)(c + srow) * 1024 + kk + scol;
            __builtin_amdgcn_global_load_lds(AS1(Whb + go), AS3(Wh_l + c*32), 16, 0, 0);
            __builtin_amdgcn_global_load_lds(AS1(Wlb + go), AS3(Wl_l + c*32), 16, 0, 0);
        }
        __syncthreads();

        short8 a[4], bh2[2], bl2[2];
#pragma unroll
        for (int mt = 0; mt < 4; mt++)
            a[mt] = *(const short8*)(A_l + (mBase + mt*16 + ln)*32 + cs);
#pragma unroll
        for (int nt = 0; nt < 2; nt++) {
            int c = nBase + nt*16 + ln;
            bh2[nt] = *(const short8*)(Wh_l + c*32 + cs);
            bl2[nt] = *(const short8*)(Wl_l + c*32 + cs);
        }
#pragma unroll
        for (int mt = 0; mt < 4; mt++)
#pragma unroll
            for (int nt = 0; nt < 2; nt++) {
                acc[mt][nt] = MFMA(a[mt], bh2[nt], acc[mt][nt]);
                acc[mt][nt] = MFMA(a[mt], bl2[nt], acc[mt][nt]);
            }
        __syncthreads();
    }

#pragma unroll
    for (int mt = 0; mt < 4; mt++) {
#pragma unroll
        for (int nt = 0; nt < 2; nt++) {
            int col = colBase + nBase + nt*16 + ln;
            float bv = bias[col];
#pragma unroll
            for (int i = 0; i < 4; i++) {
                int row = rowBase + mBase + mt*16 + quad*4 + i;
                out[(size_t)row * 1024 + col] = acc[mt][nt][i] + bv;
            }
        }
    }
}

// rowsum[q] += sum over this block's k-quarter of 2^(c_qk), HI-ONLY scores.
__global__ __launch_bounds__(256) void attn_rowsum(
    const short* __restrict__ Qhi, const short* __restrict__ Khi,
    float* __restrict__ rowsum)
{
    int bh = blockIdx.z, tid = threadIdx.x;
    int w = tid >> 6, lane = tid & 63, ln = lane & 15, quad = lane >> 4;
    int qb  = blockIdx.x * 256 + w * 64;
    int kt0 = blockIdx.y * 32;            // 32 k-tiles of 16 = 512 keys
    const short* QH = Qhi + (size_t)bh * 131072;
    const short* KH = Khi + (size_t)bh * 131072;

    short8 qh[4][2];
#pragma unroll
    for (int mt = 0; mt < 4; mt++)
#pragma unroll
        for (int half = 0; half < 2; half++) {
            size_t o = (size_t)((qb >> 5) + (mt >> 1)) * 2048
                     + (size_t)(half * 4 + quad) * 256 + ((mt & 1) * 16 + ln) * 8;
            qh[mt][half] = *(const short8*)(QH + o);
        }

    short8 kh[2][2];   // [buf][dchunk]
    auto loadK = [&](int buf, int kt) {
        size_t ko = (size_t)(kt >> 1) * 2048 + (size_t)quad * 256 + ((kt & 1) * 16 + ln) * 8;
        kh[buf][0] = *(const short8*)(KH + ko);
        kh[buf][1] = *(const short8*)(KH + ko + 1024);
    };

    float racc[4][4] = {};
    auto comp = [&](int buf) {
#pragma unroll
        for (int mt = 0; mt < 4; mt++) {
            f32x4 c1 = (f32x4){0.f,0.f,0.f,0.f};
            c1 = MFMA(qh[mt][0], kh[buf][0], c1);
            c1 = MFMA(qh[mt][1], kh[buf][1], c1);
#pragma unroll
            for (int i = 0; i < 4; i++)
                racc[mt][i] += PEXP(c1[i]);
        }
    };

    loadK(0, kt0);
    for (int t = 0; t < 32; t += 2) {
        loadK(1, kt0 + t + 1);
        comp(0);
        if (t + 2 < 32) loadK(0, kt0 + t + 2);
        comp(1);
    }
#pragma unroll
    for (int mt = 0; mt < 4; mt++)
#pragma unroll
        for (int i = 0; i < 4; i++)
            for (int d = 1; d < 16; d <<= 1)
                racc[mt][i] += __shfl_xor(racc[mt][i], d, 64);
    if (ln == 0) {
#pragma unroll
        for (int mt = 0; mt < 4; mt++)
#pragma unroll
            for (int i = 0; i < 4; i++)
                atomicAdd(&rowsum[bh * 2048 + qb + mt*16 + quad*4 + i], racc[mt][i]);
    }
}

// colsum[k] += sum over this block's q-quarter of 2^(c_qk)/rowsum[q].
// 3-term split (hi*hi + hi*lo + lo*hi) — feeds the top-k ranking, which
// needs per-score ~2^-17 precision (R17 proved hi-only flips the mask).
__global__ __launch_bounds__(256) void attn_colsum(
    const short* __restrict__ Qhi, const short* __restrict__ Qlo,
    const short* __restrict__ Khi, const short* __restrict__ Klo,
    const float* __restrict__ rowsum, float* __restrict__ colsum)
{
    __shared__ float sli[512];
    int bh = blockIdx.z, tid = threadIdx.x;
    int q0 = blockIdx.y * 512;
    for (int j = tid; j < 512; j += 256)
        sli[j] = 1.0f / rowsum[bh * 2048 + q0 + j];
    __syncthreads();

    int w = tid >> 6, lane = tid & 63, ln = lane & 15, quad = lane >> 4;
    int kb  = blockIdx.x * 256 + w * 64;
    int qt0 = blockIdx.y * 32;            // 32 q-tiles of 16
    const short* QH = Qhi + (size_t)bh * 131072;
    const short* QL = Qlo + (size_t)bh * 131072;
    const short* KH = Khi + (size_t)bh * 131072;
    const short* KL = Klo + (size_t)bh * 131072;

    short8 kh[4][2], kl[4][2];
#pragma unroll
    for (int nt = 0; nt < 4; nt++)
#pragma unroll
        for (int half = 0; half < 2; half++) {
            size_t o = (size_t)((kb >> 5) + (nt >> 1)) * 2048 + (size_t)half * 1024
                     + (size_t)quad * 256 + ((nt & 1) * 16 + ln) * 8;
            kh[nt][half] = *(const short8*)(KH + o);
            kl[nt][half] = *(const short8*)(KL + o);
        }

    short8 qh[2][2], ql[2][2];   // [buf][half]
    auto loadQ = [&](int buf, int qt) {
        int qtt = qt0 + qt;
        size_t base = (size_t)(qtt >> 1) * 2048 + ((qtt & 1) * 16 + ln) * 8;
        qh[buf][0] = *(const short8*)(QH + base + (size_t)quad * 256);
        qh[buf][1] = *(const short8*)(QH + base + (size_t)(4 + quad) * 256);
        ql[buf][0] = *(const short8*)(QL + base + (size_t)quad * 256);
        ql[buf][1] = *(const short8*)(QL + base + (size_t)(4 + quad) * 256);
    };

    float cacc[4] = {0.f, 0.f, 0.f, 0.f};
    auto comp = [&](int buf, int qt) {
#pragma unroll
        for (int nt = 0; nt < 4; nt++) {
            f32x4 c1 = (f32x4){0.f,0.f,0.f,0.f};
            f32x4 c2 = (f32x4){0.f,0.f,0.f,0.f};
            c1 = MFMA(qh[buf][0], kh[nt][0], c1); c1 = MFMA(qh[buf][1], kh[nt][1], c1);
            c2 = MFMA(qh[buf][0], kl[nt][0], c2); c2 = MFMA(qh[buf][1], kl[nt][1], c2);
            c2 = MFMA(ql[buf][0], kh[nt][0], c2); c2 = MFMA(ql[buf][1], kh[nt][1], c2);
#pragma unroll
            for (int i = 0; i < 4; i++) {
                int r = qt*16 + quad*4 + i;
                cacc[nt] += PEXP(c1[i] + c2[i]) * sli[r];
            }
        }
    };

    loadQ(0, 0);
    for (int qt = 0; qt < 32; qt += 2) {
        loadQ(1, qt + 1);
        comp(0, qt);
        if (qt + 2 < 32) loadQ(0, qt + 2);
        comp(1, qt + 1);
    }
#pragma unroll
    for (int nt = 0; nt < 4; nt++) {
        cacc[nt] += __shfl_xor(cacc[nt], 16, 64);
        cacc[nt] += __shfl_xor(cacc[nt], 32, 64);
        if (lane < 16) atomicAdd(&colsum[bh * 2048 + kb + nt*16 + lane], cacc[nt]);
    }
}

// Per (b,h): threshold = KEEP-th largest colsum via 4-level radix select.
// Parallel suffix-scan over the 256-bin histogram (was tid0-serial).
__global__ __launch_bounds__(256) void topk_mask(
    const float* __restrict__ colsum, float* __restrict__ maskf)
{
    __shared__ unsigned keys[2048];
    __shared__ int hist[256];
    __shared__ int suf[256];
    __shared__ unsigned sh_pref;
    __shared__ int sh_need;
    int bh = blockIdx.x, tid = threadIdx.x;
    for (int j = tid; j < 2048; j += 256) {
        unsigned u = __float_as_uint(colsum[bh * 2048 + j]);
        keys[j] = (u & 0x80000000u) ? ~u : (u | 0x80000000u);
    }
    if (tid == 0) { sh_pref = 0; sh_need = KEEP; }
    __syncthreads();
#pragma unroll
    for (int shift = 24; shift >= 0; shift -= 8) {
        int need = sh_need;
        unsigned pref = sh_pref;
        hist[tid] = 0;
        __syncthreads();
        unsigned hmask = (shift == 24) ? 0u : (0xFFFFFFFFu << (shift + 8));
        for (int j = tid; j < 2048; j += 256) {
            unsigned ky = keys[j];
            if ((ky & hmask) == pref)
                atomicAdd(&hist[(ky >> shift) & 255], 1);
        }
        __syncthreads();
        // inclusive suffix sum: suf[d] = sum_{d'>=d} hist[d']
        suf[tid] = hist[tid];
        __syncthreads();
#pragma unroll
        for (int st = 1; st < 256; st <<= 1) {
            int add = (tid + st < 256) ? suf[tid + st] : 0;
            __syncthreads();
            suf[tid] += add;
            __syncthreads();
        }
        // unique digit d with suffix_excl(d) < need <= suffix_incl(d)
        if (suf[tid] >= need && suf[tid] - hist[tid] < need) {
            sh_pref = pref | ((unsigned)tid << shift);
            sh_need = need - (suf[tid] - hist[tid]);
        }
        __syncthreads();
    }
    unsigned thr = sh_pref;
    for (int j = tid; j < 2048; j += 256)
        maskf[bh * 2048 + j] = (keys[j] >= thr) ? 1.0f : 0.0f;
}

// PV with swapped-operand QK^T, in-register P, block-level LDS staging of
// frag-major K/V in 64-key chunks (half the barriers of 32-key chunks).
// XCD-chunked remap keeps a bh's blocks on one XCD.
__global__ __launch_bounds__(256) void attn_av(
    const short* __restrict__ Qhi, const short* __restrict__ Kf,
    const short* __restrict__ Vf, const float* __restrict__ rowsum,
    unsigned short* __restrict__ concat)
{
    __shared__ __align__(16) short KA[8192];   // [0,4096): K 64 keys, [4096,8192): V
    __shared__ __align__(16) short KB[8192];
    int lin = blockIdx.x + (blockIdx.y << 4);          // [0,512)
    int tile = (lin & 7) * 64 + (lin >> 3);
    int bxx = tile & 15, bh = tile >> 4;
    int tid = threadIdx.x;
    int w = tid >> 6, lane = tid & 63;
    int lq = lane & 31, hi = lane >> 5;
    int qb = bxx * 128 + w * 32;
    const short* Qb = Qhi + (size_t)bh * 131072 + (size_t)(qb >> 5) * 2048;
    const short* Kg = Kf  + (size_t)bh * 131072;
    const short* Vg = Vf  + (size_t)bh * 131072;

    short8 qf[4];
#pragma unroll
    for (int d = 0; d < 4; d++)
        qf[d] = *(const short8*)(Qb + (size_t)(d*2 + hi) * 256 + lq * 8);

    f32x16 o0, o1;
#pragma unroll
    for (int i = 0; i < 16; i++) { o0[i] = 0.f; o1[i] = 0.f; }

    auto STAGE = [&](short* B, int c) {     // c in [0,32): 64-key chunk
        const short* Kc = Kg + (size_t)c * 4096;
        const short* Vc = Vg + (size_t)c * 4096;
        __builtin_amdgcn_global_load_lds(AS1(Kc + tid*8),        AS3(B + w*512), 16, 0, 0);
        __builtin_amdgcn_global_load_lds(AS1(Kc + 2048 + tid*8), AS3(B + 2048 + w*512), 16, 0, 0);
        __builtin_amdgcn_global_load_lds(AS1(Vc + tid*8),        AS3(B + 4096 + w*512), 16, 0, 0);
        __builtin_amdgcn_global_load_lds(AS1(Vc + 2048 + tid*8), AS3(B + 4096 + 2048 + w*512), 16, 0, 0);
    };

    // one 32-key half: S^T -> exp -> pack -> PV (same op order as before)
    auto half_comp = [&](const short* Bk, const short* Bv) {
        short8 kf_[4], vf_[4];
#pragma unroll
        for (int d = 0; d < 4; d++)
            kf_[d] = *(const short8*)(Bk + (d*2 + hi)*256 + lq*8);
#pragma unroll
        for (int ks = 0; ks < 2; ks++)
#pragma unroll
            for (int nt = 0; nt < 2; nt++)
                vf_[ks*2+nt] = *(const short8*)(Bv + ((ks*2+nt)*2 + hi)*256 + lq*8);

        f32x16 s;
#pragma unroll
        for (int i = 0; i < 16; i++) s[i] = 0.f;
        s = MFMA32(kf_[0], qf[0], s);
        s = MFMA32(kf_[1], qf[1], s);
        s = MFMA32(kf_[2], qf[2], s);
        s = MFMA32(kf_[3], qf[3], s);

        float p[16];
#pragma unroll
        for (int i = 0; i < 16; i++) p[i] = PEXP(s[i]);

        short8 pa[2];
#pragma unroll
        for (int ks = 0; ks < 2; ks++) {
            unsigned w0, w1, w2, w3;
            int o8 = ks * 8;
            asm("v_cvt_pk_bf16_f32 %0, %1, %2" : "=v"(w0) : "v"(p[o8+0]), "v"(p[o8+1]));
            asm("v_cvt_pk_bf16_f32 %0, %1, %2" : "=v"(w1) : "v"(p[o8+2]), "v"(p[o8+3]));
            asm("v_cvt_pk_bf16_f32 %0, %1, %2" : "=v"(w2) : "v"(p[o8+4]), "v"(p[o8+5]));
            asm("v_cvt_pk_bf16_f32 %0, %1, %2" : "=v"(w3) : "v"(p[o8+6]), "v"(p[o8+7]));
            asm("v_permlane32_swap_b32 %0, %1" : "+v"(w0), "+v"(w2));
            asm("v_permlane32_swap_b32 %0, %1" : "+v"(w1), "+v"(w3));
            u32x4 pw = { w0, w1, w2, w3 };
            pa[ks] = __builtin_bit_cast(short8, pw);
        }

        o0 = MFMA32(pa[0], vf_[0], o0);
        o1 = MFMA32(pa[0], vf_[1], o1);
        o0 = MFMA32(pa[1], vf_[2], o0);
        o1 = MFMA32(pa[1], vf_[3], o1);
    };
    auto comp = [&](const short* B) {
        half_comp(B, B + 4096);                 // keys [c*64, c*64+32)
        half_comp(B + 2048, B + 4096 + 2048);   // keys [c*64+32, c*64+64)
    };

    STAGE(KA, 0);
    __syncthreads();
    for (int c = 0; c < 32; c += 2) {
        STAGE(KB, c + 1);           // next chunk's loads fly under compute
        comp(KA);
        __syncthreads();            // publishes KB, guards KA reuse
        if (c + 2 < 32) STAGE(KA, c + 2);
        comp(KB);
        __syncthreads();
    }

    int b_ = bh >> 4, h = bh & 15;
#pragma unroll
    for (int r = 0; r < 16; r++) {
        int crow = (r & 3) + 8*(r >> 2) + 4*hi;
        float inv = 1.0f / rowsum[bh * 2048 + qb + crow];
        size_t base = ((size_t)(b_*2048 + qb + crow)) * 1024 + h*64;
        concat[base + lq]      = f2bf(o0[r] * inv);
        concat[base + 32 + lq] = f2bf(o1[r] * inv);
    }
}

extern "C" void kernel_launch(void* const* d_in, const int* in_sizes, int n_in,
                              void* d_out, int out_size, void* d_ws, size_t ws_size,
                              hipStream_t stream)
{
    const float* q  = (const float*)d_in[0];
    const float* k  = (const float*)d_in[1];
    const float* v  = (const float*)d_in[2];
    const float* Wq = (const float*)d_in[3];
    const float* bq = (const float*)d_in[4];
    const float* Wk = (const float*)d_in[5];
    const float* bk = (const float*)d_in[6];
    const float* Wv = (const float*)d_in[7];
    const float* bv = (const float*)d_in[8];
    const float* Wo = (const float*)d_in[9];
    const float* bo = (const float*)d_in[10];

    char* ws = (char*)d_ws;
    size_t off = 0;
    auto alloc = [&](size_t bytes) -> void* {
        void* p = ws + off;
        off += (bytes + 255) & ~(size_t)255;
        return p;
    };
    const size_t ASZ = (size_t)4096 * 1024 * 2;   // 8.4 MB bf16 activation
    const size_t WSZ = (size_t)1024 * 1024 * 2;   // 2 MB bf16 weight
    unsigned short* qh_ = (unsigned short*)alloc(ASZ);
    unsigned short* ql_ = (unsigned short*)alloc(ASZ);
    unsigned short* kh_ = (unsigned short*)alloc(ASZ);
    unsigned short* kl_ = (unsigned short*)alloc(ASZ);
    unsigned short* vh_ = (unsigned short*)alloc(ASZ);
    unsigned short* wqh = (unsigned short*)alloc(WSZ);
    unsigned short* wql = (unsigned short*)alloc(WSZ);
    unsigned short* wkh = (unsigned short*)alloc(WSZ);
    unsigned short* wkl = (unsigned short*)alloc(WSZ);
    unsigned short* wvh = (unsigned short*)alloc(WSZ);
    unsigned short* woh = (unsigned short*)alloc(WSZ);
    unsigned short* wol = (unsigned short*)alloc(WSZ);
    short* Qhi = (short*)alloc(ASZ);   // frag-major
    short* Qlo = (short*)alloc(ASZ);   // frag-major
    short* Khi = (short*)alloc(ASZ);   // frag-major
    short* Klo = (short*)alloc(ASZ);   // frag-major
    short* Vt  = (short*)alloc(ASZ);   // frag-major
    float* rowsum = (float*)alloc((size_t)32 * 2048 * 4);
    float* colsum = (float*)alloc((size_t)32 * 2048 * 4);   // contiguous after rowsum
    float* maskf  = (float*)alloc((size_t)32 * 2048 * 4);
    unsigned short* concat = (unsigned short*)alloc(ASZ);
    // total ~110 MB (known-safe)

    dim3 blk(256);

    cvt_all<<<dim3(16512), blk, 0, stream>>>(
        q, k, v, Wq, Wk, Wv, Wo,
        qh_, ql_, kh_, kl_, vh_, wqh, wql, wkh, wkl, wvh, woh, wol,
        rowsum /* zbuf: zeros rowsum+colsum (contiguous) */);

    gemm_qkv<<<dim3(8, 32, 2), blk, 0, stream>>>(
        (const short*)qh_, (const short*)ql_, (const short*)kh_, (const short*)kl_,
        (const short*)wqh, (const short*)wql, (const short*)wkh, (const short*)wkl,
        bq, bk,
        (unsigned short*)Qhi, (unsigned short*)Qlo,
        (unsigned short*)Khi, (unsigned short*)Klo);

    attn_rowsum<<<dim3(8, 4, 32), blk, 0, stream>>>(Qhi, Khi, rowsum);
    attn_colsum<<<dim3(8, 4, 32), blk, 0, stream>>>(Qhi, Qlo, Khi, Klo, rowsum, colsum);
    topk_mask  <<<dim3(32),   blk, 0, stream>>>(colsum, maskf);

    gemm_v<<<dim3(16, 32), blk, 0, stream>>>(
        (const short*)vh_, (const short*)wvh, bv, maskf, (unsigned short*)Vt);

    attn_av    <<<dim3(16, 32), blk, 0, stream>>>(Qhi, Khi, Vt, rowsum, concat);

    gemm_out<<<dim3(16, 32), blk, 0, stream>>>((const short*)concat,
        (const short*)woh, (const short*)wol, bo, (float*)d_out);
}